// Round 1
// baseline (673.060 us; speedup 1.0000x reference)
//
#include <hip/hip_runtime.h>

// Problem constants
#define NN    16384      // N nodes
#define EE    262144     // edges
#define BNODES 32768     // B*N
#define AH    384        // A*H
#define TOT_NOISE 1572864u
#define HALF_NOISE 786432u

// ---------------------------------------------------------------------------
// Threefry-2x32, keys = (0, 42)  [jax.random.key(42)]
// ---------------------------------------------------------------------------
__device__ __forceinline__ void threefry2x32_042(unsigned& x0, unsigned& x1) {
  const unsigned ks0 = 0u;
  const unsigned ks1 = 42u;
  const unsigned ks2 = 0x1BD11BDAu ^ 0u ^ 42u;
  x0 += ks0; x1 += ks1;
#define TFR(r) { x0 += x1; x1 = (x1 << (r)) | (x1 >> (32 - (r))); x1 ^= x0; }
  TFR(13) TFR(15) TFR(26) TFR(6)   x0 += ks1; x1 += ks2 + 1u;
  TFR(17) TFR(29) TFR(16) TFR(24)  x0 += ks2; x1 += ks0 + 2u;
  TFR(13) TFR(15) TFR(26) TFR(6)   x0 += ks0; x1 += ks1 + 3u;
  TFR(17) TFR(29) TFR(16) TFR(24)  x0 += ks1; x1 += ks2 + 4u;
  TFR(13) TFR(15) TFR(26) TFR(6)   x0 += ks2; x1 += ks0 + 5u;
#undef TFR
}

// XLA ErfInv32 (Giles) polynomial — matches CHLO erf_inv lowering
__device__ __forceinline__ float erfinv_f32(float x) {
  float w = -log1pf(-x * x);
  float p;
  if (w < 5.0f) {
    w -= 2.5f;
    p = 2.81022636e-08f;
    p = fmaf(p, w, 3.43273939e-07f);
    p = fmaf(p, w, -3.5233877e-06f);
    p = fmaf(p, w, -4.39150654e-06f);
    p = fmaf(p, w, 0.00021858087f);
    p = fmaf(p, w, -0.00125372503f);
    p = fmaf(p, w, -0.00417768164f);
    p = fmaf(p, w, 0.246640727f);
    p = fmaf(p, w, 1.50140941f);
  } else {
    w = sqrtf(w) - 3.0f;
    p = -0.000200214257f;
    p = fmaf(p, w, 0.000100950558f);
    p = fmaf(p, w, 0.00134934322f);
    p = fmaf(p, w, -0.00367342844f);
    p = fmaf(p, w, 0.00573950773f);
    p = fmaf(p, w, -0.0076224613f);
    p = fmaf(p, w, 0.00943887047f);
    p = fmaf(p, w, 1.00167406f);
    p = fmaf(p, w, 2.83297682f);
  }
  return p * x;
}

// jax_threefry_partitionable=True 32-bit draw for flat index i:
// counter = (hi=0, lo=i); bits = out0 ^ out1
__device__ __forceinline__ unsigned jax_random_bits32(unsigned i) {
  unsigned x0 = 0u, x1 = i;
  threefry2x32_042(x0, x1);
  return x0 ^ x1;
}

__device__ __forceinline__ float jax_normal_from_bits(unsigned bits) {
  float f = __uint_as_float((bits >> 9) | 0x3f800000u) - 1.0f;  // [0,1)
  const float lo = -0.99999994f;                                 // nextafter(-1,0)
  float u = f * 2.0f + lo;   // (maxval-minval) rounds to exactly 2.0f
  u = fmaxf(u, lo);
  return 1.4142135623730951f * erfinv_f32(u);
}

// ---------------------------------------------------------------------------
// CSR build
// ---------------------------------------------------------------------------
__global__ void edge_count(const int* __restrict__ dst, int* __restrict__ deg) {
  int e = blockIdx.x * 256 + threadIdx.x;
  if (e < EE) atomicAdd(&deg[dst[e]], 1);
}

__global__ __launch_bounds__(256) void scan_k(const int* __restrict__ deg,
                                              int* __restrict__ offs,
                                              int* __restrict__ cur) {
  __shared__ int part[256];
  int t = threadIdx.x;
  int base = t * 64;
  int s = 0;
  for (int i = 0; i < 64; i++) s += deg[base + i];
  part[t] = s;
  __syncthreads();
  for (int off = 1; off < 256; off <<= 1) {
    int v = (t >= off) ? part[t - off] : 0;
    __syncthreads();
    part[t] += v;
    __syncthreads();
  }
  int run = (t == 0) ? 0 : part[t - 1];
  for (int i = 0; i < 64; i++) {
    offs[base + i] = run;
    cur[base + i] = run;
    run += deg[base + i];
  }
  if (t == 255) offs[NN] = run;
}

__global__ void edge_fill(const int* __restrict__ dst, const int* __restrict__ srcv,
                          int* __restrict__ cur, int* __restrict__ csr) {
  int e = blockIdx.x * 256 + threadIdx.x;
  if (e < EE) {
    int d = dst[e];
    int p = atomicAdd(&cur[d], 1);
    csr[p] = srcv[e];
  }
}

// ---------------------------------------------------------------------------
// Generic per-a GEMM: C[m, a*cAOff + c] = act( X[m (stride), a*xAOff + k] @ W[a][k][c] + bias[a][c] )
// M tile = 128 rows, N = 128 cols, K = 128. X tile in LDS (XOR-swizzled), W streamed from L2.
// ---------------------------------------------------------------------------
__global__ __launch_bounds__(256) void gemm_a128(
    const float* __restrict__ X, long xRowStride, long xAOff,
    const float* __restrict__ W, long wAStride,
    const float* __restrict__ Bias, long bAStride,
    float* __restrict__ C, long cRowStride, long cAOff,
    int relu) {
  __shared__ float Xs[128 * 128];
  const int a = blockIdx.y;
  const long m0 = (long)blockIdx.x * 128;
  const int tid = threadIdx.x;
  const float* Xp = X + (long)a * xAOff;
  const float* Wp = W + (long)a * wAStride;

  // load X tile with per-row XOR quad swizzle (breaks 4-way LDS bank conflicts)
  for (int i = tid; i < 128 * 32; i += 256) {
    int r = i >> 5;
    int q = i & 31;
    int qs = q ^ (r & 3);
    float4 v = *(const float4*)(Xp + (m0 + r) * xRowStride + (q << 2));
    *(float4*)(&Xs[r * 128 + (qs << 2)]) = v;
  }
  __syncthreads();

  const int rb = tid >> 4;          // 0..15, within wave 0..3
  const int c0 = (tid & 15) << 3;   // 0..120
  float acc[8][8];
#pragma unroll
  for (int j = 0; j < 8; j++)
#pragma unroll
    for (int c = 0; c < 8; c++) acc[j][c] = 0.0f;

  for (int k0 = 0; k0 < 128; k0 += 4) {
    float4 wv[4][2];
#pragma unroll
    for (int kk = 0; kk < 4; kk++) {
      wv[kk][0] = *(const float4*)(Wp + (long)(k0 + kk) * 128 + c0);
      wv[kk][1] = *(const float4*)(Wp + (long)(k0 + kk) * 128 + c0 + 4);
    }
    int qphys = ((k0 >> 2) ^ (rb & 3)) << 2;
#pragma unroll
    for (int j = 0; j < 8; j++) {
      int r = rb + 16 * j;
      float4 xv = *(const float4*)(&Xs[r * 128 + qphys]);
#pragma unroll
      for (int kk = 0; kk < 4; kk++) {
        float xk = (kk == 0) ? xv.x : (kk == 1) ? xv.y : (kk == 2) ? xv.z : xv.w;
        acc[j][0] += xk * wv[kk][0].x;
        acc[j][1] += xk * wv[kk][0].y;
        acc[j][2] += xk * wv[kk][0].z;
        acc[j][3] += xk * wv[kk][0].w;
        acc[j][4] += xk * wv[kk][1].x;
        acc[j][5] += xk * wv[kk][1].y;
        acc[j][6] += xk * wv[kk][1].z;
        acc[j][7] += xk * wv[kk][1].w;
      }
    }
  }

  const float* bp = Bias + (long)a * bAStride + c0;
  float bias8[8];
#pragma unroll
  for (int c = 0; c < 8; c++) bias8[c] = bp[c];

#pragma unroll
  for (int j = 0; j < 8; j++) {
    long row = m0 + rb + 16 * j;
    float* cp = C + row * cRowStride + (long)a * cAOff + c0;
    float v[8];
#pragma unroll
    for (int c = 0; c < 8; c++) {
      float t = acc[j][c] + bias8[c];
      v[c] = relu ? fmaxf(t, 0.0f) : t;
    }
    *(float4*)(cp) = make_float4(v[0], v[1], v[2], v[3]);
    *(float4*)(cp + 4) = make_float4(v[4], v[5], v[6], v[7]);
  }
}

// Small GEMM for mu_W2: N=16, K=128, per-a
__global__ __launch_bounds__(256) void gemm_a16(
    const float* __restrict__ X, long xRowStride, long xAOff,
    const float* __restrict__ W, long wAStride,
    const float* __restrict__ Bias, long bAStride,
    float* __restrict__ C, long cRowStride, long cAOff) {
  __shared__ float Xs[64 * 132];
  __shared__ float Ws[128 * 16];
  const int a = blockIdx.y;
  const long m0 = (long)blockIdx.x * 64;
  const int tid = threadIdx.x;
  const float* Xp = X + (long)a * xAOff;
  const float* Wp = W + (long)a * wAStride;

  for (int i = tid; i < 64 * 32; i += 256) {
    int r = i >> 5, c4 = (i & 31) << 2;
    *(float4*)(&Xs[r * 132 + c4]) = *(const float4*)(Xp + (m0 + r) * xRowStride + c4);
  }
  for (int i = tid; i < 512; i += 256) {
    int r = i >> 2, c4 = (i & 3) << 2;
    *(float4*)(&Ws[r * 16 + c4]) = *(const float4*)(Wp + r * 16 + c4);
  }
  __syncthreads();

  const int c = tid & 15;
  const int rg = tid >> 4;  // 0..15 -> rows rg*4 .. rg*4+3
  float acc[4] = {0.f, 0.f, 0.f, 0.f};
  for (int k = 0; k < 128; k++) {
    float w = Ws[k * 16 + c];
#pragma unroll
    for (int i = 0; i < 4; i++) acc[i] += Xs[(rg * 4 + i) * 132 + k] * w;
  }
  float b = Bias[(long)a * bAStride + c];
#pragma unroll
  for (int i = 0; i < 4; i++) {
    long row = m0 + rg * 4 + i;
    C[row * cRowStride + (long)a * cAOff + c] = acc[i] + b;
  }
}

// ---------------------------------------------------------------------------
// Segment-sum aggregation via CSR: agg[b,n,:] = sum over incoming edges of h[b,src,:]
// ---------------------------------------------------------------------------
__global__ __launch_bounds__(128) void aggregate(
    const float* __restrict__ Hfeat, const int* __restrict__ offs,
    const int* __restrict__ csr, float* __restrict__ AGG) {
  const int bn = blockIdx.x;
  const int b = bn >> 14;
  const int n = bn & (NN - 1);
  const int tid = threadIdx.x;
  const int e0 = offs[n], e1 = offs[n + 1];
  const float* hb = Hfeat + (long)b * NN * AH;
  float a0 = 0.f, a1 = 0.f, a2 = 0.f;
  for (int j = e0; j < e1; j++) {
    int s = csr[j];
    const float* hp = hb + (long)s * AH;
    a0 += hp[tid];
    a1 += hp[tid + 128];
    a2 += hp[tid + 256];
  }
  float* ap = AGG + (long)bn * AH;
  ap[tid] = a0;
  ap[tid + 128] = a1;
  ap[tid + 256] = a2;
}

// ---------------------------------------------------------------------------
// Fused per-node attention: q/k/v proj, 3x3 softmax per head, o, hI = agg + o@Wo + bo
// 4 nodes per 128-thread block; weights streamed from L2; in-place output over agg.
// ---------------------------------------------------------------------------
__global__ __launch_bounds__(128) void attn_node(
    const float* __restrict__ AGG,
    const float* __restrict__ Wq, const float* __restrict__ bq,
    const float* __restrict__ Wk, const float* __restrict__ bk,
    const float* __restrict__ Wv, const float* __restrict__ bv,
    const float* __restrict__ Wo, const float* __restrict__ bo,
    float* __restrict__ OUT) {
  __shared__ float aggS[4][3][128];
  __shared__ float qS[4][3][128];
  __shared__ float kS[4][3][128];
  __shared__ float vS[4][3][128];
  __shared__ float oS[4][3][128];
  const int tid = threadIdx.x;
  const int c = tid;
  const long node0 = (long)blockIdx.x * 4;

  for (int i = tid; i < 4 * AH; i += 128)
    ((float*)aggS)[i] = AGG[node0 * AH + i];
  __syncthreads();

  // q,k,v projections: thread owns output column c
  float qa[4][3], ka[4][3], va[4][3];
#pragma unroll
  for (int nd = 0; nd < 4; nd++)
#pragma unroll
    for (int a = 0; a < 3; a++) { qa[nd][a] = 0.f; ka[nd][a] = 0.f; va[nd][a] = 0.f; }

  for (int k0 = 0; k0 < 128; k0 += 4) {
    float4 xr[4][3];
#pragma unroll
    for (int nd = 0; nd < 4; nd++)
#pragma unroll
      for (int a = 0; a < 3; a++)
        xr[nd][a] = *(const float4*)(&aggS[nd][a][k0]);
#pragma unroll
    for (int kk = 0; kk < 4; kk++) {
      float wq = Wq[(long)(k0 + kk) * 128 + c];
      float wk = Wk[(long)(k0 + kk) * 128 + c];
      float wv = Wv[(long)(k0 + kk) * 128 + c];
#pragma unroll
      for (int nd = 0; nd < 4; nd++)
#pragma unroll
        for (int a = 0; a < 3; a++) {
          float x = (kk == 0) ? xr[nd][a].x : (kk == 1) ? xr[nd][a].y
                   : (kk == 2) ? xr[nd][a].z : xr[nd][a].w;
          qa[nd][a] += x * wq;
          ka[nd][a] += x * wk;
          va[nd][a] += x * wv;
        }
    }
  }
  {
    float bqv = bq[c], bkv = bk[c], bvv = bv[c];
#pragma unroll
    for (int nd = 0; nd < 4; nd++)
#pragma unroll
      for (int a = 0; a < 3; a++) {
        qS[nd][a][c] = qa[nd][a] + bqv;
        kS[nd][a][c] = ka[nd][a] + bkv;
        vS[nd][a][c] = va[nd][a] + bvv;
      }
  }
  __syncthreads();

  // attention: per (head e, dim d); 3x3 scores, softmax over a_k
  const int d = tid & 31;
  const int e = tid >> 5;  // 0..3
  const float scale = 0.17677669529663687f;  // 1/sqrt(32)
  for (int nd = 0; nd < 4; nd++) {
    float qv[3], kv[3], vv[3];
    int idx = e * 32 + d;
#pragma unroll
    for (int a = 0; a < 3; a++) {
      qv[a] = qS[nd][a][idx];
      kv[a] = kS[nd][a][idx];
      vv[a] = vS[nd][a][idx];
    }
    float sc[3][3];
#pragma unroll
    for (int aq = 0; aq < 3; aq++)
#pragma unroll
      for (int ak = 0; ak < 3; ak++) {
        float p = qv[aq] * kv[ak];
        p += __shfl_xor(p, 16, 64);
        p += __shfl_xor(p, 8, 64);
        p += __shfl_xor(p, 4, 64);
        p += __shfl_xor(p, 2, 64);
        p += __shfl_xor(p, 1, 64);
        sc[aq][ak] = p * scale;
      }
#pragma unroll
    for (int aq = 0; aq < 3; aq++) {
      float mx = fmaxf(sc[aq][0], fmaxf(sc[aq][1], sc[aq][2]));
      float e0 = expf(sc[aq][0] - mx);
      float e1 = expf(sc[aq][1] - mx);
      float e2 = expf(sc[aq][2] - mx);
      float inv = 1.0f / (e0 + e1 + e2);
      oS[nd][aq][idx] = (e0 * vv[0] + e1 * vv[1] + e2 * vv[2]) * inv;
    }
  }
  __syncthreads();

  // hI = agg + o @ Wo + bo  (in place)
  float ha[4][3];
  {
    float bov = bo[c];
#pragma unroll
    for (int nd = 0; nd < 4; nd++)
#pragma unroll
      for (int a = 0; a < 3; a++) ha[nd][a] = aggS[nd][a][c] + bov;
  }
  for (int k0 = 0; k0 < 128; k0 += 4) {
    float4 xo[4][3];
#pragma unroll
    for (int nd = 0; nd < 4; nd++)
#pragma unroll
      for (int a = 0; a < 3; a++)
        xo[nd][a] = *(const float4*)(&oS[nd][a][k0]);
#pragma unroll
    for (int kk = 0; kk < 4; kk++) {
      float wo = Wo[(long)(k0 + kk) * 128 + c];
#pragma unroll
      for (int nd = 0; nd < 4; nd++)
#pragma unroll
        for (int a = 0; a < 3; a++) {
          float x = (kk == 0) ? xo[nd][a].x : (kk == 1) ? xo[nd][a].y
                   : (kk == 2) ? xo[nd][a].z : xo[nd][a].w;
          ha[nd][a] += x * wo;
        }
    }
  }
#pragma unroll
  for (int nd = 0; nd < 4; nd++)
#pragma unroll
    for (int a = 0; a < 3; a++)
      OUT[(node0 + nd) * AH + a * 128 + c] = ha[nd][a];
}

// ---------------------------------------------------------------------------
// Final: threefry noise + sample activations + logp sum. One wave per node.
// ---------------------------------------------------------------------------
__global__ __launch_bounds__(256) void final_out(
    const float* __restrict__ MU, float* __restrict__ out0, float* __restrict__ out1) {
  const int tid = threadIdx.x;
  const int t = tid & 63;
  const long bn = (long)blockIdx.x * 4 + (tid >> 6);
  const bool act = (t < 48);
  const long gidx = bn * 48 + t;
  float sample = 0.f, lp = 0.f;
  if (act) {
    unsigned bits = jax_random_bits32((unsigned)gidx);
    float noise = jax_normal_from_bits(bits);
    sample = MU[gidx] + noise;
    lp = -0.9189385332046727f - 0.5f * noise * noise;
  }
  float s = lp;
  s += __shfl_xor(s, 32, 64);
  s += __shfl_xor(s, 16, 64);
  s += __shfl_xor(s, 8, 64);
  s += __shfl_xor(s, 4, 64);
  s += __shfl_xor(s, 2, 64);
  s += __shfl_xor(s, 1, 64);
  if (t == 0) out1[bn] = s;

  if (t < 16) {
    float th = tanhf(sample);
    float mx = th;
    mx = fmaxf(mx, __shfl_xor(mx, 8, 64));
    mx = fmaxf(mx, __shfl_xor(mx, 4, 64));
    mx = fmaxf(mx, __shfl_xor(mx, 2, 64));
    mx = fmaxf(mx, __shfl_xor(mx, 1, 64));
    float ex = expf(th - mx);
    float ss = ex;
    ss += __shfl_xor(ss, 8, 64);
    ss += __shfl_xor(ss, 4, 64);
    ss += __shfl_xor(ss, 2, 64);
    ss += __shfl_xor(ss, 1, 64);
    out0[gidx] = ex / ss;
  } else if (t < 32) {
    out0[gidx] = 1.0f / (1.0f + expf(-sample));
  } else if (t < 48) {
    out0[gidx] = tanhf(sample);
  }
}

// ---------------------------------------------------------------------------
extern "C" void kernel_launch(void* const* d_in, const int* in_sizes, int n_in,
                              void* d_out, int out_size, void* d_ws, size_t ws_size,
                              hipStream_t stream) {
  const float* x = (const float*)d_in[0];
  const int* ei = (const int*)d_in[1];
  const float* W1 = (const float*)d_in[2];
  const float* b1 = (const float*)d_in[3];
  const float* W2 = (const float*)d_in[4];
  const float* b2 = (const float*)d_in[5];
  const float* Wq = (const float*)d_in[6];
  const float* bq = (const float*)d_in[7];
  const float* Wk = (const float*)d_in[8];
  const float* bk = (const float*)d_in[9];
  const float* Wv = (const float*)d_in[10];
  const float* bv = (const float*)d_in[11];
  const float* Wo = (const float*)d_in[12];
  const float* bo = (const float*)d_in[13];
  const float* mW1 = (const float*)d_in[14];
  const float* mb1 = (const float*)d_in[15];
  const float* mW2 = (const float*)d_in[16];
  const float* mb2 = (const float*)d_in[17];
  (void)in_sizes; (void)n_in; (void)out_size; (void)ws_size;

  float* bufA = (float*)d_ws;              // 12,582,912 floats (B*N*A*H)
  float* bufB = bufA + 12582912;           // 12,582,912
  float* bufC = bufB + 12582912;           // 1,572,864 (mu)
  int* deg = (int*)(bufC + 1572864);       // 16384
  int* offs = deg + NN;                    // 16385
  int* cur = offs + (NN + 1);              // 16384
  int* csr = cur + NN;                     // 262144

  const int* dst = ei;
  const int* srcv = ei + EE;

  float* out0 = (float*)d_out;
  float* out1 = out0 + TOT_NOISE;

  // CSR build
  hipMemsetAsync(deg, 0, NN * sizeof(int), stream);
  edge_count<<<EE / 256, 256, 0, stream>>>(dst, deg);
  scan_k<<<1, 256, 0, stream>>>(deg, offs, cur);
  edge_fill<<<EE / 256, 256, 0, stream>>>(dst, srcv, cur, csr);

  dim3 g128(BNODES / 128, 3);
  // t1 = relu(x @ W1[a] + b1[a])
  gemm_a128<<<g128, 256, 0, stream>>>(x, 128, 0, W1, 16384, b1, 128, bufA, AH, 128, 1);
  // h = t1 @ W2[a] + b2[a]
  gemm_a128<<<g128, 256, 0, stream>>>(bufA, AH, 128, W2, 16384, b2, 128, bufB, AH, 128, 0);
  // agg = segment_sum(h[src] -> dst)
  aggregate<<<BNODES, 128, 0, stream>>>(bufB, offs, csr, bufA);
  // attention + hI (in place over agg)
  attn_node<<<BNODES / 4, 128, 0, stream>>>(bufA, Wq, bq, Wk, bk, Wv, bv, Wo, bo, bufA);
  // m = relu(hI @ mu_W1[a] + mu_b1[a])
  gemm_a128<<<g128, 256, 0, stream>>>(bufA, AH, 128, mW1, 16384, mb1, 128, bufB, AH, 128, 1);
  // mu = m @ mu_W2[a] + mu_b2[a]
  gemm_a16<<<dim3(BNODES / 64, 3), 256, 0, stream>>>(bufB, AH, 128, mW2, 2048, mb2, 16, bufC, 48, 16);
  // noise + activations + logp
  final_out<<<BNODES / 4, 256, 0, stream>>>(bufC, out0, out1);
}

// Round 2
// 490.678 us; speedup vs baseline: 1.3717x; 1.3717x over previous
//
#include <hip/hip_runtime.h>

// Problem constants
#define NN    16384      // N nodes
#define EE    262144     // edges
#define BNODES 32768     // B*N
#define AH    384        // A*H
#define TOT_NOISE 1572864u

typedef __attribute__((ext_vector_type(8))) short short8;
typedef __attribute__((ext_vector_type(4))) float v4f;

__device__ __forceinline__ unsigned short f2bf(float f) {
  unsigned u = __float_as_uint(f);
  unsigned r = u + 0x7fffu + ((u >> 16) & 1u);
  return (unsigned short)(r >> 16);
}
__device__ __forceinline__ float bf2f(unsigned short h) {
  return __uint_as_float(((unsigned)h) << 16);
}

// ---------------------------------------------------------------------------
// Threefry-2x32, keys = (0, 42)  [jax.random.key(42)]
// ---------------------------------------------------------------------------
__device__ __forceinline__ void threefry2x32_042(unsigned& x0, unsigned& x1) {
  const unsigned ks0 = 0u;
  const unsigned ks1 = 42u;
  const unsigned ks2 = 0x1BD11BDAu ^ 0u ^ 42u;
  x0 += ks0; x1 += ks1;
#define TFR(r) { x0 += x1; x1 = (x1 << (r)) | (x1 >> (32 - (r))); x1 ^= x0; }
  TFR(13) TFR(15) TFR(26) TFR(6)   x0 += ks1; x1 += ks2 + 1u;
  TFR(17) TFR(29) TFR(16) TFR(24)  x0 += ks2; x1 += ks0 + 2u;
  TFR(13) TFR(15) TFR(26) TFR(6)   x0 += ks0; x1 += ks1 + 3u;
  TFR(17) TFR(29) TFR(16) TFR(24)  x0 += ks1; x1 += ks2 + 4u;
  TFR(13) TFR(15) TFR(26) TFR(6)   x0 += ks2; x1 += ks0 + 5u;
#undef TFR
}

// XLA ErfInv32 (Giles) polynomial — matches CHLO erf_inv lowering
__device__ __forceinline__ float erfinv_f32(float x) {
  float w = -log1pf(-x * x);
  float p;
  if (w < 5.0f) {
    w -= 2.5f;
    p = 2.81022636e-08f;
    p = fmaf(p, w, 3.43273939e-07f);
    p = fmaf(p, w, -3.5233877e-06f);
    p = fmaf(p, w, -4.39150654e-06f);
    p = fmaf(p, w, 0.00021858087f);
    p = fmaf(p, w, -0.00125372503f);
    p = fmaf(p, w, -0.00417768164f);
    p = fmaf(p, w, 0.246640727f);
    p = fmaf(p, w, 1.50140941f);
  } else {
    w = sqrtf(w) - 3.0f;
    p = -0.000200214257f;
    p = fmaf(p, w, 0.000100950558f);
    p = fmaf(p, w, 0.00134934322f);
    p = fmaf(p, w, -0.00367342844f);
    p = fmaf(p, w, 0.00573950773f);
    p = fmaf(p, w, -0.0076224613f);
    p = fmaf(p, w, 0.00943887047f);
    p = fmaf(p, w, 1.00167406f);
    p = fmaf(p, w, 2.83297682f);
  }
  return p * x;
}

__device__ __forceinline__ unsigned jax_random_bits32(unsigned i) {
  unsigned x0 = 0u, x1 = i;
  threefry2x32_042(x0, x1);
  return x0 ^ x1;
}

__device__ __forceinline__ float jax_normal_from_bits(unsigned bits) {
  float f = __uint_as_float((bits >> 9) | 0x3f800000u) - 1.0f;  // [0,1)
  const float lo = -0.99999994f;                                 // nextafter(-1,0)
  float u = f * 2.0f + lo;
  u = fmaxf(u, lo);
  return 1.4142135623730951f * erfinv_f32(u);
}

// ---------------------------------------------------------------------------
// CSR build
// ---------------------------------------------------------------------------
__global__ void edge_count(const int* __restrict__ dst, int* __restrict__ deg) {
  int e = blockIdx.x * 256 + threadIdx.x;
  if (e < EE) atomicAdd(&deg[dst[e]], 1);
}

__global__ __launch_bounds__(256) void scan_k(const int* __restrict__ deg,
                                              int* __restrict__ offs,
                                              int* __restrict__ cur) {
  __shared__ int part[256];
  int t = threadIdx.x;
  int base = t * 64;
  int s = 0;
  for (int i = 0; i < 64; i++) s += deg[base + i];
  part[t] = s;
  __syncthreads();
  for (int off = 1; off < 256; off <<= 1) {
    int v = (t >= off) ? part[t - off] : 0;
    __syncthreads();
    part[t] += v;
    __syncthreads();
  }
  int run = (t == 0) ? 0 : part[t - 1];
  for (int i = 0; i < 64; i++) {
    offs[base + i] = run;
    cur[base + i] = run;
    run += deg[base + i];
  }
  if (t == 255) offs[NN] = run;
}

__global__ void edge_fill(const int* __restrict__ dst, const int* __restrict__ srcv,
                          int* __restrict__ cur, int* __restrict__ csr) {
  int e = blockIdx.x * 256 + threadIdx.x;
  if (e < EE) {
    int d = dst[e];
    int p = atomicAdd(&cur[d], 1);
    csr[p] = srcv[e];
  }
}

// ---------------------------------------------------------------------------
// Generic per-a GEMM (fp32 VALU): unchanged from round 1
// ---------------------------------------------------------------------------
__global__ __launch_bounds__(256) void gemm_a128(
    const float* __restrict__ X, long xRowStride, long xAOff,
    const float* __restrict__ W, long wAStride,
    const float* __restrict__ Bias, long bAStride,
    float* __restrict__ C, long cRowStride, long cAOff,
    int relu) {
  __shared__ float Xs[128 * 128];
  const int a = blockIdx.y;
  const long m0 = (long)blockIdx.x * 128;
  const int tid = threadIdx.x;
  const float* Xp = X + (long)a * xAOff;
  const float* Wp = W + (long)a * wAStride;

  for (int i = tid; i < 128 * 32; i += 256) {
    int r = i >> 5;
    int q = i & 31;
    int qs = q ^ (r & 3);
    float4 v = *(const float4*)(Xp + (m0 + r) * xRowStride + (q << 2));
    *(float4*)(&Xs[r * 128 + (qs << 2)]) = v;
  }
  __syncthreads();

  const int rb = tid >> 4;
  const int c0 = (tid & 15) << 3;
  float acc[8][8];
#pragma unroll
  for (int j = 0; j < 8; j++)
#pragma unroll
    for (int c = 0; c < 8; c++) acc[j][c] = 0.0f;

  for (int k0 = 0; k0 < 128; k0 += 4) {
    float4 wv[4][2];
#pragma unroll
    for (int kk = 0; kk < 4; kk++) {
      wv[kk][0] = *(const float4*)(Wp + (long)(k0 + kk) * 128 + c0);
      wv[kk][1] = *(const float4*)(Wp + (long)(k0 + kk) * 128 + c0 + 4);
    }
    int qphys = ((k0 >> 2) ^ (rb & 3)) << 2;
#pragma unroll
    for (int j = 0; j < 8; j++) {
      int r = rb + 16 * j;
      float4 xv = *(const float4*)(&Xs[r * 128 + qphys]);
#pragma unroll
      for (int kk = 0; kk < 4; kk++) {
        float xk = (kk == 0) ? xv.x : (kk == 1) ? xv.y : (kk == 2) ? xv.z : xv.w;
        acc[j][0] += xk * wv[kk][0].x;
        acc[j][1] += xk * wv[kk][0].y;
        acc[j][2] += xk * wv[kk][0].z;
        acc[j][3] += xk * wv[kk][0].w;
        acc[j][4] += xk * wv[kk][1].x;
        acc[j][5] += xk * wv[kk][1].y;
        acc[j][6] += xk * wv[kk][1].z;
        acc[j][7] += xk * wv[kk][1].w;
      }
    }
  }

  const float* bp = Bias + (long)a * bAStride + c0;
  float bias8[8];
#pragma unroll
  for (int c = 0; c < 8; c++) bias8[c] = bp[c];

#pragma unroll
  for (int j = 0; j < 8; j++) {
    long row = m0 + rb + 16 * j;
    float* cp = C + row * cRowStride + (long)a * cAOff + c0;
    float v[8];
#pragma unroll
    for (int c = 0; c < 8; c++) {
      float t = acc[j][c] + bias8[c];
      v[c] = relu ? fmaxf(t, 0.0f) : t;
    }
    *(float4*)(cp) = make_float4(v[0], v[1], v[2], v[3]);
    *(float4*)(cp + 4) = make_float4(v[4], v[5], v[6], v[7]);
  }
}

// Small GEMM for mu_W2: N=16, K=128, per-a
__global__ __launch_bounds__(256) void gemm_a16(
    const float* __restrict__ X, long xRowStride, long xAOff,
    const float* __restrict__ W, long wAStride,
    const float* __restrict__ Bias, long bAStride,
    float* __restrict__ C, long cRowStride, long cAOff) {
  __shared__ float Xs[64 * 132];
  __shared__ float Ws[128 * 16];
  const int a = blockIdx.y;
  const long m0 = (long)blockIdx.x * 64;
  const int tid = threadIdx.x;
  const float* Xp = X + (long)a * xAOff;
  const float* Wp = W + (long)a * wAStride;

  for (int i = tid; i < 64 * 32; i += 256) {
    int r = i >> 5, c4 = (i & 31) << 2;
    *(float4*)(&Xs[r * 132 + c4]) = *(const float4*)(Xp + (m0 + r) * xRowStride + c4);
  }
  for (int i = tid; i < 512; i += 256) {
    int r = i >> 2, c4 = (i & 3) << 2;
    *(float4*)(&Ws[r * 16 + c4]) = *(const float4*)(Wp + r * 16 + c4);
  }
  __syncthreads();

  const int c = tid & 15;
  const int rg = tid >> 4;
  float acc[4] = {0.f, 0.f, 0.f, 0.f};
  for (int k = 0; k < 128; k++) {
    float w = Ws[k * 16 + c];
#pragma unroll
    for (int i = 0; i < 4; i++) acc[i] += Xs[(rg * 4 + i) * 132 + k] * w;
  }
  float b = Bias[(long)a * bAStride + c];
#pragma unroll
  for (int i = 0; i < 4; i++) {
    long row = m0 + rg * 4 + i;
    C[row * cRowStride + (long)a * cAOff + c] = acc[i] + b;
  }
}

// ---------------------------------------------------------------------------
// Segment-sum aggregation via CSR
// ---------------------------------------------------------------------------
__global__ __launch_bounds__(128) void aggregate(
    const float* __restrict__ Hfeat, const int* __restrict__ offs,
    const int* __restrict__ csr, float* __restrict__ AGG) {
  const int bn = blockIdx.x;
  const int b = bn >> 14;
  const int n = bn & (NN - 1);
  const int tid = threadIdx.x;
  const int e0 = offs[n], e1 = offs[n + 1];
  const float* hb = Hfeat + (long)b * NN * AH;
  float a0 = 0.f, a1 = 0.f, a2 = 0.f;
  for (int j = e0; j < e1; j++) {
    int s = csr[j];
    const float* hp = hb + (long)s * AH;
    a0 += hp[tid];
    a1 += hp[tid + 128];
    a2 += hp[tid + 256];
  }
  float* ap = AGG + (long)bn * AH;
  ap[tid] = a0;
  ap[tid + 128] = a1;
  ap[tid + 256] = a2;
}

// ---------------------------------------------------------------------------
// Weight prep: convert Wq/Wk/Wv/Wo (128x128 fp32, row-major [k][n]) into
// bf16 MFMA B-fragment layout:
//   frag[f], f = (kt*8+nt)*512 + lane*8 + j  <->  W[kt*32+(lane>>4)*8+j][nt*16+(lane&15)]
// ---------------------------------------------------------------------------
__global__ __launch_bounds__(256) void prep_wfrag4(
    const float* __restrict__ Wq, const float* __restrict__ Wk,
    const float* __restrict__ Wv, const float* __restrict__ Wo,
    unsigned short* __restrict__ F) {
  int m = blockIdx.y;
  const float* W = (m == 0) ? Wq : (m == 1) ? Wk : (m == 2) ? Wv : Wo;
  int f = blockIdx.x * 256 + threadIdx.x;   // 0..16383
  int tile = f >> 9;
  int kt = tile >> 3, nt = tile & 7;
  int r = f & 511;
  int lane = r >> 3, j = r & 7;
  int k = kt * 32 + (lane >> 4) * 8 + j;
  int n = nt * 16 + (lane & 15);
  F[m * 16384 + f] = f2bf(W[k * 128 + n]);
}

// ---------------------------------------------------------------------------
// Fused MFMA attention: 16 nodes/block (M=48 rows), 256 threads (4 waves).
// Wave w owns cols [32w,32w+32) == head w, so QKV->attention is wave-local.
// hI = agg + softmax(QK^T/sqrt(32)) V @ Wo + bo, written in place over AGG.
// ---------------------------------------------------------------------------
#define XSTR 136   // xS/oS row stride in bf16 elements (pad 8)
#define QSTR 34    // per-wave q/k/v row stride (32 + 2 pad)
__global__ __launch_bounds__(256, 2) void attn_mfma(
    const float* __restrict__ AGG, const unsigned short* __restrict__ WF,
    const float* __restrict__ bq, const float* __restrict__ bk,
    const float* __restrict__ bv, const float* __restrict__ bo,
    float* __restrict__ OUT) {
  __shared__ __align__(16) unsigned short xS[48 * XSTR];
  __shared__ __align__(16) unsigned short qS[4 * 48 * QSTR];
  __shared__ __align__(16) unsigned short kS[4 * 48 * QSTR];
  __shared__ __align__(16) unsigned short vS[4 * 48 * QSTR];
  __shared__ __align__(16) unsigned short oS[48 * XSTR];

  const int tid = threadIdx.x;
  const long node0 = (long)blockIdx.x * 16;
  const float* src = AGG + node0 * 3 * 128;

  // ---- stage agg tile (48x128 fp32 -> bf16 LDS) ----
#pragma unroll
  for (int p = 0; p < 6; p++) {
    int i4 = tid + p * 256;            // 1536 float4s
    int row = i4 >> 5, c4 = (i4 & 31) << 2;
    float4 v = *(const float4*)(src + row * 128 + c4);
    unsigned short b0 = f2bf(v.x), b1 = f2bf(v.y), b2 = f2bf(v.z), b3 = f2bf(v.w);
    unsigned short* dp = &xS[row * XSTR + c4];
    dp[0] = b0; dp[1] = b1; dp[2] = b2; dp[3] = b3;
  }
  __syncthreads();

  const int w = tid >> 6;
  const int l = tid & 63;
  const int lr = l & 15;      // col within 16-tile / row within 16-tile (A)
  const int lg = l >> 4;      // k-group / row-quad
  const unsigned short* WQ = WF;
  const unsigned short* WK = WF + 16384;
  const unsigned short* WV = WF + 32768;
  const unsigned short* WO = WF + 49152;

  // ---- QKV projections via MFMA ----
  v4f accq[3][2], acck[3][2], accv[3][2];
#pragma unroll
  for (int mt = 0; mt < 3; mt++)
#pragma unroll
    for (int n = 0; n < 2; n++) {
      accq[mt][n] = (v4f){0.f, 0.f, 0.f, 0.f};
      acck[mt][n] = (v4f){0.f, 0.f, 0.f, 0.f};
      accv[mt][n] = (v4f){0.f, 0.f, 0.f, 0.f};
    }

#pragma unroll
  for (int kt = 0; kt < 4; kt++) {
    short8 af[3];
#pragma unroll
    for (int mt = 0; mt < 3; mt++)
      af[mt] = *(const short8*)&xS[(mt * 16 + lr) * XSTR + kt * 32 + lg * 8];
#pragma unroll
    for (int ntl = 0; ntl < 2; ntl++) {
      long tf = (long)(kt * 8 + 2 * w + ntl) * 512 + l * 8;
      short8 b0 = *(const short8*)&WQ[tf];
      short8 b1 = *(const short8*)&WK[tf];
      short8 b2 = *(const short8*)&WV[tf];
#pragma unroll
      for (int mt = 0; mt < 3; mt++) {
        accq[mt][ntl] = __builtin_amdgcn_mfma_f32_16x16x32_bf16(af[mt], b0, accq[mt][ntl], 0, 0, 0);
        acck[mt][ntl] = __builtin_amdgcn_mfma_f32_16x16x32_bf16(af[mt], b1, acck[mt][ntl], 0, 0, 0);
        accv[mt][ntl] = __builtin_amdgcn_mfma_f32_16x16x32_bf16(af[mt], b2, accv[mt][ntl], 0, 0, 0);
      }
    }
  }

  // epilogue: +bias, store bf16 into per-wave q/k/v LDS regions
  {
    unsigned short* qw = &qS[w * 48 * QSTR];
    unsigned short* kw = &kS[w * 48 * QSTR];
    unsigned short* vw = &vS[w * 48 * QSTR];
    float bqv[2] = {bq[32 * w + lr], bq[32 * w + 16 + lr]};
    float bkv[2] = {bk[32 * w + lr], bk[32 * w + 16 + lr]};
    float bvv[2] = {bv[32 * w + lr], bv[32 * w + 16 + lr]};
#pragma unroll
    for (int mt = 0; mt < 3; mt++)
#pragma unroll
      for (int ntl = 0; ntl < 2; ntl++)
#pragma unroll
        for (int i = 0; i < 4; i++) {
          int row = mt * 16 + lg * 4 + i;
          int col = ntl * 16 + lr;
          qw[row * QSTR + col] = f2bf(accq[mt][ntl][i] + bqv[ntl]);
          kw[row * QSTR + col] = f2bf(acck[mt][ntl][i] + bkv[ntl]);
          vw[row * QSTR + col] = f2bf(accv[mt][ntl][i] + bvv[ntl]);
        }
  }
  __syncthreads();

  // ---- attention (wave-local: head w) ----
  {
    const unsigned short* qw = &qS[w * 48 * QSTR];
    const unsigned short* kw = &kS[w * 48 * QSTR];
    const unsigned short* vw = &vS[w * 48 * QSTR];
    const int hh = l >> 5;      // half-wave
    const int d = l & 31;       // dim within head
    const float scale = 0.17677669529663687f;  // 1/sqrt(32)
#pragma unroll
    for (int i = 0; i < 8; i++) {
      int nd = hh * 8 + i;
      float qv[3], kv[3], vv[3];
#pragma unroll
      for (int a = 0; a < 3; a++) {
        qv[a] = bf2f(qw[(3 * nd + a) * QSTR + d]);
        kv[a] = bf2f(kw[(3 * nd + a) * QSTR + d]);
        vv[a] = bf2f(vw[(3 * nd + a) * QSTR + d]);
      }
      float sc[3][3];
#pragma unroll
      for (int aq = 0; aq < 3; aq++)
#pragma unroll
        for (int ak = 0; ak < 3; ak++) {
          float p = qv[aq] * kv[ak];
          p += __shfl_xor(p, 16, 64);
          p += __shfl_xor(p, 8, 64);
          p += __shfl_xor(p, 4, 64);
          p += __shfl_xor(p, 2, 64);
          p += __shfl_xor(p, 1, 64);
          sc[aq][ak] = p * scale;
        }
#pragma unroll
      for (int aq = 0; aq < 3; aq++) {
        float mx = fmaxf(sc[aq][0], fmaxf(sc[aq][1], sc[aq][2]));
        float e0 = expf(sc[aq][0] - mx);
        float e1 = expf(sc[aq][1] - mx);
        float e2 = expf(sc[aq][2] - mx);
        float inv = 1.0f / (e0 + e1 + e2);
        float o = (e0 * vv[0] + e1 * vv[1] + e2 * vv[2]) * inv;
        oS[(3 * nd + aq) * XSTR + 32 * w + d] = f2bf(o);
      }
    }
  }
  __syncthreads();

  // ---- hI = agg + O @ Wo + bo ----
  v4f acco[3][2];
#pragma unroll
  for (int mt = 0; mt < 3; mt++)
#pragma unroll
    for (int n = 0; n < 2; n++) acco[mt][n] = (v4f){0.f, 0.f, 0.f, 0.f};

#pragma unroll
  for (int kt = 0; kt < 4; kt++) {
    short8 af[3];
#pragma unroll
    for (int mt = 0; mt < 3; mt++)
      af[mt] = *(const short8*)&oS[(mt * 16 + lr) * XSTR + kt * 32 + lg * 8];
#pragma unroll
    for (int ntl = 0; ntl < 2; ntl++) {
      long tf = (long)(kt * 8 + 2 * w + ntl) * 512 + l * 8;
      short8 b = *(const short8*)&WO[tf];
#pragma unroll
      for (int mt = 0; mt < 3; mt++)
        acco[mt][ntl] = __builtin_amdgcn_mfma_f32_16x16x32_bf16(af[mt], b, acco[mt][ntl], 0, 0, 0);
    }
  }

  {
    float bov[2] = {bo[32 * w + lr], bo[32 * w + 16 + lr]};
#pragma unroll
    for (int mt = 0; mt < 3; mt++)
#pragma unroll
      for (int ntl = 0; ntl < 2; ntl++)
#pragma unroll
        for (int i = 0; i < 4; i++) {
          int row = mt * 16 + lg * 4 + i;
          int gcol = 32 * w + ntl * 16 + lr;
          float res = bf2f(xS[row * XSTR + gcol]);
          OUT[(node0 * 3 + row) * 128 + gcol] = acco[mt][ntl][i] + bov[ntl] + res;
        }
  }
}

// ---------------------------------------------------------------------------
// Final: threefry noise + sample activations + logp sum
// ---------------------------------------------------------------------------
__global__ __launch_bounds__(256) void final_out(
    const float* __restrict__ MU, float* __restrict__ out0, float* __restrict__ out1) {
  const int tid = threadIdx.x;
  const int t = tid & 63;
  const long bn = (long)blockIdx.x * 4 + (tid >> 6);
  const bool act = (t < 48);
  const long gidx = bn * 48 + t;
  float sample = 0.f, lp = 0.f;
  if (act) {
    unsigned bits = jax_random_bits32((unsigned)gidx);
    float noise = jax_normal_from_bits(bits);
    sample = MU[gidx] + noise;
    lp = -0.9189385332046727f - 0.5f * noise * noise;
  }
  float s = lp;
  s += __shfl_xor(s, 32, 64);
  s += __shfl_xor(s, 16, 64);
  s += __shfl_xor(s, 8, 64);
  s += __shfl_xor(s, 4, 64);
  s += __shfl_xor(s, 2, 64);
  s += __shfl_xor(s, 1, 64);
  if (t == 0) out1[bn] = s;

  if (t < 16) {
    float th = tanhf(sample);
    float mx = th;
    mx = fmaxf(mx, __shfl_xor(mx, 8, 64));
    mx = fmaxf(mx, __shfl_xor(mx, 4, 64));
    mx = fmaxf(mx, __shfl_xor(mx, 2, 64));
    mx = fmaxf(mx, __shfl_xor(mx, 1, 64));
    float ex = expf(th - mx);
    float ss = ex;
    ss += __shfl_xor(ss, 8, 64);
    ss += __shfl_xor(ss, 4, 64);
    ss += __shfl_xor(ss, 2, 64);
    ss += __shfl_xor(ss, 1, 64);
    out0[gidx] = ex / ss;
  } else if (t < 32) {
    out0[gidx] = 1.0f / (1.0f + expf(-sample));
  } else if (t < 48) {
    out0[gidx] = tanhf(sample);
  }
}

// ---------------------------------------------------------------------------
extern "C" void kernel_launch(void* const* d_in, const int* in_sizes, int n_in,
                              void* d_out, int out_size, void* d_ws, size_t ws_size,
                              hipStream_t stream) {
  const float* x = (const float*)d_in[0];
  const int* ei = (const int*)d_in[1];
  const float* W1 = (const float*)d_in[2];
  const float* b1 = (const float*)d_in[3];
  const float* W2 = (const float*)d_in[4];
  const float* b2 = (const float*)d_in[5];
  const float* Wq = (const float*)d_in[6];
  const float* bq = (const float*)d_in[7];
  const float* Wk = (const float*)d_in[8];
  const float* bk = (const float*)d_in[9];
  const float* Wv = (const float*)d_in[10];
  const float* bv = (const float*)d_in[11];
  const float* Wo = (const float*)d_in[12];
  const float* bo = (const float*)d_in[13];
  const float* mW1 = (const float*)d_in[14];
  const float* mb1 = (const float*)d_in[15];
  const float* mW2 = (const float*)d_in[16];
  const float* mb2 = (const float*)d_in[17];
  (void)in_sizes; (void)n_in; (void)out_size; (void)ws_size;

  float* bufA = (float*)d_ws;              // 12,582,912 floats (B*N*A*H)
  float* bufB = bufA + 12582912;
  float* bufC = bufB + 12582912;           // 1,572,864 (mu)
  int* deg = (int*)(bufC + 1572864);       // 16384
  int* offs = deg + NN;                    // 16385
  int* cur = offs + (NN + 1);              // 16384
  int* csr = cur + NN;                     // 262144
  unsigned short* wfrag = (unsigned short*)(((uintptr_t)(csr + EE) + 15) & ~(uintptr_t)15);

  const int* dst = ei;
  const int* srcv = ei + EE;

  float* out0 = (float*)d_out;
  float* out1 = out0 + TOT_NOISE;

  // CSR build + weight prep
  hipMemsetAsync(deg, 0, NN * sizeof(int), stream);
  edge_count<<<EE / 256, 256, 0, stream>>>(dst, deg);
  scan_k<<<1, 256, 0, stream>>>(deg, offs, cur);
  edge_fill<<<EE / 256, 256, 0, stream>>>(dst, srcv, cur, csr);
  prep_wfrag4<<<dim3(64, 4), 256, 0, stream>>>(Wq, Wk, Wv, Wo, wfrag);

  dim3 g128(BNODES / 128, 3);
  gemm_a128<<<g128, 256, 0, stream>>>(x, 128, 0, W1, 16384, b1, 128, bufA, AH, 128, 1);
  gemm_a128<<<g128, 256, 0, stream>>>(bufA, AH, 128, W2, 16384, b2, 128, bufB, AH, 128, 0);
  aggregate<<<BNODES, 128, 0, stream>>>(bufB, offs, csr, bufA);
  attn_mfma<<<BNODES / 16, 256, 0, stream>>>(bufA, wfrag, bq, bk, bv, bo, bufA);
  gemm_a128<<<g128, 256, 0, stream>>>(bufA, AH, 128, mW1, 16384, mb1, 128, bufB, AH, 128, 1);
  gemm_a16<<<dim3(BNODES / 64, 3), 256, 0, stream>>>(bufB, AH, 128, mW2, 2048, mb2, 16, bufC, 48, 16);
  final_out<<<BNODES / 4, 256, 0, stream>>>(bufC, out0, out1);
}

// Round 3
// 354.758 us; speedup vs baseline: 1.8972x; 1.3831x over previous
//
#include <hip/hip_runtime.h>

// Problem constants
#define NN    16384      // N nodes
#define EE    262144     // edges
#define BNODES 32768     // B*N
#define AH    384        // A*H
#define TOT_NOISE 1572864u

typedef __attribute__((ext_vector_type(8))) short short8;
typedef __attribute__((ext_vector_type(4))) float v4f;

__device__ __forceinline__ unsigned short f2bf(float f) {
  unsigned u = __float_as_uint(f);
  unsigned r = u + 0x7fffu + ((u >> 16) & 1u);
  return (unsigned short)(r >> 16);
}
__device__ __forceinline__ float bf2f(unsigned short h) {
  return __uint_as_float(((unsigned)h) << 16);
}

// ---------------------------------------------------------------------------
// Threefry-2x32, keys = (0, 42)  [jax.random.key(42)]
// ---------------------------------------------------------------------------
__device__ __forceinline__ void threefry2x32_042(unsigned& x0, unsigned& x1) {
  const unsigned ks0 = 0u;
  const unsigned ks1 = 42u;
  const unsigned ks2 = 0x1BD11BDAu ^ 0u ^ 42u;
  x0 += ks0; x1 += ks1;
#define TFR(r) { x0 += x1; x1 = (x1 << (r)) | (x1 >> (32 - (r))); x1 ^= x0; }
  TFR(13) TFR(15) TFR(26) TFR(6)   x0 += ks1; x1 += ks2 + 1u;
  TFR(17) TFR(29) TFR(16) TFR(24)  x0 += ks2; x1 += ks0 + 2u;
  TFR(13) TFR(15) TFR(26) TFR(6)   x0 += ks0; x1 += ks1 + 3u;
  TFR(17) TFR(29) TFR(16) TFR(24)  x0 += ks1; x1 += ks2 + 4u;
  TFR(13) TFR(15) TFR(26) TFR(6)   x0 += ks2; x1 += ks0 + 5u;
#undef TFR
}

// XLA ErfInv32 (Giles) polynomial
__device__ __forceinline__ float erfinv_f32(float x) {
  float w = -log1pf(-x * x);
  float p;
  if (w < 5.0f) {
    w -= 2.5f;
    p = 2.81022636e-08f;
    p = fmaf(p, w, 3.43273939e-07f);
    p = fmaf(p, w, -3.5233877e-06f);
    p = fmaf(p, w, -4.39150654e-06f);
    p = fmaf(p, w, 0.00021858087f);
    p = fmaf(p, w, -0.00125372503f);
    p = fmaf(p, w, -0.00417768164f);
    p = fmaf(p, w, 0.246640727f);
    p = fmaf(p, w, 1.50140941f);
  } else {
    w = sqrtf(w) - 3.0f;
    p = -0.000200214257f;
    p = fmaf(p, w, 0.000100950558f);
    p = fmaf(p, w, 0.00134934322f);
    p = fmaf(p, w, -0.00367342844f);
    p = fmaf(p, w, 0.00573950773f);
    p = fmaf(p, w, -0.0076224613f);
    p = fmaf(p, w, 0.00943887047f);
    p = fmaf(p, w, 1.00167406f);
    p = fmaf(p, w, 2.83297682f);
  }
  return p * x;
}

__device__ __forceinline__ unsigned jax_random_bits32(unsigned i) {
  unsigned x0 = 0u, x1 = i;
  threefry2x32_042(x0, x1);
  return x0 ^ x1;
}

__device__ __forceinline__ float jax_normal_from_bits(unsigned bits) {
  float f = __uint_as_float((bits >> 9) | 0x3f800000u) - 1.0f;  // [0,1)
  const float lo = -0.99999994f;                                 // nextafter(-1,0)
  float u = f * 2.0f + lo;
  u = fmaxf(u, lo);
  return 1.4142135623730951f * erfinv_f32(u);
}

// ---------------------------------------------------------------------------
// x -> bf16 convert
// ---------------------------------------------------------------------------
__global__ __launch_bounds__(256) void cvt_x(const float* __restrict__ x,
                                             unsigned short* __restrict__ xb) {
  int i = (blockIdx.x * 256 + threadIdx.x) * 4;
  float4 v = *(const float4*)(x + i);
  unsigned lo = (unsigned)f2bf(v.x) | ((unsigned)f2bf(v.y) << 16);
  unsigned hi = (unsigned)f2bf(v.z) | ((unsigned)f2bf(v.w) << 16);
  *(uint2*)(&xb[i]) = make_uint2(lo, hi);
}

// ---------------------------------------------------------------------------
// CSR build
// ---------------------------------------------------------------------------
__global__ void edge_count(const int* __restrict__ dst, int* __restrict__ deg) {
  int e = blockIdx.x * 256 + threadIdx.x;
  if (e < EE) atomicAdd(&deg[dst[e]], 1);
}

__global__ __launch_bounds__(256) void scan_k(const int* __restrict__ deg,
                                              int* __restrict__ offs,
                                              int* __restrict__ cur) {
  __shared__ int part[256];
  int t = threadIdx.x;
  int base = t * 64;
  int s = 0;
  for (int i = 0; i < 64; i++) s += deg[base + i];
  part[t] = s;
  __syncthreads();
  for (int off = 1; off < 256; off <<= 1) {
    int v = (t >= off) ? part[t - off] : 0;
    __syncthreads();
    part[t] += v;
    __syncthreads();
  }
  int run = (t == 0) ? 0 : part[t - 1];
  for (int i = 0; i < 64; i++) {
    offs[base + i] = run;
    cur[base + i] = run;
    run += deg[base + i];
  }
  if (t == 255) offs[NN] = run;
}

__global__ void edge_fill(const int* __restrict__ dst, const int* __restrict__ srcv,
                          int* __restrict__ cur, int* __restrict__ csr) {
  int e = blockIdx.x * 256 + threadIdx.x;
  if (e < EE) {
    int d = dst[e];
    int p = atomicAdd(&cur[d], 1);
    csr[p] = srcv[e];
  }
}

// ---------------------------------------------------------------------------
// Weight prep: 13 slots of 128x128 fp32 [k][n] -> bf16 MFMA B-fragment layout
//   frag[f], f = (kt*8+nt)*512 + lane*8 + j <-> W[kt*32+(lane>>4)*8+j][nt*16+(lane&15)]
// slots 0-2: W1[a]; 3-5: W2[a]; 6-8: mu_W1[a]; 9:Wq 10:Wk 11:Wv 12:Wo
// ---------------------------------------------------------------------------
__global__ __launch_bounds__(256) void prep_wfrag(
    const float* __restrict__ W1, const float* __restrict__ W2,
    const float* __restrict__ mW1,
    const float* __restrict__ Wq, const float* __restrict__ Wk,
    const float* __restrict__ Wv, const float* __restrict__ Wo,
    unsigned short* __restrict__ F) {
  int m = blockIdx.y;
  const float* W;
  if (m < 3) W = W1 + (long)m * 16384;
  else if (m < 6) W = W2 + (long)(m - 3) * 16384;
  else if (m < 9) W = mW1 + (long)(m - 6) * 16384;
  else W = (m == 9) ? Wq : (m == 10) ? Wk : (m == 11) ? Wv : Wo;
  int f = blockIdx.x * 256 + threadIdx.x;
  int tile = f >> 9;
  int kt = tile >> 3, nt = tile & 7;
  int r = f & 511;
  int lane = r >> 3, j = r & 7;
  int k = kt * 32 + (lane >> 4) * 8 + j;
  int n = nt * 16 + (lane & 15);
  F[(long)m * 16384 + f] = f2bf(W[k * 128 + n]);
}

// ---------------------------------------------------------------------------
// bf16 MFMA GEMM: per-a 128(N)x128(K), M tile 128, 256 threads (4 waves).
// Wave w owns output cols [32w, 32w+32). C written in bf16.
// ---------------------------------------------------------------------------
#define GXSTR 136
__global__ __launch_bounds__(256) void gemm_bf16(
    const unsigned short* __restrict__ X, long xRowStride, long xAOff,
    const unsigned short* __restrict__ WF,
    const float* __restrict__ Bias, long bAStride,
    unsigned short* __restrict__ C, long cRowStride, long cAOff,
    int relu) {
  __shared__ __align__(16) unsigned short As[128 * GXSTR];
  const int a = blockIdx.y;
  const long m0 = (long)blockIdx.x * 128;
  const int tid = threadIdx.x;
  const unsigned short* Xp = X + (long)a * xAOff + m0 * xRowStride;
  const unsigned short* Wp = WF + (long)a * 16384;

  // stage A tile: 128x128 bf16 = 2048 16B chunks
#pragma unroll
  for (int p = 0; p < 8; p++) {
    int c = tid + p * 256;
    int row = c >> 4, c8 = (c & 15) * 8;
    short8 v = *(const short8*)(Xp + (long)row * xRowStride + c8);
    *(short8*)(&As[row * GXSTR + c8]) = v;
  }
  __syncthreads();

  const int w = tid >> 6;
  const int l = tid & 63;
  const int lr = l & 15;
  const int lg = l >> 4;

  v4f acc[8][2];
#pragma unroll
  for (int mt = 0; mt < 8; mt++) {
    acc[mt][0] = (v4f){0.f, 0.f, 0.f, 0.f};
    acc[mt][1] = (v4f){0.f, 0.f, 0.f, 0.f};
  }

#pragma unroll
  for (int kt = 0; kt < 4; kt++) {
    short8 bfr[2];
#pragma unroll
    for (int ntl = 0; ntl < 2; ntl++)
      bfr[ntl] = *(const short8*)(Wp + (long)(kt * 8 + 2 * w + ntl) * 512 + l * 8);
#pragma unroll
    for (int mt = 0; mt < 8; mt++) {
      short8 af = *(const short8*)(&As[(mt * 16 + lr) * GXSTR + kt * 32 + lg * 8]);
      acc[mt][0] = __builtin_amdgcn_mfma_f32_16x16x32_bf16(af, bfr[0], acc[mt][0], 0, 0, 0);
      acc[mt][1] = __builtin_amdgcn_mfma_f32_16x16x32_bf16(af, bfr[1], acc[mt][1], 0, 0, 0);
    }
  }

  float bv[2] = {Bias[(long)a * bAStride + 32 * w + lr],
                 Bias[(long)a * bAStride + 32 * w + 16 + lr]};
#pragma unroll
  for (int mt = 0; mt < 8; mt++)
#pragma unroll
    for (int ntl = 0; ntl < 2; ntl++)
#pragma unroll
      for (int i = 0; i < 4; i++) {
        long row = m0 + mt * 16 + lg * 4 + i;
        int col = 32 * w + ntl * 16 + lr;
        float t = acc[mt][ntl][i] + bv[ntl];
        if (relu) t = fmaxf(t, 0.0f);
        C[row * cRowStride + (long)a * cAOff + col] = f2bf(t);
      }
}

// ---------------------------------------------------------------------------
// Small GEMM for mu_W2: N=16, K=128, per-a; bf16 X input, fp32 out
// ---------------------------------------------------------------------------
__global__ __launch_bounds__(256) void gemm_a16(
    const unsigned short* __restrict__ X, long xRowStride, long xAOff,
    const float* __restrict__ W, long wAStride,
    const float* __restrict__ Bias, long bAStride,
    float* __restrict__ C, long cRowStride, long cAOff) {
  __shared__ float Xs[64 * 132];
  __shared__ float Ws[128 * 16];
  const int a = blockIdx.y;
  const long m0 = (long)blockIdx.x * 64;
  const int tid = threadIdx.x;
  const unsigned short* Xp = X + (long)a * xAOff;
  const float* Wp = W + (long)a * wAStride;

  for (int i = tid; i < 64 * 32; i += 256) {
    int r = i >> 5, c4 = (i & 31) << 2;
    uint2 v = *(const uint2*)(Xp + (m0 + r) * xRowStride + c4);
    Xs[r * 132 + c4 + 0] = __uint_as_float(v.x << 16);
    Xs[r * 132 + c4 + 1] = __uint_as_float(v.x & 0xffff0000u);
    Xs[r * 132 + c4 + 2] = __uint_as_float(v.y << 16);
    Xs[r * 132 + c4 + 3] = __uint_as_float(v.y & 0xffff0000u);
  }
  for (int i = tid; i < 512; i += 256) {
    int r = i >> 2, c4 = (i & 3) << 2;
    *(float4*)(&Ws[r * 16 + c4]) = *(const float4*)(Wp + r * 16 + c4);
  }
  __syncthreads();

  const int c = tid & 15;
  const int rg = tid >> 4;
  float acc[4] = {0.f, 0.f, 0.f, 0.f};
  for (int k = 0; k < 128; k++) {
    float w = Ws[k * 16 + c];
#pragma unroll
    for (int i = 0; i < 4; i++) acc[i] += Xs[(rg * 4 + i) * 132 + k] * w;
  }
  float b = Bias[(long)a * bAStride + c];
#pragma unroll
  for (int i = 0; i < 4; i++) {
    long row = m0 + rg * 4 + i;
    C[row * cRowStride + (long)a * cAOff + c] = acc[i] + b;
  }
}

// ---------------------------------------------------------------------------
// Segment-sum aggregation (bf16 gather, fp32 accumulate, bf16 out)
// 192 threads: thread t covers cols [2t, 2t+1] of the 384-wide row
// ---------------------------------------------------------------------------
__global__ __launch_bounds__(192) void aggregate_bf(
    const unsigned short* __restrict__ H, const int* __restrict__ offs,
    const int* __restrict__ csr, unsigned short* __restrict__ AGB) {
  const int bn = blockIdx.x;
  const int b = bn >> 14;
  const int n = bn & (NN - 1);
  const int tid = threadIdx.x;
  const int e0 = offs[n], e1 = offs[n + 1];
  const unsigned short* hb = H + (long)b * NN * 384 + tid * 2;
  float a0 = 0.f, a1 = 0.f;
  for (int j = e0; j < e1; j++) {
    int s = csr[j];
    unsigned v = *(const unsigned*)(hb + (long)s * 384);
    a0 += __uint_as_float(v << 16);
    a1 += __uint_as_float(v & 0xffff0000u);
  }
  unsigned out = (unsigned)f2bf(a0) | ((unsigned)f2bf(a1) << 16);
  *(unsigned*)(AGB + (long)bn * 384 + tid * 2) = out;
}

// ---------------------------------------------------------------------------
// Fused MFMA attention: 16 nodes/block (M=48 rows), 256 threads (4 waves).
// Wave w owns cols [32w,32w+32) == head w. Input agg bf16; output hI bf16.
// ---------------------------------------------------------------------------
#define XSTR 136
#define QSTR 34
__global__ __launch_bounds__(256, 2) void attn_mfma(
    const unsigned short* __restrict__ AGB, const unsigned short* __restrict__ WF,
    const float* __restrict__ bq, const float* __restrict__ bk,
    const float* __restrict__ bv, const float* __restrict__ bo,
    unsigned short* __restrict__ OUTB) {
  __shared__ __align__(16) unsigned short xS[48 * XSTR];
  __shared__ __align__(16) unsigned short qS[4 * 48 * QSTR];
  __shared__ __align__(16) unsigned short kS[4 * 48 * QSTR];
  __shared__ __align__(16) unsigned short vS[4 * 48 * QSTR];
  __shared__ __align__(16) unsigned short oS[48 * XSTR];

  const int tid = threadIdx.x;
  const long node0 = (long)blockIdx.x * 16;
  const unsigned short* src = AGB + node0 * 384;

  // stage agg tile: 48x128 bf16 = 768 16B chunks (src contiguous)
#pragma unroll
  for (int p = 0; p < 3; p++) {
    int c = tid + p * 256;
    int row = c >> 4, c8 = (c & 15) * 8;
    short8 v = *(const short8*)(src + c * 8);
    *(short8*)(&xS[row * XSTR + c8]) = v;
  }
  __syncthreads();

  const int w = tid >> 6;
  const int l = tid & 63;
  const int lr = l & 15;
  const int lg = l >> 4;
  const unsigned short* WQ = WF;
  const unsigned short* WK = WF + 16384;
  const unsigned short* WV = WF + 32768;
  const unsigned short* WO = WF + 49152;

  // ---- QKV projections via MFMA ----
  v4f accq[3][2], acck[3][2], accv[3][2];
#pragma unroll
  for (int mt = 0; mt < 3; mt++)
#pragma unroll
    for (int n = 0; n < 2; n++) {
      accq[mt][n] = (v4f){0.f, 0.f, 0.f, 0.f};
      acck[mt][n] = (v4f){0.f, 0.f, 0.f, 0.f};
      accv[mt][n] = (v4f){0.f, 0.f, 0.f, 0.f};
    }

#pragma unroll
  for (int kt = 0; kt < 4; kt++) {
    short8 af[3];
#pragma unroll
    for (int mt = 0; mt < 3; mt++)
      af[mt] = *(const short8*)&xS[(mt * 16 + lr) * XSTR + kt * 32 + lg * 8];
#pragma unroll
    for (int ntl = 0; ntl < 2; ntl++) {
      long tf = (long)(kt * 8 + 2 * w + ntl) * 512 + l * 8;
      short8 b0 = *(const short8*)&WQ[tf];
      short8 b1 = *(const short8*)&WK[tf];
      short8 b2 = *(const short8*)&WV[tf];
#pragma unroll
      for (int mt = 0; mt < 3; mt++) {
        accq[mt][ntl] = __builtin_amdgcn_mfma_f32_16x16x32_bf16(af[mt], b0, accq[mt][ntl], 0, 0, 0);
        acck[mt][ntl] = __builtin_amdgcn_mfma_f32_16x16x32_bf16(af[mt], b1, acck[mt][ntl], 0, 0, 0);
        accv[mt][ntl] = __builtin_amdgcn_mfma_f32_16x16x32_bf16(af[mt], b2, accv[mt][ntl], 0, 0, 0);
      }
    }
  }

  {
    unsigned short* qw = &qS[w * 48 * QSTR];
    unsigned short* kw = &kS[w * 48 * QSTR];
    unsigned short* vw = &vS[w * 48 * QSTR];
    float bqv[2] = {bq[32 * w + lr], bq[32 * w + 16 + lr]};
    float bkv[2] = {bk[32 * w + lr], bk[32 * w + 16 + lr]};
    float bvv[2] = {bv[32 * w + lr], bv[32 * w + 16 + lr]};
#pragma unroll
    for (int mt = 0; mt < 3; mt++)
#pragma unroll
      for (int ntl = 0; ntl < 2; ntl++)
#pragma unroll
        for (int i = 0; i < 4; i++) {
          int row = mt * 16 + lg * 4 + i;
          int col = ntl * 16 + lr;
          qw[row * QSTR + col] = f2bf(accq[mt][ntl][i] + bqv[ntl]);
          kw[row * QSTR + col] = f2bf(acck[mt][ntl][i] + bkv[ntl]);
          vw[row * QSTR + col] = f2bf(accv[mt][ntl][i] + bvv[ntl]);
        }
  }
  __syncthreads();

  // ---- attention (wave-local: head w) ----
  {
    const unsigned short* qw = &qS[w * 48 * QSTR];
    const unsigned short* kw = &kS[w * 48 * QSTR];
    const unsigned short* vw = &vS[w * 48 * QSTR];
    const int hh = l >> 5;
    const int d = l & 31;
    const float scale = 0.17677669529663687f;
#pragma unroll
    for (int i = 0; i < 8; i++) {
      int nd = hh * 8 + i;
      float qv[3], kv[3], vv[3];
#pragma unroll
      for (int a = 0; a < 3; a++) {
        qv[a] = bf2f(qw[(3 * nd + a) * QSTR + d]);
        kv[a] = bf2f(kw[(3 * nd + a) * QSTR + d]);
        vv[a] = bf2f(vw[(3 * nd + a) * QSTR + d]);
      }
      float sc[3][3];
#pragma unroll
      for (int aq = 0; aq < 3; aq++)
#pragma unroll
        for (int ak = 0; ak < 3; ak++) {
          float p = qv[aq] * kv[ak];
          p += __shfl_xor(p, 16, 64);
          p += __shfl_xor(p, 8, 64);
          p += __shfl_xor(p, 4, 64);
          p += __shfl_xor(p, 2, 64);
          p += __shfl_xor(p, 1, 64);
          sc[aq][ak] = p * scale;
        }
#pragma unroll
      for (int aq = 0; aq < 3; aq++) {
        float mx = fmaxf(sc[aq][0], fmaxf(sc[aq][1], sc[aq][2]));
        float e0 = expf(sc[aq][0] - mx);
        float e1 = expf(sc[aq][1] - mx);
        float e2 = expf(sc[aq][2] - mx);
        float inv = 1.0f / (e0 + e1 + e2);
        float o = (e0 * vv[0] + e1 * vv[1] + e2 * vv[2]) * inv;
        oS[(3 * nd + aq) * XSTR + 32 * w + d] = f2bf(o);
      }
    }
  }
  __syncthreads();

  // ---- hI = agg + O @ Wo + bo (bf16 out) ----
  v4f acco[3][2];
#pragma unroll
  for (int mt = 0; mt < 3; mt++)
#pragma unroll
    for (int n = 0; n < 2; n++) acco[mt][n] = (v4f){0.f, 0.f, 0.f, 0.f};

#pragma unroll
  for (int kt = 0; kt < 4; kt++) {
    short8 af[3];
#pragma unroll
    for (int mt = 0; mt < 3; mt++)
      af[mt] = *(const short8*)&oS[(mt * 16 + lr) * XSTR + kt * 32 + lg * 8];
#pragma unroll
    for (int ntl = 0; ntl < 2; ntl++) {
      long tf = (long)(kt * 8 + 2 * w + ntl) * 512 + l * 8;
      short8 b = *(const short8*)&WO[tf];
#pragma unroll
      for (int mt = 0; mt < 3; mt++)
        acco[mt][ntl] = __builtin_amdgcn_mfma_f32_16x16x32_bf16(af[mt], b, acco[mt][ntl], 0, 0, 0);
    }
  }

  {
    float bov[2] = {bo[32 * w + lr], bo[32 * w + 16 + lr]};
#pragma unroll
    for (int mt = 0; mt < 3; mt++)
#pragma unroll
      for (int ntl = 0; ntl < 2; ntl++)
#pragma unroll
        for (int i = 0; i < 4; i++) {
          int row = mt * 16 + lg * 4 + i;
          int gcol = 32 * w + ntl * 16 + lr;
          float res = bf2f(xS[row * XSTR + gcol]);
          OUTB[(node0 * 3 + row) * 128 + gcol] = f2bf(acco[mt][ntl][i] + bov[ntl] + res);
        }
  }
}

// ---------------------------------------------------------------------------
// Final: threefry noise + sample activations + logp sum
// ---------------------------------------------------------------------------
__global__ __launch_bounds__(256) void final_out(
    const float* __restrict__ MU, float* __restrict__ out0, float* __restrict__ out1) {
  const int tid = threadIdx.x;
  const int t = tid & 63;
  const long bn = (long)blockIdx.x * 4 + (tid >> 6);
  const bool act = (t < 48);
  const long gidx = bn * 48 + t;
  float sample = 0.f, lp = 0.f;
  if (act) {
    unsigned bits = jax_random_bits32((unsigned)gidx);
    float noise = jax_normal_from_bits(bits);
    sample = MU[gidx] + noise;
    lp = -0.9189385332046727f - 0.5f * noise * noise;
  }
  float s = lp;
  s += __shfl_xor(s, 32, 64);
  s += __shfl_xor(s, 16, 64);
  s += __shfl_xor(s, 8, 64);
  s += __shfl_xor(s, 4, 64);
  s += __shfl_xor(s, 2, 64);
  s += __shfl_xor(s, 1, 64);
  if (t == 0) out1[bn] = s;

  if (t < 16) {
    float th = tanhf(sample);
    float mx = th;
    mx = fmaxf(mx, __shfl_xor(mx, 8, 64));
    mx = fmaxf(mx, __shfl_xor(mx, 4, 64));
    mx = fmaxf(mx, __shfl_xor(mx, 2, 64));
    mx = fmaxf(mx, __shfl_xor(mx, 1, 64));
    float ex = expf(th - mx);
    float ss = ex;
    ss += __shfl_xor(ss, 8, 64);
    ss += __shfl_xor(ss, 4, 64);
    ss += __shfl_xor(ss, 2, 64);
    ss += __shfl_xor(ss, 1, 64);
    out0[gidx] = ex / ss;
  } else if (t < 32) {
    out0[gidx] = 1.0f / (1.0f + expf(-sample));
  } else if (t < 48) {
    out0[gidx] = tanhf(sample);
  }
}

// ---------------------------------------------------------------------------
extern "C" void kernel_launch(void* const* d_in, const int* in_sizes, int n_in,
                              void* d_out, int out_size, void* d_ws, size_t ws_size,
                              hipStream_t stream) {
  const float* x = (const float*)d_in[0];
  const int* ei = (const int*)d_in[1];
  const float* W1 = (const float*)d_in[2];
  const float* b1 = (const float*)d_in[3];
  const float* W2 = (const float*)d_in[4];
  const float* b2 = (const float*)d_in[5];
  const float* Wq = (const float*)d_in[6];
  const float* bq = (const float*)d_in[7];
  const float* Wk = (const float*)d_in[8];
  const float* bk = (const float*)d_in[9];
  const float* Wv = (const float*)d_in[10];
  const float* bv = (const float*)d_in[11];
  const float* Wo = (const float*)d_in[12];
  const float* bo = (const float*)d_in[13];
  const float* mW1 = (const float*)d_in[14];
  const float* mb1 = (const float*)d_in[15];
  const float* mW2 = (const float*)d_in[16];
  const float* mb2 = (const float*)d_in[17];
  (void)in_sizes; (void)n_in; (void)out_size; (void)ws_size;

  unsigned short* XB = (unsigned short*)d_ws;     // 4,194,304 (x bf16)
  unsigned short* T1 = XB + 4194304;               // 12,582,912 (t1, later hI)
  unsigned short* HB = T1 + 12582912;              // 12,582,912 (h, later m)
  unsigned short* AGB = HB + 12582912;             // 12,582,912 (agg bf16)
  float* MU = (float*)(AGB + 12582912);            // 1,572,864 fp32
  int* deg = (int*)(MU + 1572864);                 // 16384
  int* offs = deg + NN;                            // 16385
  int* cur = offs + (NN + 1);                      // 16384
  int* csr = cur + NN;                             // 262144
  unsigned short* wfrag = (unsigned short*)(((uintptr_t)(csr + EE) + 15) & ~(uintptr_t)15);

  const int* dst = ei;
  const int* srcv = ei + EE;

  float* out0 = (float*)d_out;
  float* out1 = out0 + TOT_NOISE;

  // prep: x->bf16, CSR, weight fragments
  cvt_x<<<4096, 256, 0, stream>>>(x, XB);
  hipMemsetAsync(deg, 0, NN * sizeof(int), stream);
  edge_count<<<EE / 256, 256, 0, stream>>>(dst, deg);
  scan_k<<<1, 256, 0, stream>>>(deg, offs, cur);
  edge_fill<<<EE / 256, 256, 0, stream>>>(dst, srcv, cur, csr);
  prep_wfrag<<<dim3(64, 13), 256, 0, stream>>>(W1, W2, mW1, Wq, Wk, Wv, Wo, wfrag);

  dim3 g128(BNODES / 128, 3);
  // t1 = relu(x @ W1[a] + b1[a])
  gemm_bf16<<<g128, 256, 0, stream>>>(XB, 128, 0, wfrag, b1, 128, T1, AH, 128, 1);
  // h = t1 @ W2[a] + b2[a]
  gemm_bf16<<<g128, 256, 0, stream>>>(T1, AH, 128, wfrag + 3 * 16384, b2, 128, HB, AH, 128, 0);
  // agg = segment_sum(h[src] -> dst)
  aggregate_bf<<<BNODES, 192, 0, stream>>>(HB, offs, csr, AGB);
  // attention + hI (bf16 out into T1)
  attn_mfma<<<BNODES / 16, 256, 0, stream>>>(AGB, wfrag + 9 * 16384, bq, bk, bv, bo, T1);
  // m = relu(hI @ mu_W1[a] + mu_b1[a])  (into HB)
  gemm_bf16<<<g128, 256, 0, stream>>>(T1, AH, 128, wfrag + 6 * 16384, mb1, 128, HB, AH, 128, 1);
  // mu = m @ mu_W2[a] + mu_b2[a]
  gemm_a16<<<dim3(BNODES / 64, 3), 256, 0, stream>>>(HB, AH, 128, mW2, 2048, mb2, 16, MU, 48, 16);
  // noise + activations + logp
  final_out<<<BNODES / 4, 256, 0, stream>>>(MU, out0, out1);
}

// Round 4
// 309.707 us; speedup vs baseline: 2.1732x; 1.1455x over previous
//
#include <hip/hip_runtime.h>

// Problem constants
#define NN    16384      // N nodes
#define EE    262144     // edges
#define BNODES 32768     // B*N
#define AH    384        // A*H
#define TOT_NOISE 1572864u

typedef __attribute__((ext_vector_type(8))) short short8;
typedef __attribute__((ext_vector_type(4))) float v4f;

__device__ __forceinline__ unsigned short f2bf(float f) {
  unsigned u = __float_as_uint(f);
  unsigned r = u + 0x7fffu + ((u >> 16) & 1u);
  return (unsigned short)(r >> 16);
}
__device__ __forceinline__ float bf2f(unsigned short h) {
  return __uint_as_float(((unsigned)h) << 16);
}
__device__ __forceinline__ float bflo(unsigned u) { return __uint_as_float(u << 16); }
__device__ __forceinline__ float bfhi(unsigned u) { return __uint_as_float(u & 0xffff0000u); }

// ---------------------------------------------------------------------------
// Threefry-2x32, keys = (0, 42)
// ---------------------------------------------------------------------------
__device__ __forceinline__ void threefry2x32_042(unsigned& x0, unsigned& x1) {
  const unsigned ks0 = 0u;
  const unsigned ks1 = 42u;
  const unsigned ks2 = 0x1BD11BDAu ^ 0u ^ 42u;
  x0 += ks0; x1 += ks1;
#define TFR(r) { x0 += x1; x1 = (x1 << (r)) | (x1 >> (32 - (r))); x1 ^= x0; }
  TFR(13) TFR(15) TFR(26) TFR(6)   x0 += ks1; x1 += ks2 + 1u;
  TFR(17) TFR(29) TFR(16) TFR(24)  x0 += ks2; x1 += ks0 + 2u;
  TFR(13) TFR(15) TFR(26) TFR(6)   x0 += ks0; x1 += ks1 + 3u;
  TFR(17) TFR(29) TFR(16) TFR(24)  x0 += ks1; x1 += ks2 + 4u;
  TFR(13) TFR(15) TFR(26) TFR(6)   x0 += ks2; x1 += ks0 + 5u;
#undef TFR
}

// XLA ErfInv32 (Giles) polynomial
__device__ __forceinline__ float erfinv_f32(float x) {
  float w = -log1pf(-x * x);
  float p;
  if (w < 5.0f) {
    w -= 2.5f;
    p = 2.81022636e-08f;
    p = fmaf(p, w, 3.43273939e-07f);
    p = fmaf(p, w, -3.5233877e-06f);
    p = fmaf(p, w, -4.39150654e-06f);
    p = fmaf(p, w, 0.00021858087f);
    p = fmaf(p, w, -0.00125372503f);
    p = fmaf(p, w, -0.00417768164f);
    p = fmaf(p, w, 0.246640727f);
    p = fmaf(p, w, 1.50140941f);
  } else {
    w = sqrtf(w) - 3.0f;
    p = -0.000200214257f;
    p = fmaf(p, w, 0.000100950558f);
    p = fmaf(p, w, 0.00134934322f);
    p = fmaf(p, w, -0.00367342844f);
    p = fmaf(p, w, 0.00573950773f);
    p = fmaf(p, w, -0.0076224613f);
    p = fmaf(p, w, 0.00943887047f);
    p = fmaf(p, w, 1.00167406f);
    p = fmaf(p, w, 2.83297682f);
  }
  return p * x;
}

__device__ __forceinline__ unsigned jax_random_bits32(unsigned i) {
  unsigned x0 = 0u, x1 = i;
  threefry2x32_042(x0, x1);
  return x0 ^ x1;
}

__device__ __forceinline__ float jax_normal_from_bits(unsigned bits) {
  float f = __uint_as_float((bits >> 9) | 0x3f800000u) - 1.0f;  // [0,1)
  const float lo = -0.99999994f;                                 // nextafter(-1,0)
  float u = f * 2.0f + lo;
  u = fmaxf(u, lo);
  return 1.4142135623730951f * erfinv_f32(u);
}

// ---------------------------------------------------------------------------
// CSR build
// ---------------------------------------------------------------------------
__global__ void edge_count(const int* __restrict__ dst, int* __restrict__ deg) {
  int e = blockIdx.x * 256 + threadIdx.x;
  if (e < EE) atomicAdd(&deg[dst[e]], 1);
}

__global__ __launch_bounds__(256) void scan_k(const int* __restrict__ deg,
                                              int* __restrict__ offs,
                                              int* __restrict__ cur) {
  __shared__ int part[256];
  int t = threadIdx.x;
  int base = t * 64;
  int s = 0;
  for (int i = 0; i < 64; i++) s += deg[base + i];
  part[t] = s;
  __syncthreads();
  for (int off = 1; off < 256; off <<= 1) {
    int v = (t >= off) ? part[t - off] : 0;
    __syncthreads();
    part[t] += v;
    __syncthreads();
  }
  int run = (t == 0) ? 0 : part[t - 1];
  for (int i = 0; i < 64; i++) {
    offs[base + i] = run;
    cur[base + i] = run;
    run += deg[base + i];
  }
  if (t == 255) offs[NN] = run;
}

__global__ void edge_fill(const int* __restrict__ dst, const int* __restrict__ srcv,
                          int* __restrict__ cur, int* __restrict__ csr) {
  int e = blockIdx.x * 256 + threadIdx.x;
  if (e < EE) {
    int d = dst[e];
    int p = atomicAdd(&cur[d], 1);
    csr[p] = srcv[e];
  }
}

// ---------------------------------------------------------------------------
// Weight prep: 13 slots of 128x128 fp32 [k][n] -> bf16 MFMA B-fragment layout
// slots 0-2: W1[a]; 3-5: W2[a]; 6-8: mu_W1[a]; 9:Wq 10:Wk 11:Wv 12:Wo
// ---------------------------------------------------------------------------
__global__ __launch_bounds__(256) void prep_wfrag(
    const float* __restrict__ W1, const float* __restrict__ W2,
    const float* __restrict__ mW1,
    const float* __restrict__ Wq, const float* __restrict__ Wk,
    const float* __restrict__ Wv, const float* __restrict__ Wo,
    unsigned short* __restrict__ F) {
  int m = blockIdx.y;
  const float* W;
  if (m < 3) W = W1 + (long)m * 16384;
  else if (m < 6) W = W2 + (long)(m - 3) * 16384;
  else if (m < 9) W = mW1 + (long)(m - 6) * 16384;
  else W = (m == 9) ? Wq : (m == 10) ? Wk : (m == 11) ? Wv : Wo;
  int f = blockIdx.x * 256 + threadIdx.x;
  int tile = f >> 9;
  int kt = tile >> 3, nt = tile & 7;
  int r = f & 511;
  int lane = r >> 3, j = r & 7;
  int k = kt * 32 + (lane >> 4) * 8 + j;
  int n = nt * 16 + (lane & 15);
  F[(long)m * 16384 + f] = f2bf(W[k * 128 + n]);
}

// mu_W2 (A x 128 x 16) -> B-fragment layout, 3 slots of 2048
__global__ __launch_bounds__(256) void prep_w2frag(
    const float* __restrict__ mW2, unsigned short* __restrict__ F2) {
  int a = blockIdx.y;
  int f = blockIdx.x * 256 + threadIdx.x;  // 0..2047
  int kt = f >> 9;
  int r = f & 511;
  int lane = r >> 3, j = r & 7;
  int k = kt * 32 + (lane >> 4) * 8 + j;
  int n = lane & 15;
  F2[a * 2048 + f] = f2bf(mW2[(a * 128 + k) * 16 + n]);
}

// ---------------------------------------------------------------------------
// bf16 MFMA GEMM: per-a 128(N)x128(K), M tile 128, 256 threads (4 waves).
// xfp32: X is fp32 (converted during LDS staging).
// ---------------------------------------------------------------------------
#define GXSTR 136
__global__ __launch_bounds__(256) void gemm_bf16(
    const unsigned short* __restrict__ X, long xRowStride, long xAOff,
    const unsigned short* __restrict__ WF,
    const float* __restrict__ Bias, long bAStride,
    unsigned short* __restrict__ C, long cRowStride, long cAOff,
    int relu, int xfp32) {
  __shared__ __align__(16) unsigned short As[128 * GXSTR];
  const int a = blockIdx.y;
  const long m0 = (long)blockIdx.x * 128;
  const int tid = threadIdx.x;
  const unsigned short* Wp = WF + (long)a * 16384;

  if (xfp32) {
    const float* Xf = (const float*)X + (long)a * xAOff + m0 * xRowStride;
#pragma unroll
    for (int p = 0; p < 8; p++) {
      int c = tid + p * 256;
      int row = c >> 4, c8 = (c & 15) * 8;
      float4 v1 = *(const float4*)(Xf + (long)row * xRowStride + c8);
      float4 v2 = *(const float4*)(Xf + (long)row * xRowStride + c8 + 4);
      short8 o;
      o[0] = (short)f2bf(v1.x); o[1] = (short)f2bf(v1.y);
      o[2] = (short)f2bf(v1.z); o[3] = (short)f2bf(v1.w);
      o[4] = (short)f2bf(v2.x); o[5] = (short)f2bf(v2.y);
      o[6] = (short)f2bf(v2.z); o[7] = (short)f2bf(v2.w);
      *(short8*)(&As[row * GXSTR + c8]) = o;
    }
  } else {
    const unsigned short* Xp = X + (long)a * xAOff + m0 * xRowStride;
#pragma unroll
    for (int p = 0; p < 8; p++) {
      int c = tid + p * 256;
      int row = c >> 4, c8 = (c & 15) * 8;
      short8 v = *(const short8*)(Xp + (long)row * xRowStride + c8);
      *(short8*)(&As[row * GXSTR + c8]) = v;
    }
  }
  __syncthreads();

  const int w = tid >> 6;
  const int l = tid & 63;
  const int lr = l & 15;
  const int lg = l >> 4;

  v4f acc[8][2];
#pragma unroll
  for (int mt = 0; mt < 8; mt++) {
    acc[mt][0] = (v4f){0.f, 0.f, 0.f, 0.f};
    acc[mt][1] = (v4f){0.f, 0.f, 0.f, 0.f};
  }

#pragma unroll
  for (int kt = 0; kt < 4; kt++) {
    short8 bfr[2];
#pragma unroll
    for (int ntl = 0; ntl < 2; ntl++)
      bfr[ntl] = *(const short8*)(Wp + (long)(kt * 8 + 2 * w + ntl) * 512 + l * 8);
#pragma unroll
    for (int mt = 0; mt < 8; mt++) {
      short8 af = *(const short8*)(&As[(mt * 16 + lr) * GXSTR + kt * 32 + lg * 8]);
      acc[mt][0] = __builtin_amdgcn_mfma_f32_16x16x32_bf16(af, bfr[0], acc[mt][0], 0, 0, 0);
      acc[mt][1] = __builtin_amdgcn_mfma_f32_16x16x32_bf16(af, bfr[1], acc[mt][1], 0, 0, 0);
    }
  }

  float bv[2] = {Bias[(long)a * bAStride + 32 * w + lr],
                 Bias[(long)a * bAStride + 32 * w + 16 + lr]};
#pragma unroll
  for (int mt = 0; mt < 8; mt++)
#pragma unroll
    for (int ntl = 0; ntl < 2; ntl++)
#pragma unroll
      for (int i = 0; i < 4; i++) {
        long row = m0 + mt * 16 + lg * 4 + i;
        int col = 32 * w + ntl * 16 + lr;
        float t = acc[mt][ntl][i] + bv[ntl];
        if (relu) t = fmaxf(t, 0.0f);
        C[row * cRowStride + (long)a * cAOff + col] = f2bf(t);
      }
}

// ---------------------------------------------------------------------------
// Segment-sum aggregation: one block per node n, both batches.
// 192 threads = {batch 0|1} x 96 cols of dwordx2 (4 bf16 each).
// Edge loop unrolled x4 -> 4 outstanding 8B loads per thread.
// ---------------------------------------------------------------------------
__global__ __launch_bounds__(192) void aggregate_bf2(
    const unsigned short* __restrict__ H, const int* __restrict__ offs,
    const int* __restrict__ csr, unsigned short* __restrict__ AGB) {
  const int n = blockIdx.x;
  const int t = threadIdx.x;
  const int bt = t / 96;
  const int c = (t % 96) * 4;
  const int e0 = offs[n], e1 = offs[n + 1];
  const unsigned short* hb = H + (long)bt * NN * 384 + c;
  float a0 = 0.f, a1 = 0.f, a2 = 0.f, a3 = 0.f;
  int j = e0;
  for (; j + 4 <= e1; j += 4) {
    int s0 = csr[j], s1 = csr[j + 1], s2 = csr[j + 2], s3 = csr[j + 3];
    uint2 u0 = *(const uint2*)(hb + (long)s0 * 384);
    uint2 u1 = *(const uint2*)(hb + (long)s1 * 384);
    uint2 u2 = *(const uint2*)(hb + (long)s2 * 384);
    uint2 u3 = *(const uint2*)(hb + (long)s3 * 384);
    a0 += bflo(u0.x); a1 += bfhi(u0.x); a2 += bflo(u0.y); a3 += bfhi(u0.y);
    a0 += bflo(u1.x); a1 += bfhi(u1.x); a2 += bflo(u1.y); a3 += bfhi(u1.y);
    a0 += bflo(u2.x); a1 += bfhi(u2.x); a2 += bflo(u2.y); a3 += bfhi(u2.y);
    a0 += bflo(u3.x); a1 += bfhi(u3.x); a2 += bflo(u3.y); a3 += bfhi(u3.y);
  }
  for (; j < e1; j++) {
    int s = csr[j];
    uint2 u = *(const uint2*)(hb + (long)s * 384);
    a0 += bflo(u.x); a1 += bfhi(u.x); a2 += bflo(u.y); a3 += bfhi(u.y);
  }
  uint2 out;
  out.x = (unsigned)f2bf(a0) | ((unsigned)f2bf(a1) << 16);
  out.y = (unsigned)f2bf(a2) | ((unsigned)f2bf(a3) << 16);
  *(uint2*)(AGB + ((long)bt * NN + n) * 384 + c) = out;
}

// ---------------------------------------------------------------------------
// Fused MFMA attention (unchanged from R3)
// ---------------------------------------------------------------------------
#define XSTR 136
#define QSTR 34
__global__ __launch_bounds__(256, 2) void attn_mfma(
    const unsigned short* __restrict__ AGB, const unsigned short* __restrict__ WF,
    const float* __restrict__ bq, const float* __restrict__ bk,
    const float* __restrict__ bv, const float* __restrict__ bo,
    unsigned short* __restrict__ OUTB) {
  __shared__ __align__(16) unsigned short xS[48 * XSTR];
  __shared__ __align__(16) unsigned short qS[4 * 48 * QSTR];
  __shared__ __align__(16) unsigned short kS[4 * 48 * QSTR];
  __shared__ __align__(16) unsigned short vS[4 * 48 * QSTR];
  __shared__ __align__(16) unsigned short oS[48 * XSTR];

  const int tid = threadIdx.x;
  const long node0 = (long)blockIdx.x * 16;
  const unsigned short* src = AGB + node0 * 384;

#pragma unroll
  for (int p = 0; p < 3; p++) {
    int c = tid + p * 256;
    int row = c >> 4, c8 = (c & 15) * 8;
    short8 v = *(const short8*)(src + c * 8);
    *(short8*)(&xS[row * XSTR + c8]) = v;
  }
  __syncthreads();

  const int w = tid >> 6;
  const int l = tid & 63;
  const int lr = l & 15;
  const int lg = l >> 4;
  const unsigned short* WQ = WF;
  const unsigned short* WK = WF + 16384;
  const unsigned short* WV = WF + 32768;
  const unsigned short* WO = WF + 49152;

  v4f accq[3][2], acck[3][2], accv[3][2];
#pragma unroll
  for (int mt = 0; mt < 3; mt++)
#pragma unroll
    for (int n = 0; n < 2; n++) {
      accq[mt][n] = (v4f){0.f, 0.f, 0.f, 0.f};
      acck[mt][n] = (v4f){0.f, 0.f, 0.f, 0.f};
      accv[mt][n] = (v4f){0.f, 0.f, 0.f, 0.f};
    }

#pragma unroll
  for (int kt = 0; kt < 4; kt++) {
    short8 af[3];
#pragma unroll
    for (int mt = 0; mt < 3; mt++)
      af[mt] = *(const short8*)&xS[(mt * 16 + lr) * XSTR + kt * 32 + lg * 8];
#pragma unroll
    for (int ntl = 0; ntl < 2; ntl++) {
      long tf = (long)(kt * 8 + 2 * w + ntl) * 512 + l * 8;
      short8 b0 = *(const short8*)&WQ[tf];
      short8 b1 = *(const short8*)&WK[tf];
      short8 b2 = *(const short8*)&WV[tf];
#pragma unroll
      for (int mt = 0; mt < 3; mt++) {
        accq[mt][ntl] = __builtin_amdgcn_mfma_f32_16x16x32_bf16(af[mt], b0, accq[mt][ntl], 0, 0, 0);
        acck[mt][ntl] = __builtin_amdgcn_mfma_f32_16x16x32_bf16(af[mt], b1, acck[mt][ntl], 0, 0, 0);
        accv[mt][ntl] = __builtin_amdgcn_mfma_f32_16x16x32_bf16(af[mt], b2, accv[mt][ntl], 0, 0, 0);
      }
    }
  }

  {
    unsigned short* qw = &qS[w * 48 * QSTR];
    unsigned short* kw = &kS[w * 48 * QSTR];
    unsigned short* vw = &vS[w * 48 * QSTR];
    float bqv[2] = {bq[32 * w + lr], bq[32 * w + 16 + lr]};
    float bkv[2] = {bk[32 * w + lr], bk[32 * w + 16 + lr]};
    float bvv[2] = {bv[32 * w + lr], bv[32 * w + 16 + lr]};
#pragma unroll
    for (int mt = 0; mt < 3; mt++)
#pragma unroll
      for (int ntl = 0; ntl < 2; ntl++)
#pragma unroll
        for (int i = 0; i < 4; i++) {
          int row = mt * 16 + lg * 4 + i;
          int col = ntl * 16 + lr;
          qw[row * QSTR + col] = f2bf(accq[mt][ntl][i] + bqv[ntl]);
          kw[row * QSTR + col] = f2bf(acck[mt][ntl][i] + bkv[ntl]);
          vw[row * QSTR + col] = f2bf(accv[mt][ntl][i] + bvv[ntl]);
        }
  }
  __syncthreads();

  {
    const unsigned short* qw = &qS[w * 48 * QSTR];
    const unsigned short* kw = &kS[w * 48 * QSTR];
    const unsigned short* vw = &vS[w * 48 * QSTR];
    const int hh = l >> 5;
    const int d = l & 31;
    const float scale = 0.17677669529663687f;
#pragma unroll
    for (int i = 0; i < 8; i++) {
      int nd = hh * 8 + i;
      float qv[3], kv[3], vv[3];
#pragma unroll
      for (int a = 0; a < 3; a++) {
        qv[a] = bf2f(qw[(3 * nd + a) * QSTR + d]);
        kv[a] = bf2f(kw[(3 * nd + a) * QSTR + d]);
        vv[a] = bf2f(vw[(3 * nd + a) * QSTR + d]);
      }
      float sc[3][3];
#pragma unroll
      for (int aq = 0; aq < 3; aq++)
#pragma unroll
        for (int ak = 0; ak < 3; ak++) {
          float p = qv[aq] * kv[ak];
          p += __shfl_xor(p, 16, 64);
          p += __shfl_xor(p, 8, 64);
          p += __shfl_xor(p, 4, 64);
          p += __shfl_xor(p, 2, 64);
          p += __shfl_xor(p, 1, 64);
          sc[aq][ak] = p * scale;
        }
#pragma unroll
      for (int aq = 0; aq < 3; aq++) {
        float mx = fmaxf(sc[aq][0], fmaxf(sc[aq][1], sc[aq][2]));
        float e0 = expf(sc[aq][0] - mx);
        float e1 = expf(sc[aq][1] - mx);
        float e2 = expf(sc[aq][2] - mx);
        float inv = 1.0f / (e0 + e1 + e2);
        float o = (e0 * vv[0] + e1 * vv[1] + e2 * vv[2]) * inv;
        oS[(3 * nd + aq) * XSTR + 32 * w + d] = f2bf(o);
      }
    }
  }
  __syncthreads();

  v4f acco[3][2];
#pragma unroll
  for (int mt = 0; mt < 3; mt++)
#pragma unroll
    for (int n = 0; n < 2; n++) acco[mt][n] = (v4f){0.f, 0.f, 0.f, 0.f};

#pragma unroll
  for (int kt = 0; kt < 4; kt++) {
    short8 af[3];
#pragma unroll
    for (int mt = 0; mt < 3; mt++)
      af[mt] = *(const short8*)&oS[(mt * 16 + lr) * XSTR + kt * 32 + lg * 8];
#pragma unroll
    for (int ntl = 0; ntl < 2; ntl++) {
      long tf = (long)(kt * 8 + 2 * w + ntl) * 512 + l * 8;
      short8 b = *(const short8*)&WO[tf];
#pragma unroll
      for (int mt = 0; mt < 3; mt++)
        acco[mt][ntl] = __builtin_amdgcn_mfma_f32_16x16x32_bf16(af[mt], b, acco[mt][ntl], 0, 0, 0);
    }
  }

  {
    float bov[2] = {bo[32 * w + lr], bo[32 * w + 16 + lr]};
#pragma unroll
    for (int mt = 0; mt < 3; mt++)
#pragma unroll
      for (int ntl = 0; ntl < 2; ntl++)
#pragma unroll
        for (int i = 0; i < 4; i++) {
          int row = mt * 16 + lg * 4 + i;
          int gcol = 32 * w + ntl * 16 + lr;
          float res = bf2f(xS[row * XSTR + gcol]);
          OUTB[(node0 * 3 + row) * 128 + gcol] = f2bf(acco[mt][ntl][i] + bov[ntl] + res);
        }
  }
}

// ---------------------------------------------------------------------------
// Fused mu-GEMM (N=16, MFMA) + noise + activations + logp.
// Block: 256 threads, 64 nodes. Rows ordered a*64+node -> 12 M-tiles of 16.
// Wave w handles tiles 3w..3w+2. C layout: f = lane&15, node-sub = lg*4+i.
// ---------------------------------------------------------------------------
#define MSTR 136
__global__ __launch_bounds__(256) void mu_final(
    const unsigned short* __restrict__ M, const unsigned short* __restrict__ WF2,
    const float* __restrict__ mb2,
    float* __restrict__ out0, float* __restrict__ out1) {
  __shared__ __align__(16) unsigned short As[192 * MSTR];
  __shared__ float lpS[192];
  const int tid = threadIdx.x;
  const long bn0 = (long)blockIdx.x * 64;

  // stage m: 64 nodes x (3a x 128k) -> rows a*64+nd
#pragma unroll
  for (int p = 0; p < 12; p++) {
    int ch = tid + p * 256;           // 0..3071
    int nd = ch / 48;
    int rest = ch % 48;
    int a = rest >> 4;
    int k8 = (rest & 15) * 8;
    short8 v = *(const short8*)(M + (bn0 + nd) * 384 + a * 128 + k8);
    *(short8*)(&As[(a * 64 + nd) * MSTR + k8]) = v;
  }
  __syncthreads();

  const int w = tid >> 6, l = tid & 63, lr = l & 15, lg = l >> 4;

  v4f acc[3];
#pragma unroll
  for (int t = 0; t < 3; t++) acc[t] = (v4f){0.f, 0.f, 0.f, 0.f};

#pragma unroll
  for (int kt = 0; kt < 4; kt++) {
#pragma unroll
    for (int t = 0; t < 3; t++) {
      int tile = 3 * w + t;
      int a = tile >> 2;
      short8 af = *(const short8*)(&As[(tile * 16 + lr) * MSTR + kt * 32 + lg * 8]);
      short8 bf = *(const short8*)(WF2 + a * 2048 + kt * 512 + l * 8);
      acc[t] = __builtin_amdgcn_mfma_f32_16x16x32_bf16(af, bf, acc[t], 0, 0, 0);
    }
  }

#pragma unroll
  for (int t = 0; t < 3; t++) {
    int tile = 3 * w + t;
    int a = tile >> 2;
    int ndbase = (tile & 3) * 16;
    float bias = mb2[a * 16 + lr];
#pragma unroll
    for (int i = 0; i < 4; i++) {
      int nd = ndbase + lg * 4 + i;
      float mu = acc[t][i] + bias;
      unsigned gidx = (unsigned)((bn0 + nd) * 48 + a * 16 + lr);
      unsigned bits = jax_random_bits32(gidx);
      float noise = jax_normal_from_bits(bits);
      float sample = mu + noise;
      float lp = -0.9189385332046727f - 0.5f * noise * noise;
      lp += __shfl_xor(lp, 1, 64);
      lp += __shfl_xor(lp, 2, 64);
      lp += __shfl_xor(lp, 4, 64);
      lp += __shfl_xor(lp, 8, 64);
      if (lr == 0) lpS[a * 64 + nd] = lp;
      float res;
      if (a == 0) {
        float th = tanhf(sample);
        float mx = th;
        mx = fmaxf(mx, __shfl_xor(mx, 1, 64));
        mx = fmaxf(mx, __shfl_xor(mx, 2, 64));
        mx = fmaxf(mx, __shfl_xor(mx, 4, 64));
        mx = fmaxf(mx, __shfl_xor(mx, 8, 64));
        float ex = expf(th - mx);
        float ss = ex;
        ss += __shfl_xor(ss, 1, 64);
        ss += __shfl_xor(ss, 2, 64);
        ss += __shfl_xor(ss, 4, 64);
        ss += __shfl_xor(ss, 8, 64);
        res = ex / ss;
      } else if (a == 1) {
        res = 1.0f / (1.0f + expf(-sample));
      } else {
        res = tanhf(sample);
      }
      out0[gidx] = res;
    }
  }
  __syncthreads();
  if (tid < 64)
    out1[bn0 + tid] = lpS[tid] + lpS[64 + tid] + lpS[128 + tid];
}

// ---------------------------------------------------------------------------
extern "C" void kernel_launch(void* const* d_in, const int* in_sizes, int n_in,
                              void* d_out, int out_size, void* d_ws, size_t ws_size,
                              hipStream_t stream) {
  const float* x = (const float*)d_in[0];
  const int* ei = (const int*)d_in[1];
  const float* W1 = (const float*)d_in[2];
  const float* b1 = (const float*)d_in[3];
  const float* W2 = (const float*)d_in[4];
  const float* b2 = (const float*)d_in[5];
  const float* Wq = (const float*)d_in[6];
  const float* bq = (const float*)d_in[7];
  const float* Wk = (const float*)d_in[8];
  const float* bk = (const float*)d_in[9];
  const float* Wv = (const float*)d_in[10];
  const float* bv = (const float*)d_in[11];
  const float* Wo = (const float*)d_in[12];
  const float* bo = (const float*)d_in[13];
  const float* mW1 = (const float*)d_in[14];
  const float* mb1 = (const float*)d_in[15];
  const float* mW2 = (const float*)d_in[16];
  const float* mb2 = (const float*)d_in[17];
  (void)in_sizes; (void)n_in; (void)out_size; (void)ws_size;

  unsigned short* T1 = (unsigned short*)d_ws;      // 12,582,912 (t1, later hI)
  unsigned short* HB = T1 + 12582912;              // 12,582,912 (h, later m)
  unsigned short* AGB = HB + 12582912;             // 12,582,912 (agg bf16)
  int* deg = (int*)(AGB + 12582912);               // 16384
  int* offs = deg + NN;                            // 16385
  int* cur = offs + (NN + 1);                      // 16384
  int* csr = cur + NN;                             // 262144
  unsigned short* wfrag = (unsigned short*)(((uintptr_t)(csr + EE) + 15) & ~(uintptr_t)15);
  unsigned short* w2frag = wfrag + 13 * 16384;     // 3*2048

  const int* dst = ei;
  const int* srcv = ei + EE;

  float* out0 = (float*)d_out;
  float* out1 = out0 + TOT_NOISE;

  hipMemsetAsync(deg, 0, NN * sizeof(int), stream);
  edge_count<<<EE / 256, 256, 0, stream>>>(dst, deg);
  scan_k<<<1, 256, 0, stream>>>(deg, offs, cur);
  edge_fill<<<EE / 256, 256, 0, stream>>>(dst, srcv, cur, csr);
  prep_wfrag<<<dim3(64, 13), 256, 0, stream>>>(W1, W2, mW1, Wq, Wk, Wv, Wo, wfrag);
  prep_w2frag<<<dim3(8, 3), 256, 0, stream>>>(mW2, w2frag);

  dim3 g128(BNODES / 128, 3);
  // t1 = relu(x @ W1[a] + b1[a])   (x fp32 converted in staging)
  gemm_bf16<<<g128, 256, 0, stream>>>((const unsigned short*)x, 128, 0, wfrag, b1, 128, T1, AH, 128, 1, 1);
  // h = t1 @ W2[a] + b2[a]
  gemm_bf16<<<g128, 256, 0, stream>>>(T1, AH, 128, wfrag + 3 * 16384, b2, 128, HB, AH, 128, 0, 0);
  // agg = segment_sum(h[src] -> dst)
  aggregate_bf2<<<NN, 192, 0, stream>>>(HB, offs, csr, AGB);
  // attention + hI (bf16 out into T1)
  attn_mfma<<<BNODES / 16, 256, 0, stream>>>(AGB, wfrag + 9 * 16384, bq, bk, bv, bo, T1);
  // m = relu(hI @ mu_W1[a] + mu_b1[a])  (into HB)
  gemm_bf16<<<g128, 256, 0, stream>>>(T1, AH, 128, wfrag + 6 * 16384, mb1, 128, HB, AH, 128, 1, 0);
  // mu + noise + activations + logp (fused)
  mu_final<<<BNODES / 64, 256, 0, stream>>>(HB, w2frag, mb2, out0, out1);
}

// Round 5
// 277.314 us; speedup vs baseline: 2.4271x; 1.1168x over previous
//
#include <hip/hip_runtime.h>

// Problem constants
#define NN    16384      // N nodes
#define EE    262144     // edges
#define BNODES 32768     // B*N
#define AH    384        // A*H
#define TOT_NOISE 1572864u

typedef __attribute__((ext_vector_type(8))) short short8;
typedef __attribute__((ext_vector_type(4))) float v4f;

__device__ __forceinline__ unsigned short f2bf(float f) {
  unsigned u = __float_as_uint(f);
  unsigned r = u + 0x7fffu + ((u >> 16) & 1u);
  return (unsigned short)(r >> 16);
}
__device__ __forceinline__ float bf2f(unsigned short h) {
  return __uint_as_float(((unsigned)h) << 16);
}
__device__ __forceinline__ float bflo(unsigned u) { return __uint_as_float(u << 16); }
__device__ __forceinline__ float bfhi(unsigned u) { return __uint_as_float(u & 0xffff0000u); }

// ---------------------------------------------------------------------------
// Threefry-2x32, keys = (0, 42)
// ---------------------------------------------------------------------------
__device__ __forceinline__ void threefry2x32_042(unsigned& x0, unsigned& x1) {
  const unsigned ks0 = 0u;
  const unsigned ks1 = 42u;
  const unsigned ks2 = 0x1BD11BDAu ^ 0u ^ 42u;
  x0 += ks0; x1 += ks1;
#define TFR(r) { x0 += x1; x1 = (x1 << (r)) | (x1 >> (32 - (r))); x1 ^= x0; }
  TFR(13) TFR(15) TFR(26) TFR(6)   x0 += ks1; x1 += ks2 + 1u;
  TFR(17) TFR(29) TFR(16) TFR(24)  x0 += ks2; x1 += ks0 + 2u;
  TFR(13) TFR(15) TFR(26) TFR(6)   x0 += ks0; x1 += ks1 + 3u;
  TFR(17) TFR(29) TFR(16) TFR(24)  x0 += ks1; x1 += ks2 + 4u;
  TFR(13) TFR(15) TFR(26) TFR(6)   x0 += ks2; x1 += ks0 + 5u;
#undef TFR
}

// XLA ErfInv32 (Giles) polynomial
__device__ __forceinline__ float erfinv_f32(float x) {
  float w = -log1pf(-x * x);
  float p;
  if (w < 5.0f) {
    w -= 2.5f;
    p = 2.81022636e-08f;
    p = fmaf(p, w, 3.43273939e-07f);
    p = fmaf(p, w, -3.5233877e-06f);
    p = fmaf(p, w, -4.39150654e-06f);
    p = fmaf(p, w, 0.00021858087f);
    p = fmaf(p, w, -0.00125372503f);
    p = fmaf(p, w, -0.00417768164f);
    p = fmaf(p, w, 0.246640727f);
    p = fmaf(p, w, 1.50140941f);
  } else {
    w = sqrtf(w) - 3.0f;
    p = -0.000200214257f;
    p = fmaf(p, w, 0.000100950558f);
    p = fmaf(p, w, 0.00134934322f);
    p = fmaf(p, w, -0.00367342844f);
    p = fmaf(p, w, 0.00573950773f);
    p = fmaf(p, w, -0.0076224613f);
    p = fmaf(p, w, 0.00943887047f);
    p = fmaf(p, w, 1.00167406f);
    p = fmaf(p, w, 2.83297682f);
  }
  return p * x;
}

__device__ __forceinline__ unsigned jax_random_bits32(unsigned i) {
  unsigned x0 = 0u, x1 = i;
  threefry2x32_042(x0, x1);
  return x0 ^ x1;
}

__device__ __forceinline__ float jax_normal_from_bits(unsigned bits) {
  float f = __uint_as_float((bits >> 9) | 0x3f800000u) - 1.0f;  // [0,1)
  const float lo = -0.99999994f;                                 // nextafter(-1,0)
  float u = f * 2.0f + lo;
  u = fmaxf(u, lo);
  return 1.4142135623730951f * erfinv_f32(u);
}

// ---------------------------------------------------------------------------
// CSR build
// ---------------------------------------------------------------------------
__global__ void edge_count(const int* __restrict__ dst, int* __restrict__ deg) {
  int e = blockIdx.x * 256 + threadIdx.x;
  if (e < EE) atomicAdd(&deg[dst[e]], 1);
}

__global__ __launch_bounds__(256) void scan_k(const int* __restrict__ deg,
                                              int* __restrict__ offs,
                                              int* __restrict__ cur) {
  __shared__ int part[256];
  int t = threadIdx.x;
  int base = t * 64;
  int s = 0;
  for (int i = 0; i < 64; i++) s += deg[base + i];
  part[t] = s;
  __syncthreads();
  for (int off = 1; off < 256; off <<= 1) {
    int v = (t >= off) ? part[t - off] : 0;
    __syncthreads();
    part[t] += v;
    __syncthreads();
  }
  int run = (t == 0) ? 0 : part[t - 1];
  for (int i = 0; i < 64; i++) {
    offs[base + i] = run;
    cur[base + i] = run;
    run += deg[base + i];
  }
  if (t == 255) offs[NN] = run;
}

__global__ void edge_fill(const int* __restrict__ dst, const int* __restrict__ srcv,
                          int* __restrict__ cur, int* __restrict__ csr) {
  int e = blockIdx.x * 256 + threadIdx.x;
  if (e < EE) {
    int d = dst[e];
    int p = atomicAdd(&cur[d], 1);
    csr[p] = srcv[e];
  }
}

// ---------------------------------------------------------------------------
// Weight prep: 13 slots of 128x128 fp32 [k][n] -> bf16 MFMA B-fragment layout
// slots 0-2: W1[a]; 3-5: W2[a]; 6-8: mu_W1[a]; 9:Wq 10:Wk 11:Wv 12:Wo
// ---------------------------------------------------------------------------
__global__ __launch_bounds__(256) void prep_wfrag(
    const float* __restrict__ W1, const float* __restrict__ W2,
    const float* __restrict__ mW1,
    const float* __restrict__ Wq, const float* __restrict__ Wk,
    const float* __restrict__ Wv, const float* __restrict__ Wo,
    unsigned short* __restrict__ F) {
  int m = blockIdx.y;
  const float* W;
  if (m < 3) W = W1 + (long)m * 16384;
  else if (m < 6) W = W2 + (long)(m - 3) * 16384;
  else if (m < 9) W = mW1 + (long)(m - 6) * 16384;
  else W = (m == 9) ? Wq : (m == 10) ? Wk : (m == 11) ? Wv : Wo;
  int f = blockIdx.x * 256 + threadIdx.x;
  int tile = f >> 9;
  int kt = tile >> 3, nt = tile & 7;
  int r = f & 511;
  int lane = r >> 3, j = r & 7;
  int k = kt * 32 + (lane >> 4) * 8 + j;
  int n = nt * 16 + (lane & 15);
  F[(long)m * 16384 + f] = f2bf(W[k * 128 + n]);
}

// mu_W2 (A x 128 x 16) -> B-fragment layout, 3 slots of 2048
__global__ __launch_bounds__(256) void prep_w2frag(
    const float* __restrict__ mW2, unsigned short* __restrict__ F2) {
  int a = blockIdx.y;
  int f = blockIdx.x * 256 + threadIdx.x;  // 0..2047
  int kt = f >> 9;
  int r = f & 511;
  int lane = r >> 3, j = r & 7;
  int k = kt * 32 + (lane >> 4) * 8 + j;
  int n = lane & 15;
  F2[a * 2048 + f] = f2bf(mW2[(a * 128 + k) * 16 + n]);
}

// ---------------------------------------------------------------------------
// bf16 MFMA GEMM: per-a 128(N)x128(K), M tile 128, 256 threads (4 waves).
// xfp32: X is fp32 (converted during LDS staging).
// ---------------------------------------------------------------------------
#define GXSTR 136
__global__ __launch_bounds__(256) void gemm_bf16(
    const unsigned short* __restrict__ X, long xRowStride, long xAOff,
    const unsigned short* __restrict__ WF,
    const float* __restrict__ Bias, long bAStride,
    unsigned short* __restrict__ C, long cRowStride, long cAOff,
    int relu, int xfp32) {
  __shared__ __align__(16) unsigned short As[128 * GXSTR];
  const int a = blockIdx.y;
  const long m0 = (long)blockIdx.x * 128;
  const int tid = threadIdx.x;
  const unsigned short* Wp = WF + (long)a * 16384;

  if (xfp32) {
    const float* Xf = (const float*)X + (long)a * xAOff + m0 * xRowStride;
#pragma unroll
    for (int p = 0; p < 8; p++) {
      int c = tid + p * 256;
      int row = c >> 4, c8 = (c & 15) * 8;
      float4 v1 = *(const float4*)(Xf + (long)row * xRowStride + c8);
      float4 v2 = *(const float4*)(Xf + (long)row * xRowStride + c8 + 4);
      short8 o;
      o[0] = (short)f2bf(v1.x); o[1] = (short)f2bf(v1.y);
      o[2] = (short)f2bf(v1.z); o[3] = (short)f2bf(v1.w);
      o[4] = (short)f2bf(v2.x); o[5] = (short)f2bf(v2.y);
      o[6] = (short)f2bf(v2.z); o[7] = (short)f2bf(v2.w);
      *(short8*)(&As[row * GXSTR + c8]) = o;
    }
  } else {
    const unsigned short* Xp = X + (long)a * xAOff + m0 * xRowStride;
#pragma unroll
    for (int p = 0; p < 8; p++) {
      int c = tid + p * 256;
      int row = c >> 4, c8 = (c & 15) * 8;
      short8 v = *(const short8*)(Xp + (long)row * xRowStride + c8);
      *(short8*)(&As[row * GXSTR + c8]) = v;
    }
  }
  __syncthreads();

  const int w = tid >> 6;
  const int l = tid & 63;
  const int lr = l & 15;
  const int lg = l >> 4;

  v4f acc[8][2];
#pragma unroll
  for (int mt = 0; mt < 8; mt++) {
    acc[mt][0] = (v4f){0.f, 0.f, 0.f, 0.f};
    acc[mt][1] = (v4f){0.f, 0.f, 0.f, 0.f};
  }

#pragma unroll
  for (int kt = 0; kt < 4; kt++) {
    short8 bfr[2];
#pragma unroll
    for (int ntl = 0; ntl < 2; ntl++)
      bfr[ntl] = *(const short8*)(Wp + (long)(kt * 8 + 2 * w + ntl) * 512 + l * 8);
#pragma unroll
    for (int mt = 0; mt < 8; mt++) {
      short8 af = *(const short8*)(&As[(mt * 16 + lr) * GXSTR + kt * 32 + lg * 8]);
      acc[mt][0] = __builtin_amdgcn_mfma_f32_16x16x32_bf16(af, bfr[0], acc[mt][0], 0, 0, 0);
      acc[mt][1] = __builtin_amdgcn_mfma_f32_16x16x32_bf16(af, bfr[1], acc[mt][1], 0, 0, 0);
    }
  }

  float bv[2] = {Bias[(long)a * bAStride + 32 * w + lr],
                 Bias[(long)a * bAStride + 32 * w + 16 + lr]};
#pragma unroll
  for (int mt = 0; mt < 8; mt++)
#pragma unroll
    for (int ntl = 0; ntl < 2; ntl++)
#pragma unroll
      for (int i = 0; i < 4; i++) {
        long row = m0 + mt * 16 + lg * 4 + i;
        int col = 32 * w + ntl * 16 + lr;
        float t = acc[mt][ntl][i] + bv[ntl];
        if (relu) t = fmaxf(t, 0.0f);
        C[row * cRowStride + (long)a * cAOff + col] = f2bf(t);
      }
}

// ---------------------------------------------------------------------------
// Segment-sum aggregation: one block per node n, both batches.
// ---------------------------------------------------------------------------
__global__ __launch_bounds__(192) void aggregate_bf2(
    const unsigned short* __restrict__ H, const int* __restrict__ offs,
    const int* __restrict__ csr, unsigned short* __restrict__ AGB) {
  const int n = blockIdx.x;
  const int t = threadIdx.x;
  const int bt = t / 96;
  const int c = (t % 96) * 4;
  const int e0 = offs[n], e1 = offs[n + 1];
  const unsigned short* hb = H + (long)bt * NN * 384 + c;
  float a0 = 0.f, a1 = 0.f, a2 = 0.f, a3 = 0.f;
  int j = e0;
  for (; j + 4 <= e1; j += 4) {
    int s0 = csr[j], s1 = csr[j + 1], s2 = csr[j + 2], s3 = csr[j + 3];
    uint2 u0 = *(const uint2*)(hb + (long)s0 * 384);
    uint2 u1 = *(const uint2*)(hb + (long)s1 * 384);
    uint2 u2 = *(const uint2*)(hb + (long)s2 * 384);
    uint2 u3 = *(const uint2*)(hb + (long)s3 * 384);
    a0 += bflo(u0.x); a1 += bfhi(u0.x); a2 += bflo(u0.y); a3 += bfhi(u0.y);
    a0 += bflo(u1.x); a1 += bfhi(u1.x); a2 += bflo(u1.y); a3 += bfhi(u1.y);
    a0 += bflo(u2.x); a1 += bfhi(u2.x); a2 += bflo(u2.y); a3 += bfhi(u2.y);
    a0 += bflo(u3.x); a1 += bfhi(u3.x); a2 += bflo(u3.y); a3 += bfhi(u3.y);
  }
  for (; j < e1; j++) {
    int s = csr[j];
    uint2 u = *(const uint2*)(hb + (long)s * 384);
    a0 += bflo(u.x); a1 += bfhi(u.x); a2 += bflo(u.y); a3 += bfhi(u.y);
  }
  uint2 out;
  out.x = (unsigned)f2bf(a0) | ((unsigned)f2bf(a1) << 16);
  out.y = (unsigned)f2bf(a2) | ((unsigned)f2bf(a3) << 16);
  *(uint2*)(AGB + ((long)bt * NN + n) * 384 + c) = out;
}

// ---------------------------------------------------------------------------
// Fused MFMA attention v2: 16 nodes/block, 256 threads (4 waves).
// Wave w owns cols [32w,32w+32) == head w. No shuffles; scores/softmax/PV are
// per-lane serial dots from dword-packed bf16 LDS. O overwrites xS (residual
// pre-read into registers). LDS 52224 B -> 3 blocks/CU.
// ---------------------------------------------------------------------------
#define XSTR 136
#define QSTR 34
__global__ __launch_bounds__(256, 3) void attn_mfma(
    const unsigned short* __restrict__ AGB, const unsigned short* __restrict__ WF,
    const float* __restrict__ bq, const float* __restrict__ bk,
    const float* __restrict__ bv, const float* __restrict__ bo,
    unsigned short* __restrict__ OUTB) {
  __shared__ __align__(16) unsigned short xS[48 * XSTR];
  __shared__ __align__(16) unsigned short qS[4 * 48 * QSTR];
  __shared__ __align__(16) unsigned short kS[4 * 48 * QSTR];
  __shared__ __align__(16) unsigned short vS[4 * 48 * QSTR];

  const int tid = threadIdx.x;
  const long node0 = (long)blockIdx.x * 16;
  const unsigned short* src = AGB + node0 * 384;

  // ---- stage agg tile: 48x128 bf16 ----
#pragma unroll
  for (int p = 0; p < 3; p++) {
    int c = tid + p * 256;
    int row = c >> 4, c8 = (c & 15) * 8;
    short8 v = *(const short8*)(src + c * 8);
    *(short8*)(&xS[row * XSTR + c8]) = v;
  }
  __syncthreads();

  const int w = tid >> 6;
  const int l = tid & 63;
  const int lr = l & 15;
  const int lg = l >> 4;
  const unsigned short* WQ = WF;
  const unsigned short* WK = WF + 16384;
  const unsigned short* WV = WF + 32768;
  const unsigned short* WO = WF + 49152;

  // ---- QKV projections via MFMA ----
  v4f accq[3][2], acck[3][2], accv[3][2];
#pragma unroll
  for (int mt = 0; mt < 3; mt++)
#pragma unroll
    for (int n = 0; n < 2; n++) {
      accq[mt][n] = (v4f){0.f, 0.f, 0.f, 0.f};
      acck[mt][n] = (v4f){0.f, 0.f, 0.f, 0.f};
      accv[mt][n] = (v4f){0.f, 0.f, 0.f, 0.f};
    }

#pragma unroll
  for (int kt = 0; kt < 4; kt++) {
    short8 af[3];
#pragma unroll
    for (int mt = 0; mt < 3; mt++)
      af[mt] = *(const short8*)&xS[(mt * 16 + lr) * XSTR + kt * 32 + lg * 8];
#pragma unroll
    for (int ntl = 0; ntl < 2; ntl++) {
      long tf = (long)(kt * 8 + 2 * w + ntl) * 512 + l * 8;
      short8 b0 = *(const short8*)&WQ[tf];
      short8 b1 = *(const short8*)&WK[tf];
      short8 b2 = *(const short8*)&WV[tf];
#pragma unroll
      for (int mt = 0; mt < 3; mt++) {
        accq[mt][ntl] = __builtin_amdgcn_mfma_f32_16x16x32_bf16(af[mt], b0, accq[mt][ntl], 0, 0, 0);
        acck[mt][ntl] = __builtin_amdgcn_mfma_f32_16x16x32_bf16(af[mt], b1, acck[mt][ntl], 0, 0, 0);
        accv[mt][ntl] = __builtin_amdgcn_mfma_f32_16x16x32_bf16(af[mt], b2, accv[mt][ntl], 0, 0, 0);
      }
    }
  }

  // ---- epilogue: bias (+scale folded into q), bf16 store to per-wave LDS ----
  {
    const float scale = 0.17677669529663687f;  // 1/sqrt(32)
    unsigned short* qw = &qS[w * 48 * QSTR];
    unsigned short* kw = &kS[w * 48 * QSTR];
    unsigned short* vw = &vS[w * 48 * QSTR];
    float bqv[2] = {bq[32 * w + lr], bq[32 * w + 16 + lr]};
    float bkv[2] = {bk[32 * w + lr], bk[32 * w + 16 + lr]};
    float bvv[2] = {bv[32 * w + lr], bv[32 * w + 16 + lr]};
#pragma unroll
    for (int mt = 0; mt < 3; mt++)
#pragma unroll
      for (int ntl = 0; ntl < 2; ntl++)
#pragma unroll
        for (int i = 0; i < 4; i++) {
          int row = mt * 16 + lg * 4 + i;
          int col = ntl * 16 + lr;
          qw[row * QSTR + col] = f2bf((accq[mt][ntl][i] + bqv[ntl]) * scale);
          kw[row * QSTR + col] = f2bf(acck[mt][ntl][i] + bkv[ntl]);
          vw[row * QSTR + col] = f2bf(accv[mt][ntl][i] + bvv[ntl]);
        }
  }

  // ---- residual pre-read (xS still holds agg) ----
  float resv[3][2][4];
#pragma unroll
  for (int mt = 0; mt < 3; mt++)
#pragma unroll
    for (int ntl = 0; ntl < 2; ntl++)
#pragma unroll
      for (int i = 0; i < 4; i++)
        resv[mt][ntl][i] =
            bf2f(xS[(mt * 16 + lg * 4 + i) * XSTR + 32 * w + ntl * 16 + lr]);
  __syncthreads();   // all xS reads done; safe to overwrite with O

  // ---- attention: lane l<48 handles (node nd=l/3, aq=l%3) of head w ----
  if (l < 48) {
    int aq = l % 3;
    int ndr = l - aq;  // 3*nd
    const unsigned* qr = (const unsigned*)&qS[(w * 48 + l) * QSTR];
    const unsigned* kr0 = (const unsigned*)&kS[(w * 48 + ndr) * QSTR];
    const unsigned* kr1 = (const unsigned*)&kS[(w * 48 + ndr + 1) * QSTR];
    const unsigned* kr2 = (const unsigned*)&kS[(w * 48 + ndr + 2) * QSTR];
    float s0 = 0.f, s1 = 0.f, s2 = 0.f;
#pragma unroll
    for (int j = 0; j < 16; j++) {
      unsigned uq = qr[j], u0 = kr0[j], u1 = kr1[j], u2 = kr2[j];
      float qa = bflo(uq), qb = bfhi(uq);
      s0 = fmaf(qa, bflo(u0), fmaf(qb, bfhi(u0), s0));
      s1 = fmaf(qa, bflo(u1), fmaf(qb, bfhi(u1), s1));
      s2 = fmaf(qa, bflo(u2), fmaf(qb, bfhi(u2), s2));
    }
    float mx = fmaxf(s0, fmaxf(s1, s2));
    float e0 = expf(s0 - mx), e1 = expf(s1 - mx), e2 = expf(s2 - mx);
    float inv = 1.0f / (e0 + e1 + e2);
    e0 *= inv; e1 *= inv; e2 *= inv;
    const unsigned* vr0 = (const unsigned*)&vS[(w * 48 + ndr) * QSTR];
    const unsigned* vr1 = (const unsigned*)&vS[(w * 48 + ndr + 1) * QSTR];
    const unsigned* vr2 = (const unsigned*)&vS[(w * 48 + ndr + 2) * QSTR];
    unsigned ov[16];
#pragma unroll
    for (int j = 0; j < 16; j++) {
      unsigned u0 = vr0[j], u1 = vr1[j], u2 = vr2[j];
      float oa = fmaf(e0, bflo(u0), fmaf(e1, bflo(u1), e2 * bflo(u2)));
      float ob = fmaf(e0, bfhi(u0), fmaf(e1, bfhi(u1), e2 * bfhi(u2)));
      ov[j] = (unsigned)f2bf(oa) | ((unsigned)f2bf(ob) << 16);
    }
    uint4* orow = (uint4*)&xS[l * XSTR + 32 * w];
    orow[0] = make_uint4(ov[0], ov[1], ov[2], ov[3]);
    orow[1] = make_uint4(ov[4], ov[5], ov[6], ov[7]);
    orow[2] = make_uint4(ov[8], ov[9], ov[10], ov[11]);
    orow[3] = make_uint4(ov[12], ov[13], ov[14], ov[15]);
  }
  __syncthreads();

  // ---- hI = agg + O @ Wo + bo (O now in xS; residual in regs) ----
  v4f acco[3][2];
#pragma unroll
  for (int mt = 0; mt < 3; mt++)
#pragma unroll
    for (int n = 0; n < 2; n++) acco[mt][n] = (v4f){0.f, 0.f, 0.f, 0.f};

#pragma unroll
  for (int kt = 0; kt < 4; kt++) {
    short8 af[3];
#pragma unroll
    for (int mt = 0; mt < 3; mt++)
      af[mt] = *(const short8*)&xS[(mt * 16 + lr) * XSTR + kt * 32 + lg * 8];
#pragma unroll
    for (int ntl = 0; ntl < 2; ntl++) {
      long tf = (long)(kt * 8 + 2 * w + ntl) * 512 + l * 8;
      short8 b = *(const short8*)&WO[tf];
#pragma unroll
      for (int mt = 0; mt < 3; mt++)
        acco[mt][ntl] = __builtin_amdgcn_mfma_f32_16x16x32_bf16(af[mt], b, acco[mt][ntl], 0, 0, 0);
    }
  }

  {
    float bov[2] = {bo[32 * w + lr], bo[32 * w + 16 + lr]};
#pragma unroll
    for (int mt = 0; mt < 3; mt++)
#pragma unroll
      for (int ntl = 0; ntl < 2; ntl++)
#pragma unroll
        for (int i = 0; i < 4; i++) {
          int row = mt * 16 + lg * 4 + i;
          int gcol = 32 * w + ntl * 16 + lr;
          OUTB[(node0 * 3 + row) * 128 + gcol] =
              f2bf(acco[mt][ntl][i] + bov[ntl] + resv[mt][ntl][i]);
        }
  }
}

// ---------------------------------------------------------------------------
// Fused mu-GEMM (N=16, MFMA) + noise + activations + logp.
// ---------------------------------------------------------------------------
#define MSTR 136
__global__ __launch_bounds__(256) void mu_final(
    const unsigned short* __restrict__ M, const unsigned short* __restrict__ WF2,
    const float* __restrict__ mb2,
    float* __restrict__ out0, float* __restrict__ out1) {
  __shared__ __align__(16) unsigned short As[192 * MSTR];
  __shared__ float lpS[192];
  const int tid = threadIdx.x;
  const long bn0 = (long)blockIdx.x * 64;

#pragma unroll
  for (int p = 0; p < 12; p++) {
    int ch = tid + p * 256;
    int nd = ch / 48;
    int rest = ch % 48;
    int a = rest >> 4;
    int k8 = (rest & 15) * 8;
    short8 v = *(const short8*)(M + (bn0 + nd) * 384 + a * 128 + k8);
    *(short8*)(&As[(a * 64 + nd) * MSTR + k8]) = v;
  }
  __syncthreads();

  const int w = tid >> 6, l = tid & 63, lr = l & 15, lg = l >> 4;

  v4f acc[3];
#pragma unroll
  for (int t = 0; t < 3; t++) acc[t] = (v4f){0.f, 0.f, 0.f, 0.f};

#pragma unroll
  for (int kt = 0; kt < 4; kt++) {
#pragma unroll
    for (int t = 0; t < 3; t++) {
      int tile = 3 * w + t;
      int a = tile >> 2;
      short8 af = *(const short8*)(&As[(tile * 16 + lr) * MSTR + kt * 32 + lg * 8]);
      short8 bf = *(const short8*)(WF2 + a * 2048 + kt * 512 + l * 8);
      acc[t] = __builtin_amdgcn_mfma_f32_16x16x32_bf16(af, bf, acc[t], 0, 0, 0);
    }
  }

#pragma unroll
  for (int t = 0; t < 3; t++) {
    int tile = 3 * w + t;
    int a = tile >> 2;
    int ndbase = (tile & 3) * 16;
    float bias = mb2[a * 16 + lr];
#pragma unroll
    for (int i = 0; i < 4; i++) {
      int nd = ndbase + lg * 4 + i;
      float mu = acc[t][i] + bias;
      unsigned gidx = (unsigned)((bn0 + nd) * 48 + a * 16 + lr);
      unsigned bits = jax_random_bits32(gidx);
      float noise = jax_normal_from_bits(bits);
      float sample = mu + noise;
      float lp = -0.9189385332046727f - 0.5f * noise * noise;
      lp += __shfl_xor(lp, 1, 64);
      lp += __shfl_xor(lp, 2, 64);
      lp += __shfl_xor(lp, 4, 64);
      lp += __shfl_xor(lp, 8, 64);
      if (lr == 0) lpS[a * 64 + nd] = lp;
      float res;
      if (a == 0) {
        float th = tanhf(sample);
        float mx = th;
        mx = fmaxf(mx, __shfl_xor(mx, 1, 64));
        mx = fmaxf(mx, __shfl_xor(mx, 2, 64));
        mx = fmaxf(mx, __shfl_xor(mx, 4, 64));
        mx = fmaxf(mx, __shfl_xor(mx, 8, 64));
        float ex = expf(th - mx);
        float ss = ex;
        ss += __shfl_xor(ss, 1, 64);
        ss += __shfl_xor(ss, 2, 64);
        ss += __shfl_xor(ss, 4, 64);
        ss += __shfl_xor(ss, 8, 64);
        res = ex / ss;
      } else if (a == 1) {
        res = 1.0f / (1.0f + expf(-sample));
      } else {
        res = tanhf(sample);
      }
      out0[gidx] = res;
    }
  }
  __syncthreads();
  if (tid < 64)
    out1[bn0 + tid] = lpS[tid] + lpS[64 + tid] + lpS[128 + tid];
}

// ---------------------------------------------------------------------------
extern "C" void kernel_launch(void* const* d_in, const int* in_sizes, int n_in,
                              void* d_out, int out_size, void* d_ws, size_t ws_size,
                              hipStream_t stream) {
  const float* x = (const float*)d_in[0];
  const int* ei = (const int*)d_in[1];
  const float* W1 = (const float*)d_in[2];
  const float* b1 = (const float*)d_in[3];
  const float* W2 = (const float*)d_in[4];
  const float* b2 = (const float*)d_in[5];
  const float* Wq = (const float*)d_in[6];
  const float* bq = (const float*)d_in[7];
  const float* Wk = (const float*)d_in[8];
  const float* bk = (const float*)d_in[9];
  const float* Wv = (const float*)d_in[10];
  const float* bv = (const float*)d_in[11];
  const float* Wo = (const float*)d_in[12];
  const float* bo = (const float*)d_in[13];
  const float* mW1 = (const float*)d_in[14];
  const float* mb1 = (const float*)d_in[15];
  const float* mW2 = (const float*)d_in[16];
  const float* mb2 = (const float*)d_in[17];
  (void)in_sizes; (void)n_in; (void)out_size; (void)ws_size;

  unsigned short* T1 = (unsigned short*)d_ws;      // 12,582,912 (t1, later hI)
  unsigned short* HB = T1 + 12582912;              // 12,582,912 (h, later m)
  unsigned short* AGB = HB + 12582912;             // 12,582,912 (agg bf16)
  int* deg = (int*)(AGB + 12582912);               // 16384
  int* offs = deg + NN;                            // 16385
  int* cur = offs + (NN + 1);                      // 16384
  int* csr = cur + NN;                             // 262144
  unsigned short* wfrag = (unsigned short*)(((uintptr_t)(csr + EE) + 15) & ~(uintptr_t)15);
  unsigned short* w2frag = wfrag + 13 * 16384;     // 3*2048

  const int* dst = ei;
  const int* srcv = ei + EE;

  float* out0 = (float*)d_out;
  float* out1 = out0 + TOT_NOISE;

  hipMemsetAsync(deg, 0, NN * sizeof(int), stream);
  edge_count<<<EE / 256, 256, 0, stream>>>(dst, deg);
  scan_k<<<1, 256, 0, stream>>>(deg, offs, cur);
  edge_fill<<<EE / 256, 256, 0, stream>>>(dst, srcv, cur, csr);
  prep_wfrag<<<dim3(64, 13), 256, 0, stream>>>(W1, W2, mW1, Wq, Wk, Wv, Wo, wfrag);
  prep_w2frag<<<dim3(8, 3), 256, 0, stream>>>(mW2, w2frag);

  dim3 g128(BNODES / 128, 3);
  // t1 = relu(x @ W1[a] + b1[a])   (x fp32 converted in staging)
  gemm_bf16<<<g128, 256, 0, stream>>>((const unsigned short*)x, 128, 0, wfrag, b1, 128, T1, AH, 128, 1, 1);
  // h = t1 @ W2[a] + b2[a]
  gemm_bf16<<<g128, 256, 0, stream>>>(T1, AH, 128, wfrag + 3 * 16384, b2, 128, HB, AH, 128, 0, 0);
  // agg = segment_sum(h[src] -> dst)
  aggregate_bf2<<<NN, 192, 0, stream>>>(HB, offs, csr, AGB);
  // attention + hI (bf16 out into T1)
  attn_mfma<<<BNODES / 16, 256, 0, stream>>>(AGB, wfrag + 9 * 16384, bq, bk, bv, bo, T1);
  // m = relu(hI @ mu_W1[a] + mu_b1[a])  (into HB)
  gemm_bf16<<<g128, 256, 0, stream>>>(T1, AH, 128, wfrag + 6 * 16384, mb1, 128, HB, AH, 128, 1, 0);
  // mu + noise + activations + logp (fused)
  mu_final<<<BNODES / 64, 256, 0, stream>>>(HB, w2frag, mb2, out0, out1);
}

// Round 6
// 250.093 us; speedup vs baseline: 2.6912x; 1.1088x over previous
//
#include <hip/hip_runtime.h>

// Problem constants
#define NN    16384      // N nodes
#define EE    262144     // edges
#define BNODES 32768     // B*N
#define AH    384        // A*H
#define TOT_NOISE 1572864u

typedef __attribute__((ext_vector_type(8))) short short8;
typedef __attribute__((ext_vector_type(4))) float v4f;

__device__ __forceinline__ unsigned short f2bf(float f) {
  unsigned u = __float_as_uint(f);
  unsigned r = u + 0x7fffu + ((u >> 16) & 1u);
  return (unsigned short)(r >> 16);
}
__device__ __forceinline__ float bf2f(unsigned short h) {
  return __uint_as_float(((unsigned)h) << 16);
}
__device__ __forceinline__ float bflo(unsigned u) { return __uint_as_float(u << 16); }
__device__ __forceinline__ float bfhi(unsigned u) { return __uint_as_float(u & 0xffff0000u); }

// ---------------------------------------------------------------------------
// Threefry-2x32, keys = (0, 42)
// ---------------------------------------------------------------------------
__device__ __forceinline__ void threefry2x32_042(unsigned& x0, unsigned& x1) {
  const unsigned ks0 = 0u;
  const unsigned ks1 = 42u;
  const unsigned ks2 = 0x1BD11BDAu ^ 0u ^ 42u;
  x0 += ks0; x1 += ks1;
#define TFR(r) { x0 += x1; x1 = (x1 << (r)) | (x1 >> (32 - (r))); x1 ^= x0; }
  TFR(13) TFR(15) TFR(26) TFR(6)   x0 += ks1; x1 += ks2 + 1u;
  TFR(17) TFR(29) TFR(16) TFR(24)  x0 += ks2; x1 += ks0 + 2u;
  TFR(13) TFR(15) TFR(26) TFR(6)   x0 += ks0; x1 += ks1 + 3u;
  TFR(17) TFR(29) TFR(16) TFR(24)  x0 += ks1; x1 += ks2 + 4u;
  TFR(13) TFR(15) TFR(26) TFR(6)   x0 += ks2; x1 += ks0 + 5u;
#undef TFR
}

// XLA ErfInv32 (Giles) polynomial
__device__ __forceinline__ float erfinv_f32(float x) {
  float w = -log1pf(-x * x);
  float p;
  if (w < 5.0f) {
    w -= 2.5f;
    p = 2.81022636e-08f;
    p = fmaf(p, w, 3.43273939e-07f);
    p = fmaf(p, w, -3.5233877e-06f);
    p = fmaf(p, w, -4.39150654e-06f);
    p = fmaf(p, w, 0.00021858087f);
    p = fmaf(p, w, -0.00125372503f);
    p = fmaf(p, w, -0.00417768164f);
    p = fmaf(p, w, 0.246640727f);
    p = fmaf(p, w, 1.50140941f);
  } else {
    w = sqrtf(w) - 3.0f;
    p = -0.000200214257f;
    p = fmaf(p, w, 0.000100950558f);
    p = fmaf(p, w, 0.00134934322f);
    p = fmaf(p, w, -0.00367342844f);
    p = fmaf(p, w, 0.00573950773f);
    p = fmaf(p, w, -0.0076224613f);
    p = fmaf(p, w, 0.00943887047f);
    p = fmaf(p, w, 1.00167406f);
    p = fmaf(p, w, 2.83297682f);
  }
  return p * x;
}

__device__ __forceinline__ unsigned jax_random_bits32(unsigned i) {
  unsigned x0 = 0u, x1 = i;
  threefry2x32_042(x0, x1);
  return x0 ^ x1;
}

__device__ __forceinline__ float jax_normal_from_bits(unsigned bits) {
  float f = __uint_as_float((bits >> 9) | 0x3f800000u) - 1.0f;  // [0,1)
  const float lo = -0.99999994f;                                 // nextafter(-1,0)
  float u = f * 2.0f + lo;
  u = fmaxf(u, lo);
  return 1.4142135623730951f * erfinv_f32(u);
}

// ---------------------------------------------------------------------------
// CSR build
// ---------------------------------------------------------------------------
__global__ void edge_count(const int* __restrict__ dst, int* __restrict__ deg) {
  int e = blockIdx.x * 256 + threadIdx.x;
  if (e < EE) atomicAdd(&deg[dst[e]], 1);
}

__global__ __launch_bounds__(256) void scan_k(const int* __restrict__ deg,
                                              int* __restrict__ offs,
                                              int* __restrict__ cur) {
  __shared__ int part[256];
  int t = threadIdx.x;
  int base = t * 64;
  int s = 0;
  for (int i = 0; i < 64; i++) s += deg[base + i];
  part[t] = s;
  __syncthreads();
  for (int off = 1; off < 256; off <<= 1) {
    int v = (t >= off) ? part[t - off] : 0;
    __syncthreads();
    part[t] += v;
    __syncthreads();
  }
  int run = (t == 0) ? 0 : part[t - 1];
  for (int i = 0; i < 64; i++) {
    offs[base + i] = run;
    cur[base + i] = run;
    run += deg[base + i];
  }
  if (t == 255) offs[NN] = run;
}

__global__ void edge_fill(const int* __restrict__ dst, const int* __restrict__ srcv,
                          int* __restrict__ cur, int* __restrict__ csr) {
  int e = blockIdx.x * 256 + threadIdx.x;
  if (e < EE) {
    int d = dst[e];
    int p = atomicAdd(&cur[d], 1);
    csr[p] = srcv[e];
  }
}

// ---------------------------------------------------------------------------
// Weight prep: 13 slots of 128x128 fp32 [k][n] -> bf16 MFMA B-fragment layout
// slots 0-2: W1[a]; 3-5: W2[a]; 6-8: mu_W1[a]; 9:Wq 10:Wk 11:Wv 12:Wo
// ---------------------------------------------------------------------------
__global__ __launch_bounds__(256) void prep_wfrag(
    const float* __restrict__ W1, const float* __restrict__ W2,
    const float* __restrict__ mW1,
    const float* __restrict__ Wq, const float* __restrict__ Wk,
    const float* __restrict__ Wv, const float* __restrict__ Wo,
    unsigned short* __restrict__ F) {
  int m = blockIdx.y;
  const float* W;
  if (m < 3) W = W1 + (long)m * 16384;
  else if (m < 6) W = W2 + (long)(m - 3) * 16384;
  else if (m < 9) W = mW1 + (long)(m - 6) * 16384;
  else W = (m == 9) ? Wq : (m == 10) ? Wk : (m == 11) ? Wv : Wo;
  int f = blockIdx.x * 256 + threadIdx.x;
  int tile = f >> 9;
  int kt = tile >> 3, nt = tile & 7;
  int r = f & 511;
  int lane = r >> 3, j = r & 7;
  int k = kt * 32 + (lane >> 4) * 8 + j;
  int n = nt * 16 + (lane & 15);
  F[(long)m * 16384 + f] = f2bf(W[k * 128 + n]);
}

// mu_W2 (A x 128 x 16) -> B-fragment layout, 3 slots of 2048
__global__ __launch_bounds__(256) void prep_w2frag(
    const float* __restrict__ mW2, unsigned short* __restrict__ F2) {
  int a = blockIdx.y;
  int f = blockIdx.x * 256 + threadIdx.x;  // 0..2047
  int kt = f >> 9;
  int r = f & 511;
  int lane = r >> 3, j = r & 7;
  int k = kt * 32 + (lane >> 4) * 8 + j;
  int n = lane & 15;
  F2[a * 2048 + f] = f2bf(mW2[(a * 128 + k) * 16 + n]);
}

// ---------------------------------------------------------------------------
// Fused 2-layer MLP: h = relu(x@W1+b1)@W2 + b2, per a. 128-row tiles.
// t1 round-trips through LDS (As reused), never touches HBM.
// ---------------------------------------------------------------------------
#define GXSTR 136
__global__ __launch_bounds__(256, 4) void mlp_fused(
    const float* __restrict__ X,
    const unsigned short* __restrict__ WF1, const float* __restrict__ b1,
    const unsigned short* __restrict__ WF2, const float* __restrict__ b2,
    unsigned short* __restrict__ H) {
  __shared__ __align__(16) unsigned short As[128 * GXSTR];
  const int a = blockIdx.y;
  const long m0 = (long)blockIdx.x * 128;
  const int tid = threadIdx.x;
  const unsigned short* Wp1 = WF1 + (long)a * 16384;
  const unsigned short* Wp2 = WF2 + (long)a * 16384;

  // stage x tile fp32 -> bf16
#pragma unroll
  for (int p = 0; p < 8; p++) {
    int c = tid + p * 256;
    int row = c >> 4, c8 = (c & 15) * 8;
    float4 v1 = *(const float4*)(X + (m0 + row) * 128 + c8);
    float4 v2 = *(const float4*)(X + (m0 + row) * 128 + c8 + 4);
    short8 o;
    o[0] = (short)f2bf(v1.x); o[1] = (short)f2bf(v1.y);
    o[2] = (short)f2bf(v1.z); o[3] = (short)f2bf(v1.w);
    o[4] = (short)f2bf(v2.x); o[5] = (short)f2bf(v2.y);
    o[6] = (short)f2bf(v2.z); o[7] = (short)f2bf(v2.w);
    *(short8*)(&As[row * GXSTR + c8]) = o;
  }
  __syncthreads();

  const int w = tid >> 6, l = tid & 63, lr = l & 15, lg = l >> 4;

  v4f acc[8][2];
#pragma unroll
  for (int mt = 0; mt < 8; mt++) {
    acc[mt][0] = (v4f){0.f, 0.f, 0.f, 0.f};
    acc[mt][1] = (v4f){0.f, 0.f, 0.f, 0.f};
  }
  // phase 1: t1 = x @ W1
#pragma unroll
  for (int kt = 0; kt < 4; kt++) {
    short8 bfr[2];
#pragma unroll
    for (int ntl = 0; ntl < 2; ntl++)
      bfr[ntl] = *(const short8*)(Wp1 + (long)(kt * 8 + 2 * w + ntl) * 512 + l * 8);
#pragma unroll
    for (int mt = 0; mt < 8; mt++) {
      short8 af = *(const short8*)(&As[(mt * 16 + lr) * GXSTR + kt * 32 + lg * 8]);
      acc[mt][0] = __builtin_amdgcn_mfma_f32_16x16x32_bf16(af, bfr[0], acc[mt][0], 0, 0, 0);
      acc[mt][1] = __builtin_amdgcn_mfma_f32_16x16x32_bf16(af, bfr[1], acc[mt][1], 0, 0, 0);
    }
  }
  __syncthreads();   // all As (x) reads done

  // write t1 = relu(acc + b1) back into As
  {
    float bv[2] = {b1[a * 128 + 32 * w + lr], b1[a * 128 + 32 * w + 16 + lr]};
#pragma unroll
    for (int mt = 0; mt < 8; mt++)
#pragma unroll
      for (int ntl = 0; ntl < 2; ntl++)
#pragma unroll
        for (int i = 0; i < 4; i++) {
          int row = mt * 16 + lg * 4 + i;
          int col = 32 * w + ntl * 16 + lr;
          As[row * GXSTR + col] = f2bf(fmaxf(acc[mt][ntl][i] + bv[ntl], 0.0f));
        }
  }
  __syncthreads();

  // phase 2: h = t1 @ W2 + b2
#pragma unroll
  for (int mt = 0; mt < 8; mt++) {
    acc[mt][0] = (v4f){0.f, 0.f, 0.f, 0.f};
    acc[mt][1] = (v4f){0.f, 0.f, 0.f, 0.f};
  }
#pragma unroll
  for (int kt = 0; kt < 4; kt++) {
    short8 bfr[2];
#pragma unroll
    for (int ntl = 0; ntl < 2; ntl++)
      bfr[ntl] = *(const short8*)(Wp2 + (long)(kt * 8 + 2 * w + ntl) * 512 + l * 8);
#pragma unroll
    for (int mt = 0; mt < 8; mt++) {
      short8 af = *(const short8*)(&As[(mt * 16 + lr) * GXSTR + kt * 32 + lg * 8]);
      acc[mt][0] = __builtin_amdgcn_mfma_f32_16x16x32_bf16(af, bfr[0], acc[mt][0], 0, 0, 0);
      acc[mt][1] = __builtin_amdgcn_mfma_f32_16x16x32_bf16(af, bfr[1], acc[mt][1], 0, 0, 0);
    }
  }
  {
    float bv[2] = {b2[a * 128 + 32 * w + lr], b2[a * 128 + 32 * w + 16 + lr]};
#pragma unroll
    for (int mt = 0; mt < 8; mt++)
#pragma unroll
      for (int ntl = 0; ntl < 2; ntl++)
#pragma unroll
        for (int i = 0; i < 4; i++) {
          long row = m0 + mt * 16 + lg * 4 + i;
          int col = 32 * w + ntl * 16 + lr;
          H[row * 384 + a * 128 + col] = f2bf(acc[mt][ntl][i] + bv[ntl]);
        }
  }
}

// ---------------------------------------------------------------------------
// Segment-sum aggregation v3: batch-major grid (L2 locality), 2 nodes/block,
// software-pipelined csr index prefetch (8 gathers in flight/thread).
// ---------------------------------------------------------------------------
__global__ __launch_bounds__(192) void aggregate_v3(
    const unsigned short* __restrict__ H, const int* __restrict__ offs,
    const int* __restrict__ csr, unsigned short* __restrict__ AGB) {
  const int bid = blockIdx.x;            // 0..16383, batch-major
  const int bt = bid >> 13;
  const int pair = bid & 8191;
  const int t = threadIdx.x;
  const int n = pair * 2 + (t / 96);
  const int c = (t % 96) * 4;
  const int e0 = offs[n], e1 = offs[n + 1];
  const unsigned short* hb = H + (long)bt * NN * 384 + c;
  float a0 = 0.f, a1 = 0.f, a2 = 0.f, a3 = 0.f;

  const int nfull = (e1 - e0) >> 3;
  int s[8];
  if (nfull > 0) {
#pragma unroll
    for (int i = 0; i < 8; i++) s[i] = csr[e0 + i];
  }
  for (int b = 0; b < nfull; b++) {
    int sn[8];
    if (b + 1 < nfull) {
      int base = e0 + b * 8 + 8;
#pragma unroll
      for (int i = 0; i < 8; i++) sn[i] = csr[base + i];
    }
#pragma unroll
    for (int i = 0; i < 8; i++) {
      uint2 u = *(const uint2*)(hb + (long)s[i] * 384);
      a0 += bflo(u.x); a1 += bfhi(u.x); a2 += bflo(u.y); a3 += bfhi(u.y);
    }
#pragma unroll
    for (int i = 0; i < 8; i++) s[i] = sn[i];
  }
  for (int j = e0 + nfull * 8; j < e1; j++) {
    int si = csr[j];
    uint2 u = *(const uint2*)(hb + (long)si * 384);
    a0 += bflo(u.x); a1 += bfhi(u.x); a2 += bflo(u.y); a3 += bfhi(u.y);
  }
  uint2 out;
  out.x = (unsigned)f2bf(a0) | ((unsigned)f2bf(a1) << 16);
  out.y = (unsigned)f2bf(a2) | ((unsigned)f2bf(a3) << 16);
  *(uint2*)(AGB + ((long)bt * NN + n) * 384 + c) = out;
}

// ---------------------------------------------------------------------------
// Mega-fused attention + mu-MLP + noise/logp tail. 16 nodes/block, 4 waves.
// Phases: QKV proj -> softmax-attn -> O@Wo (+residual) -> mu_W1 (relu) ->
// mu_W2 -> threefry noise, activations, out0/out1. hI and m live in LDS only.
// ---------------------------------------------------------------------------
#define XSTR 136
#define QSTR 34
__global__ __launch_bounds__(256, 3) void attn_mega(
    const unsigned short* __restrict__ AGB, const unsigned short* __restrict__ WF,
    const float* __restrict__ bq, const float* __restrict__ bk,
    const float* __restrict__ bv, const float* __restrict__ bo,
    const unsigned short* __restrict__ WM1, const float* __restrict__ mb1,
    const unsigned short* __restrict__ WM2, const float* __restrict__ mb2,
    float* __restrict__ out0, float* __restrict__ out1) {
  __shared__ __align__(16) unsigned short xS[48 * XSTR];
  __shared__ __align__(16) unsigned short qS[4 * 48 * QSTR];
  __shared__ __align__(16) unsigned short kS[4 * 48 * QSTR];
  __shared__ __align__(16) unsigned short vS[4 * 48 * QSTR];
  __shared__ float lpS[48];

  const int tid = threadIdx.x;
  const long node0 = (long)blockIdx.x * 16;
  const unsigned short* src = AGB + node0 * 384;

  // ---- stage agg tile: 48x128 bf16 (row r = 3*nd + a) ----
#pragma unroll
  for (int p = 0; p < 3; p++) {
    int c = tid + p * 256;
    int row = c >> 4, c8 = (c & 15) * 8;
    short8 v = *(const short8*)(src + c * 8);
    *(short8*)(&xS[row * XSTR + c8]) = v;
  }
  __syncthreads();

  const int w = tid >> 6;
  const int l = tid & 63;
  const int lr = l & 15;
  const int lg = l >> 4;
  const unsigned short* WQ = WF;
  const unsigned short* WK = WF + 16384;
  const unsigned short* WV = WF + 32768;
  const unsigned short* WO = WF + 49152;

  // ---- phase 1: QKV projections ----
  v4f accq[3][2], acck[3][2], accv[3][2];
#pragma unroll
  for (int mt = 0; mt < 3; mt++)
#pragma unroll
    for (int n = 0; n < 2; n++) {
      accq[mt][n] = (v4f){0.f, 0.f, 0.f, 0.f};
      acck[mt][n] = (v4f){0.f, 0.f, 0.f, 0.f};
      accv[mt][n] = (v4f){0.f, 0.f, 0.f, 0.f};
    }
#pragma unroll
  for (int kt = 0; kt < 4; kt++) {
    short8 af[3];
#pragma unroll
    for (int mt = 0; mt < 3; mt++)
      af[mt] = *(const short8*)&xS[(mt * 16 + lr) * XSTR + kt * 32 + lg * 8];
#pragma unroll
    for (int ntl = 0; ntl < 2; ntl++) {
      long tf = (long)(kt * 8 + 2 * w + ntl) * 512 + l * 8;
      short8 b0 = *(const short8*)&WQ[tf];
      short8 b1 = *(const short8*)&WK[tf];
      short8 b2 = *(const short8*)&WV[tf];
#pragma unroll
      for (int mt = 0; mt < 3; mt++) {
        accq[mt][ntl] = __builtin_amdgcn_mfma_f32_16x16x32_bf16(af[mt], b0, accq[mt][ntl], 0, 0, 0);
        acck[mt][ntl] = __builtin_amdgcn_mfma_f32_16x16x32_bf16(af[mt], b1, acck[mt][ntl], 0, 0, 0);
        accv[mt][ntl] = __builtin_amdgcn_mfma_f32_16x16x32_bf16(af[mt], b2, accv[mt][ntl], 0, 0, 0);
      }
    }
  }
  {
    const float scale = 0.17677669529663687f;  // 1/sqrt(32)
    unsigned short* qw = &qS[w * 48 * QSTR];
    unsigned short* kw = &kS[w * 48 * QSTR];
    unsigned short* vw = &vS[w * 48 * QSTR];
    float bqv[2] = {bq[32 * w + lr], bq[32 * w + 16 + lr]};
    float bkv[2] = {bk[32 * w + lr], bk[32 * w + 16 + lr]};
    float bvv[2] = {bv[32 * w + lr], bv[32 * w + 16 + lr]};
#pragma unroll
    for (int mt = 0; mt < 3; mt++)
#pragma unroll
      for (int ntl = 0; ntl < 2; ntl++)
#pragma unroll
        for (int i = 0; i < 4; i++) {
          int row = mt * 16 + lg * 4 + i;
          int col = ntl * 16 + lr;
          qw[row * QSTR + col] = f2bf((accq[mt][ntl][i] + bqv[ntl]) * scale);
          kw[row * QSTR + col] = f2bf(acck[mt][ntl][i] + bkv[ntl]);
          vw[row * QSTR + col] = f2bf(accv[mt][ntl][i] + bvv[ntl]);
        }
  }

  // residual pre-read (xS still holds agg)
  float resv[3][2][4];
#pragma unroll
  for (int mt = 0; mt < 3; mt++)
#pragma unroll
    for (int ntl = 0; ntl < 2; ntl++)
#pragma unroll
      for (int i = 0; i < 4; i++)
        resv[mt][ntl][i] =
            bf2f(xS[(mt * 16 + lg * 4 + i) * XSTR + 32 * w + ntl * 16 + lr]);
  __syncthreads();

  // ---- phase 2: attention; O overwrites xS (rows = 3*nd+aq) ----
  if (l < 48) {
    int aq = l % 3;
    int ndr = l - aq;
    const unsigned* qr = (const unsigned*)&qS[(w * 48 + l) * QSTR];
    const unsigned* kr0 = (const unsigned*)&kS[(w * 48 + ndr) * QSTR];
    const unsigned* kr1 = (const unsigned*)&kS[(w * 48 + ndr + 1) * QSTR];
    const unsigned* kr2 = (const unsigned*)&kS[(w * 48 + ndr + 2) * QSTR];
    float s0 = 0.f, s1 = 0.f, s2 = 0.f;
#pragma unroll
    for (int j = 0; j < 16; j++) {
      unsigned uq = qr[j], u0 = kr0[j], u1 = kr1[j], u2 = kr2[j];
      float qa = bflo(uq), qb = bfhi(uq);
      s0 = fmaf(qa, bflo(u0), fmaf(qb, bfhi(u0), s0));
      s1 = fmaf(qa, bflo(u1), fmaf(qb, bfhi(u1), s1));
      s2 = fmaf(qa, bflo(u2), fmaf(qb, bfhi(u2), s2));
    }
    float mx = fmaxf(s0, fmaxf(s1, s2));
    float e0 = expf(s0 - mx), e1 = expf(s1 - mx), e2 = expf(s2 - mx);
    float inv = 1.0f / (e0 + e1 + e2);
    e0 *= inv; e1 *= inv; e2 *= inv;
    const unsigned* vr0 = (const unsigned*)&vS[(w * 48 + ndr) * QSTR];
    const unsigned* vr1 = (const unsigned*)&vS[(w * 48 + ndr + 1) * QSTR];
    const unsigned* vr2 = (const unsigned*)&vS[(w * 48 + ndr + 2) * QSTR];
    unsigned ov[16];
#pragma unroll
    for (int j = 0; j < 16; j++) {
      unsigned u0 = vr0[j], u1 = vr1[j], u2 = vr2[j];
      float oa = fmaf(e0, bflo(u0), fmaf(e1, bflo(u1), e2 * bflo(u2)));
      float ob = fmaf(e0, bfhi(u0), fmaf(e1, bfhi(u1), e2 * bfhi(u2)));
      ov[j] = (unsigned)f2bf(oa) | ((unsigned)f2bf(ob) << 16);
    }
    uint4* orow = (uint4*)&xS[l * XSTR + 32 * w];
    orow[0] = make_uint4(ov[0], ov[1], ov[2], ov[3]);
    orow[1] = make_uint4(ov[4], ov[5], ov[6], ov[7]);
    orow[2] = make_uint4(ov[8], ov[9], ov[10], ov[11]);
    orow[3] = make_uint4(ov[12], ov[13], ov[14], ov[15]);
  }
  __syncthreads();

  // ---- phase 3: hI = agg + O @ Wo + bo ----
  v4f acco[3][2];
#pragma unroll
  for (int mt = 0; mt < 3; mt++)
#pragma unroll
    for (int n = 0; n < 2; n++) acco[mt][n] = (v4f){0.f, 0.f, 0.f, 0.f};
#pragma unroll
  for (int kt = 0; kt < 4; kt++) {
    short8 af[3];
#pragma unroll
    for (int mt = 0; mt < 3; mt++)
      af[mt] = *(const short8*)&xS[(mt * 16 + lr) * XSTR + kt * 32 + lg * 8];
#pragma unroll
    for (int ntl = 0; ntl < 2; ntl++) {
      long tf = (long)(kt * 8 + 2 * w + ntl) * 512 + l * 8;
      short8 b = *(const short8*)&WO[tf];
#pragma unroll
      for (int mt = 0; mt < 3; mt++)
        acco[mt][ntl] = __builtin_amdgcn_mfma_f32_16x16x32_bf16(af[mt], b, acco[mt][ntl], 0, 0, 0);
    }
  }
  __syncthreads();   // all O reads of xS done

  // write hI into xS, a-major rows: row' = a*16 + nd  (orig row = 3*nd + a)
  {
    float bov[2] = {bo[32 * w + lr], bo[32 * w + 16 + lr]};
#pragma unroll
    for (int mt = 0; mt < 3; mt++)
#pragma unroll
      for (int ntl = 0; ntl < 2; ntl++)
#pragma unroll
        for (int i = 0; i < 4; i++) {
          int row = mt * 16 + lg * 4 + i;
          int nd = row / 3, a_ = row - nd * 3;
          int gcol = 32 * w + ntl * 16 + lr;
          xS[(a_ * 16 + nd) * XSTR + gcol] =
              f2bf(acco[mt][ntl][i] + bov[ntl] + resv[mt][ntl][i]);
        }
  }
  __syncthreads();

  // ---- phase 4: m = relu(hI @ mu_W1[a] + mb1[a]); tile mt == a ----
  v4f accm[3][2];
#pragma unroll
  for (int mt = 0; mt < 3; mt++)
#pragma unroll
    for (int n = 0; n < 2; n++) accm[mt][n] = (v4f){0.f, 0.f, 0.f, 0.f};
#pragma unroll
  for (int kt = 0; kt < 4; kt++) {
#pragma unroll
    for (int mt = 0; mt < 3; mt++) {
      short8 af = *(const short8*)&xS[(mt * 16 + lr) * XSTR + kt * 32 + lg * 8];
#pragma unroll
      for (int ntl = 0; ntl < 2; ntl++) {
        short8 b = *(const short8*)(WM1 + (long)mt * 16384 +
                                    (long)(kt * 8 + 2 * w + ntl) * 512 + l * 8);
        accm[mt][ntl] = __builtin_amdgcn_mfma_f32_16x16x32_bf16(af, b, accm[mt][ntl], 0, 0, 0);
      }
    }
  }
  __syncthreads();   // all hI reads done

  // write m into xS (already a-major: tile mt rows = a*16 + nd)
#pragma unroll
  for (int mt = 0; mt < 3; mt++)
#pragma unroll
    for (int ntl = 0; ntl < 2; ntl++) {
      int col = 32 * w + ntl * 16 + lr;
      float bias = mb1[mt * 128 + col];
#pragma unroll
      for (int i = 0; i < 4; i++) {
        int rowp = mt * 16 + lg * 4 + i;
        xS[rowp * XSTR + col] = f2bf(fmaxf(accm[mt][ntl][i] + bias, 0.0f));
      }
    }
  __syncthreads();

  // ---- phase 5: mu = m @ mu_W2[a] + mb2[a]; wave w handles a = w (w<3) ----
  if (w < 3) {
    v4f accu = (v4f){0.f, 0.f, 0.f, 0.f};
#pragma unroll
    for (int kt = 0; kt < 4; kt++) {
      short8 af = *(const short8*)&xS[(w * 16 + lr) * XSTR + kt * 32 + lg * 8];
      short8 b = *(const short8*)(WM2 + w * 2048 + kt * 512 + l * 8);
      accu = __builtin_amdgcn_mfma_f32_16x16x32_bf16(af, b, accu, 0, 0, 0);
    }
    float bias = mb2[w * 16 + lr];
#pragma unroll
    for (int i = 0; i < 4; i++) {
      int nd = lg * 4 + i;
      float mu = accu[i] + bias;
      unsigned gidx = (unsigned)((node0 + nd) * 48 + w * 16 + lr);
      unsigned bits = jax_random_bits32(gidx);
      float noise = jax_normal_from_bits(bits);
      float sample = mu + noise;
      float lp = -0.9189385332046727f - 0.5f * noise * noise;
      lp += __shfl_xor(lp, 1, 64);
      lp += __shfl_xor(lp, 2, 64);
      lp += __shfl_xor(lp, 4, 64);
      lp += __shfl_xor(lp, 8, 64);
      if (lr == 0) lpS[w * 16 + nd] = lp;
      float res;
      if (w == 0) {
        float th = tanhf(sample);
        float mx = th;
        mx = fmaxf(mx, __shfl_xor(mx, 1, 64));
        mx = fmaxf(mx, __shfl_xor(mx, 2, 64));
        mx = fmaxf(mx, __shfl_xor(mx, 4, 64));
        mx = fmaxf(mx, __shfl_xor(mx, 8, 64));
        float ex = expf(th - mx);
        float ss = ex;
        ss += __shfl_xor(ss, 1, 64);
        ss += __shfl_xor(ss, 2, 64);
        ss += __shfl_xor(ss, 4, 64);
        ss += __shfl_xor(ss, 8, 64);
        res = ex / ss;
      } else if (w == 1) {
        res = 1.0f / (1.0f + expf(-sample));
      } else {
        res = tanhf(sample);
      }
      out0[gidx] = res;
    }
  }
  __syncthreads();
  if (tid < 16)
    out1[node0 + tid] = lpS[tid] + lpS[16 + tid] + lpS[32 + tid];
}

// ---------------------------------------------------------------------------
extern "C" void kernel_launch(void* const* d_in, const int* in_sizes, int n_in,
                              void* d_out, int out_size, void* d_ws, size_t ws_size,
                              hipStream_t stream) {
  const float* x = (const float*)d_in[0];
  const int* ei = (const int*)d_in[1];
  const float* W1 = (const float*)d_in[2];
  const float* b1 = (const float*)d_in[3];
  const float* W2 = (const float*)d_in[4];
  const float* b2 = (const float*)d_in[5];
  const float* Wq = (const float*)d_in[6];
  const float* bq = (const float*)d_in[7];
  const float* Wk = (const float*)d_in[8];
  const float* bk = (const float*)d_in[9];
  const float* Wv = (const float*)d_in[10];
  const float* bv = (const float*)d_in[11];
  const float* Wo = (const float*)d_in[12];
  const float* bo = (const float*)d_in[13];
  const float* mW1 = (const float*)d_in[14];
  const float* mb1 = (const float*)d_in[15];
  const float* mW2 = (const float*)d_in[16];
  const float* mb2 = (const float*)d_in[17];
  (void)in_sizes; (void)n_in; (void)out_size; (void)ws_size;

  unsigned short* HB = (unsigned short*)d_ws;      // 12,582,912 (h bf16)
  unsigned short* AGB = HB + 12582912;             // 12,582,912 (agg bf16)
  int* deg = (int*)(AGB + 12582912);               // 16384
  int* offs = deg + NN;                            // 16385
  int* cur = offs + (NN + 1);                      // 16384
  int* csr = cur + NN;                             // 262144
  unsigned short* wfrag = (unsigned short*)(((uintptr_t)(csr + EE) + 15) & ~(uintptr_t)15);
  unsigned short* w2frag = wfrag + 13 * 16384;     // 3*2048

  const int* dst = ei;
  const int* srcv = ei + EE;

  float* out0 = (float*)d_out;
  float* out1 = out0 + TOT_NOISE;

  hipMemsetAsync(deg, 0, NN * sizeof(int), stream);
  edge_count<<<EE / 256, 256, 0, stream>>>(dst, deg);
  scan_k<<<1, 256, 0, stream>>>(deg, offs, cur);
  edge_fill<<<EE / 256, 256, 0, stream>>>(dst, srcv, cur, csr);
  prep_wfrag<<<dim3(64, 13), 256, 0, stream>>>(W1, W2, mW1, Wq, Wk, Wv, Wo, wfrag);
  prep_w2frag<<<dim3(8, 3), 256, 0, stream>>>(mW2, w2frag);

  // h = relu(x@W1+b1)@W2 + b2  (fused 2-layer MLP)
  mlp_fused<<<dim3(BNODES / 128, 3), 256, 0, stream>>>(x, wfrag, b1, wfrag + 3 * 16384, b2, HB);
  // agg = segment_sum(h[src] -> dst)
  aggregate_v3<<<2 * NN / 2, 192, 0, stream>>>(HB, offs, csr, AGB);
  // attention + hI + mu-MLP + noise/logp (mega-fused)
  attn_mega<<<BNODES / 16, 256, 0, stream>>>(AGB, wfrag + 9 * 16384, bq, bk, bv, bo,
                                             wfrag + 6 * 16384, mb1, w2frag, mb2,
                                             out0, out1);
}

// Round 7
// 244.694 us; speedup vs baseline: 2.7506x; 1.0221x over previous
//
#include <hip/hip_runtime.h>

// Problem constants
#define NN    16384      // N nodes
#define EE    262144     // edges
#define BNODES 32768     // B*N
#define AH    384        // A*H
#define TOT_NOISE 1572864u

typedef __attribute__((ext_vector_type(8))) short short8;
typedef __attribute__((ext_vector_type(4))) float v4f;

__device__ __forceinline__ unsigned short f2bf(float f) {
  unsigned u = __float_as_uint(f);
  unsigned r = u + 0x7fffu + ((u >> 16) & 1u);
  return (unsigned short)(r >> 16);
}
__device__ __forceinline__ float bf2f(unsigned short h) {
  return __uint_as_float(((unsigned)h) << 16);
}
__device__ __forceinline__ float bflo(unsigned u) { return __uint_as_float(u << 16); }
__device__ __forceinline__ float bfhi(unsigned u) { return __uint_as_float(u & 0xffff0000u); }

// ---------------------------------------------------------------------------
// Threefry-2x32, keys = (0, 42)
// ---------------------------------------------------------------------------
__device__ __forceinline__ void threefry2x32_042(unsigned& x0, unsigned& x1) {
  const unsigned ks0 = 0u;
  const unsigned ks1 = 42u;
  const unsigned ks2 = 0x1BD11BDAu ^ 0u ^ 42u;
  x0 += ks0; x1 += ks1;
#define TFR(r) { x0 += x1; x1 = (x1 << (r)) | (x1 >> (32 - (r))); x1 ^= x0; }
  TFR(13) TFR(15) TFR(26) TFR(6)   x0 += ks1; x1 += ks2 + 1u;
  TFR(17) TFR(29) TFR(16) TFR(24)  x0 += ks2; x1 += ks0 + 2u;
  TFR(13) TFR(15) TFR(26) TFR(6)   x0 += ks0; x1 += ks1 + 3u;
  TFR(17) TFR(29) TFR(16) TFR(24)  x0 += ks1; x1 += ks2 + 4u;
  TFR(13) TFR(15) TFR(26) TFR(6)   x0 += ks2; x1 += ks0 + 5u;
#undef TFR
}

// XLA ErfInv32 (Giles) polynomial
__device__ __forceinline__ float erfinv_f32(float x) {
  float w = -log1pf(-x * x);
  float p;
  if (w < 5.0f) {
    w -= 2.5f;
    p = 2.81022636e-08f;
    p = fmaf(p, w, 3.43273939e-07f);
    p = fmaf(p, w, -3.5233877e-06f);
    p = fmaf(p, w, -4.39150654e-06f);
    p = fmaf(p, w, 0.00021858087f);
    p = fmaf(p, w, -0.00125372503f);
    p = fmaf(p, w, -0.00417768164f);
    p = fmaf(p, w, 0.246640727f);
    p = fmaf(p, w, 1.50140941f);
  } else {
    w = sqrtf(w) - 3.0f;
    p = -0.000200214257f;
    p = fmaf(p, w, 0.000100950558f);
    p = fmaf(p, w, 0.00134934322f);
    p = fmaf(p, w, -0.00367342844f);
    p = fmaf(p, w, 0.00573950773f);
    p = fmaf(p, w, -0.0076224613f);
    p = fmaf(p, w, 0.00943887047f);
    p = fmaf(p, w, 1.00167406f);
    p = fmaf(p, w, 2.83297682f);
  }
  return p * x;
}

__device__ __forceinline__ unsigned jax_random_bits32(unsigned i) {
  unsigned x0 = 0u, x1 = i;
  threefry2x32_042(x0, x1);
  return x0 ^ x1;
}

__device__ __forceinline__ float jax_normal_from_bits(unsigned bits) {
  float f = __uint_as_float((bits >> 9) | 0x3f800000u) - 1.0f;  // [0,1)
  const float lo = -0.99999994f;                                 // nextafter(-1,0)
  float u = f * 2.0f + lo;
  u = fmaxf(u, lo);
  return 1.4142135623730951f * erfinv_f32(u);
}

// ---------------------------------------------------------------------------
// CSR build
// ---------------------------------------------------------------------------
__global__ void edge_count(const int* __restrict__ dst, int* __restrict__ deg) {
  int e = blockIdx.x * 256 + threadIdx.x;
  if (e < EE) atomicAdd(&deg[dst[e]], 1);
}

__global__ __launch_bounds__(256) void scan_k(const int* __restrict__ deg,
                                              int* __restrict__ offs,
                                              int* __restrict__ cur) {
  __shared__ int part[256];
  int t = threadIdx.x;
  int base = t * 64;
  int s = 0;
  for (int i = 0; i < 64; i++) s += deg[base + i];
  part[t] = s;
  __syncthreads();
  for (int off = 1; off < 256; off <<= 1) {
    int v = (t >= off) ? part[t - off] : 0;
    __syncthreads();
    part[t] += v;
    __syncthreads();
  }
  int run = (t == 0) ? 0 : part[t - 1];
  for (int i = 0; i < 64; i++) {
    offs[base + i] = run;
    cur[base + i] = run;
    run += deg[base + i];
  }
  if (t == 255) offs[NN] = run;
}

__global__ void edge_fill(const int* __restrict__ dst, const int* __restrict__ srcv,
                          int* __restrict__ cur, int* __restrict__ csr) {
  int e = blockIdx.x * 256 + threadIdx.x;
  if (e < EE) {
    int d = dst[e];
    int p = atomicAdd(&cur[d], 1);
    csr[p] = srcv[e];
  }
}

// ---------------------------------------------------------------------------
// Weight prep: 13 slots of 128x128 fp32 [k][n] -> bf16 MFMA B-fragment layout
// slots 0-2: W1[a]; 3-5: W2[a]; 6-8: mu_W1[a]; 9:Wq 10:Wk 11:Wv 12:Wo
// ---------------------------------------------------------------------------
__global__ __launch_bounds__(256) void prep_wfrag(
    const float* __restrict__ W1, const float* __restrict__ W2,
    const float* __restrict__ mW1,
    const float* __restrict__ Wq, const float* __restrict__ Wk,
    const float* __restrict__ Wv, const float* __restrict__ Wo,
    unsigned short* __restrict__ F) {
  int m = blockIdx.y;
  const float* W;
  if (m < 3) W = W1 + (long)m * 16384;
  else if (m < 6) W = W2 + (long)(m - 3) * 16384;
  else if (m < 9) W = mW1 + (long)(m - 6) * 16384;
  else W = (m == 9) ? Wq : (m == 10) ? Wk : (m == 11) ? Wv : Wo;
  int f = blockIdx.x * 256 + threadIdx.x;
  int tile = f >> 9;
  int kt = tile >> 3, nt = tile & 7;
  int r = f & 511;
  int lane = r >> 3, j = r & 7;
  int k = kt * 32 + (lane >> 4) * 8 + j;
  int n = nt * 16 + (lane & 15);
  F[(long)m * 16384 + f] = f2bf(W[k * 128 + n]);
}

// mu_W2 (A x 128 x 16) -> B-fragment layout, 3 slots of 2048
__global__ __launch_bounds__(256) void prep_w2frag(
    const float* __restrict__ mW2, unsigned short* __restrict__ F2) {
  int a = blockIdx.y;
  int f = blockIdx.x * 256 + threadIdx.x;  // 0..2047
  int kt = f >> 9;
  int r = f & 511;
  int lane = r >> 3, j = r & 7;
  int k = kt * 32 + (lane >> 4) * 8 + j;
  int n = lane & 15;
  F2[a * 2048 + f] = f2bf(mW2[(a * 128 + k) * 16 + n]);
}

// ---------------------------------------------------------------------------
// Fused 2-layer MLP: h = relu(x@W1+b1)@W2 + b2, per a. 128-row tiles.
// t1 round-trips through LDS (As reused), never touches HBM.
// ---------------------------------------------------------------------------
#define GXSTR 136
__global__ __launch_bounds__(256, 4) void mlp_fused(
    const float* __restrict__ X,
    const unsigned short* __restrict__ WF1, const float* __restrict__ b1,
    const unsigned short* __restrict__ WF2, const float* __restrict__ b2,
    unsigned short* __restrict__ H) {
  __shared__ __align__(16) unsigned short As[128 * GXSTR];
  const int a = blockIdx.y;
  const long m0 = (long)blockIdx.x * 128;
  const int tid = threadIdx.x;
  const unsigned short* Wp1 = WF1 + (long)a * 16384;
  const unsigned short* Wp2 = WF2 + (long)a * 16384;

  // stage x tile fp32 -> bf16
#pragma unroll
  for (int p = 0; p < 8; p++) {
    int c = tid + p * 256;
    int row = c >> 4, c8 = (c & 15) * 8;
    float4 v1 = *(const float4*)(X + (m0 + row) * 128 + c8);
    float4 v2 = *(const float4*)(X + (m0 + row) * 128 + c8 + 4);
    short8 o;
    o[0] = (short)f2bf(v1.x); o[1] = (short)f2bf(v1.y);
    o[2] = (short)f2bf(v1.z); o[3] = (short)f2bf(v1.w);
    o[4] = (short)f2bf(v2.x); o[5] = (short)f2bf(v2.y);
    o[6] = (short)f2bf(v2.z); o[7] = (short)f2bf(v2.w);
    *(short8*)(&As[row * GXSTR + c8]) = o;
  }
  __syncthreads();

  const int w = tid >> 6, l = tid & 63, lr = l & 15, lg = l >> 4;

  v4f acc[8][2];
#pragma unroll
  for (int mt = 0; mt < 8; mt++) {
    acc[mt][0] = (v4f){0.f, 0.f, 0.f, 0.f};
    acc[mt][1] = (v4f){0.f, 0.f, 0.f, 0.f};
  }
  // phase 1: t1 = x @ W1
#pragma unroll
  for (int kt = 0; kt < 4; kt++) {
    short8 bfr[2];
#pragma unroll
    for (int ntl = 0; ntl < 2; ntl++)
      bfr[ntl] = *(const short8*)(Wp1 + (long)(kt * 8 + 2 * w + ntl) * 512 + l * 8);
#pragma unroll
    for (int mt = 0; mt < 8; mt++) {
      short8 af = *(const short8*)(&As[(mt * 16 + lr) * GXSTR + kt * 32 + lg * 8]);
      acc[mt][0] = __builtin_amdgcn_mfma_f32_16x16x32_bf16(af, bfr[0], acc[mt][0], 0, 0, 0);
      acc[mt][1] = __builtin_amdgcn_mfma_f32_16x16x32_bf16(af, bfr[1], acc[mt][1], 0, 0, 0);
    }
  }
  __syncthreads();   // all As (x) reads done

  // write t1 = relu(acc + b1) back into As
  {
    float bv[2] = {b1[a * 128 + 32 * w + lr], b1[a * 128 + 32 * w + 16 + lr]};
#pragma unroll
    for (int mt = 0; mt < 8; mt++)
#pragma unroll
      for (int ntl = 0; ntl < 2; ntl++)
#pragma unroll
        for (int i = 0; i < 4; i++) {
          int row = mt * 16 + lg * 4 + i;
          int col = 32 * w + ntl * 16 + lr;
          As[row * GXSTR + col] = f2bf(fmaxf(acc[mt][ntl][i] + bv[ntl], 0.0f));
        }
  }
  __syncthreads();

  // phase 2: h = t1 @ W2 + b2
#pragma unroll
  for (int mt = 0; mt < 8; mt++) {
    acc[mt][0] = (v4f){0.f, 0.f, 0.f, 0.f};
    acc[mt][1] = (v4f){0.f, 0.f, 0.f, 0.f};
  }
#pragma unroll
  for (int kt = 0; kt < 4; kt++) {
    short8 bfr[2];
#pragma unroll
    for (int ntl = 0; ntl < 2; ntl++)
      bfr[ntl] = *(const short8*)(Wp2 + (long)(kt * 8 + 2 * w + ntl) * 512 + l * 8);
#pragma unroll
    for (int mt = 0; mt < 8; mt++) {
      short8 af = *(const short8*)(&As[(mt * 16 + lr) * GXSTR + kt * 32 + lg * 8]);
      acc[mt][0] = __builtin_amdgcn_mfma_f32_16x16x32_bf16(af, bfr[0], acc[mt][0], 0, 0, 0);
      acc[mt][1] = __builtin_amdgcn_mfma_f32_16x16x32_bf16(af, bfr[1], acc[mt][1], 0, 0, 0);
    }
  }
  {
    float bv[2] = {b2[a * 128 + 32 * w + lr], b2[a * 128 + 32 * w + 16 + lr]};
#pragma unroll
    for (int mt = 0; mt < 8; mt++)
#pragma unroll
      for (int ntl = 0; ntl < 2; ntl++)
#pragma unroll
        for (int i = 0; i < 4; i++) {
          long row = m0 + mt * 16 + lg * 4 + i;
          int col = 32 * w + ntl * 16 + lr;
          H[row * 384 + a * 128 + col] = f2bf(acc[mt][ntl][i] + bv[ntl]);
        }
  }
}

// ---------------------------------------------------------------------------
// Mega-fused: segment-sum gather + attention + mu-MLP + noise/logp tail.
// 16 nodes/block, 4 waves. Gather: 16 threads/node, 48B/thread/edge,
// 2-edge software pipeline; agg accumulated fp32 in regs -> bf16 xS.
// ---------------------------------------------------------------------------
#define XSTR 136
#define QSTR 34
__global__ __launch_bounds__(256, 3) void attn_mega(
    const unsigned short* __restrict__ H, const int* __restrict__ offs,
    const int* __restrict__ csr,
    const unsigned short* __restrict__ WF,
    const float* __restrict__ bq, const float* __restrict__ bk,
    const float* __restrict__ bv, const float* __restrict__ bo,
    const unsigned short* __restrict__ WM1, const float* __restrict__ mb1,
    const unsigned short* __restrict__ WM2, const float* __restrict__ mb2,
    float* __restrict__ out0, float* __restrict__ out1) {
  __shared__ __align__(16) unsigned short xS[48 * XSTR];
  __shared__ __align__(16) unsigned short qS[4 * 48 * QSTR];
  __shared__ __align__(16) unsigned short kS[4 * 48 * QSTR];
  __shared__ __align__(16) unsigned short vS[4 * 48 * QSTR];
  __shared__ float lpS[48];

  const int tid = threadIdx.x;
  const long node0 = (long)blockIdx.x * 16;

  // ---- phase 0: gather + segment-sum agg for 16 nodes directly into xS ----
  {
    const int bt = (int)(node0 >> 14);           // batch
    const int nbase = (int)(node0 & (NN - 1));
    const int nd = tid >> 4;                     // 0..15 local node
    const int sub = tid & 15;                    // 0..15 col group (24 bf16)
    const int n = nbase + nd;
    const int e0 = offs[n], e1 = offs[n + 1];
    const unsigned short* hb = H + (long)bt * NN * 384 + sub * 24;
    float acc24[24];
#pragma unroll
    for (int i = 0; i < 24; i++) acc24[i] = 0.f;

    int j = e0;
    for (; j + 2 <= e1; j += 2) {
      int s0 = csr[j], s1 = csr[j + 1];
      const unsigned short* p0 = hb + (long)s0 * 384;
      const unsigned short* p1 = hb + (long)s1 * 384;
      uint4 A0 = *(const uint4*)(p0);
      uint4 A1 = *(const uint4*)(p0 + 8);
      uint4 A2 = *(const uint4*)(p0 + 16);
      uint4 B0 = *(const uint4*)(p1);
      uint4 B1 = *(const uint4*)(p1 + 8);
      uint4 B2 = *(const uint4*)(p1 + 16);
#define ACC8(base, u)                                                   \
      { acc24[base+0] += bflo(u.x); acc24[base+1] += bfhi(u.x);         \
        acc24[base+2] += bflo(u.y); acc24[base+3] += bfhi(u.y);         \
        acc24[base+4] += bflo(u.z); acc24[base+5] += bfhi(u.z);         \
        acc24[base+6] += bflo(u.w); acc24[base+7] += bfhi(u.w); }
      ACC8(0, A0) ACC8(8, A1) ACC8(16, A2)
      ACC8(0, B0) ACC8(8, B1) ACC8(16, B2)
    }
    if (j < e1) {
      int s0 = csr[j];
      const unsigned short* p0 = hb + (long)s0 * 384;
      uint4 A0 = *(const uint4*)(p0);
      uint4 A1 = *(const uint4*)(p0 + 8);
      uint4 A2 = *(const uint4*)(p0 + 16);
      ACC8(0, A0) ACC8(8, A1) ACC8(16, A2)
#undef ACC8
    }
    // write agg -> xS rows (3*nd + a), packed pairs (pairs never cross a)
#pragma unroll
    for (int jj = 0; jj < 12; jj++) {
      int g = sub * 24 + 2 * jj;
      int a_ = g >> 7;
      int c = g & 127;
      unsigned pack = (unsigned)f2bf(acc24[2 * jj]) |
                      ((unsigned)f2bf(acc24[2 * jj + 1]) << 16);
      *(unsigned*)&xS[(3 * nd + a_) * XSTR + c] = pack;
    }
  }
  __syncthreads();

  const int w = tid >> 6;
  const int l = tid & 63;
  const int lr = l & 15;
  const int lg = l >> 4;
  const unsigned short* WQ = WF;
  const unsigned short* WK = WF + 16384;
  const unsigned short* WV = WF + 32768;
  const unsigned short* WO = WF + 49152;

  // ---- phase 1: QKV projections ----
  v4f accq[3][2], acck[3][2], accv[3][2];
#pragma unroll
  for (int mt = 0; mt < 3; mt++)
#pragma unroll
    for (int n = 0; n < 2; n++) {
      accq[mt][n] = (v4f){0.f, 0.f, 0.f, 0.f};
      acck[mt][n] = (v4f){0.f, 0.f, 0.f, 0.f};
      accv[mt][n] = (v4f){0.f, 0.f, 0.f, 0.f};
    }
#pragma unroll
  for (int kt = 0; kt < 4; kt++) {
    short8 af[3];
#pragma unroll
    for (int mt = 0; mt < 3; mt++)
      af[mt] = *(const short8*)&xS[(mt * 16 + lr) * XSTR + kt * 32 + lg * 8];
#pragma unroll
    for (int ntl = 0; ntl < 2; ntl++) {
      long tf = (long)(kt * 8 + 2 * w + ntl) * 512 + l * 8;
      short8 b0 = *(const short8*)&WQ[tf];
      short8 b1 = *(const short8*)&WK[tf];
      short8 b2 = *(const short8*)&WV[tf];
#pragma unroll
      for (int mt = 0; mt < 3; mt++) {
        accq[mt][ntl] = __builtin_amdgcn_mfma_f32_16x16x32_bf16(af[mt], b0, accq[mt][ntl], 0, 0, 0);
        acck[mt][ntl] = __builtin_amdgcn_mfma_f32_16x16x32_bf16(af[mt], b1, acck[mt][ntl], 0, 0, 0);
        accv[mt][ntl] = __builtin_amdgcn_mfma_f32_16x16x32_bf16(af[mt], b2, accv[mt][ntl], 0, 0, 0);
      }
    }
  }
  {
    const float scale = 0.17677669529663687f;  // 1/sqrt(32)
    unsigned short* qw = &qS[w * 48 * QSTR];
    unsigned short* kw = &kS[w * 48 * QSTR];
    unsigned short* vw = &vS[w * 48 * QSTR];
    float bqv[2] = {bq[32 * w + lr], bq[32 * w + 16 + lr]};
    float bkv[2] = {bk[32 * w + lr], bk[32 * w + 16 + lr]};
    float bvv[2] = {bv[32 * w + lr], bv[32 * w + 16 + lr]};
#pragma unroll
    for (int mt = 0; mt < 3; mt++)
#pragma unroll
      for (int ntl = 0; ntl < 2; ntl++)
#pragma unroll
        for (int i = 0; i < 4; i++) {
          int row = mt * 16 + lg * 4 + i;
          int col = ntl * 16 + lr;
          qw[row * QSTR + col] = f2bf((accq[mt][ntl][i] + bqv[ntl]) * scale);
          kw[row * QSTR + col] = f2bf(acck[mt][ntl][i] + bkv[ntl]);
          vw[row * QSTR + col] = f2bf(accv[mt][ntl][i] + bvv[ntl]);
        }
  }

  // residual pre-read (xS still holds agg)
  float resv[3][2][4];
#pragma unroll
  for (int mt = 0; mt < 3; mt++)
#pragma unroll
    for (int ntl = 0; ntl < 2; ntl++)
#pragma unroll
      for (int i = 0; i < 4; i++)
        resv[mt][ntl][i] =
            bf2f(xS[(mt * 16 + lg * 4 + i) * XSTR + 32 * w + ntl * 16 + lr]);
  __syncthreads();

  // ---- phase 2: attention; O overwrites xS (rows = 3*nd+aq) ----
  if (l < 48) {
    int aq = l % 3;
    int ndr = l - aq;
    const unsigned* qr = (const unsigned*)&qS[(w * 48 + l) * QSTR];
    const unsigned* kr0 = (const unsigned*)&kS[(w * 48 + ndr) * QSTR];
    const unsigned* kr1 = (const unsigned*)&kS[(w * 48 + ndr + 1) * QSTR];
    const unsigned* kr2 = (const unsigned*)&kS[(w * 48 + ndr + 2) * QSTR];
    float s0 = 0.f, s1 = 0.f, s2 = 0.f;
#pragma unroll
    for (int j = 0; j < 16; j++) {
      unsigned uq = qr[j], u0 = kr0[j], u1 = kr1[j], u2 = kr2[j];
      float qa = bflo(uq), qb = bfhi(uq);
      s0 = fmaf(qa, bflo(u0), fmaf(qb, bfhi(u0), s0));
      s1 = fmaf(qa, bflo(u1), fmaf(qb, bfhi(u1), s1));
      s2 = fmaf(qa, bflo(u2), fmaf(qb, bfhi(u2), s2));
    }
    float mx = fmaxf(s0, fmaxf(s1, s2));
    float e0 = expf(s0 - mx), e1 = expf(s1 - mx), e2 = expf(s2 - mx);
    float inv = 1.0f / (e0 + e1 + e2);
    e0 *= inv; e1 *= inv; e2 *= inv;
    const unsigned* vr0 = (const unsigned*)&vS[(w * 48 + ndr) * QSTR];
    const unsigned* vr1 = (const unsigned*)&vS[(w * 48 + ndr + 1) * QSTR];
    const unsigned* vr2 = (const unsigned*)&vS[(w * 48 + ndr + 2) * QSTR];
    unsigned ov[16];
#pragma unroll
    for (int j = 0; j < 16; j++) {
      unsigned u0 = vr0[j], u1 = vr1[j], u2 = vr2[j];
      float oa = fmaf(e0, bflo(u0), fmaf(e1, bflo(u1), e2 * bflo(u2)));
      float ob = fmaf(e0, bfhi(u0), fmaf(e1, bfhi(u1), e2 * bfhi(u2)));
      ov[j] = (unsigned)f2bf(oa) | ((unsigned)f2bf(ob) << 16);
    }
    uint4* orow = (uint4*)&xS[l * XSTR + 32 * w];
    orow[0] = make_uint4(ov[0], ov[1], ov[2], ov[3]);
    orow[1] = make_uint4(ov[4], ov[5], ov[6], ov[7]);
    orow[2] = make_uint4(ov[8], ov[9], ov[10], ov[11]);
    orow[3] = make_uint4(ov[12], ov[13], ov[14], ov[15]);
  }
  __syncthreads();

  // ---- phase 3: hI = agg + O @ Wo + bo ----
  v4f acco[3][2];
#pragma unroll
  for (int mt = 0; mt < 3; mt++)
#pragma unroll
    for (int n = 0; n < 2; n++) acco[mt][n] = (v4f){0.f, 0.f, 0.f, 0.f};
#pragma unroll
  for (int kt = 0; kt < 4; kt++) {
    short8 af[3];
#pragma unroll
    for (int mt = 0; mt < 3; mt++)
      af[mt] = *(const short8*)&xS[(mt * 16 + lr) * XSTR + kt * 32 + lg * 8];
#pragma unroll
    for (int ntl = 0; ntl < 2; ntl++) {
      long tf = (long)(kt * 8 + 2 * w + ntl) * 512 + l * 8;
      short8 b = *(const short8*)&WO[tf];
#pragma unroll
      for (int mt = 0; mt < 3; mt++)
        acco[mt][ntl] = __builtin_amdgcn_mfma_f32_16x16x32_bf16(af[mt], b, acco[mt][ntl], 0, 0, 0);
    }
  }
  __syncthreads();   // all O reads of xS done

  // write hI into xS, a-major rows: row' = a*16 + nd  (orig row = 3*nd + a)
  {
    float bov[2] = {bo[32 * w + lr], bo[32 * w + 16 + lr]};
#pragma unroll
    for (int mt = 0; mt < 3; mt++)
#pragma unroll
      for (int ntl = 0; ntl < 2; ntl++)
#pragma unroll
        for (int i = 0; i < 4; i++) {
          int row = mt * 16 + lg * 4 + i;
          int nd = row / 3, a_ = row - nd * 3;
          int gcol = 32 * w + ntl * 16 + lr;
          xS[(a_ * 16 + nd) * XSTR + gcol] =
              f2bf(acco[mt][ntl][i] + bov[ntl] + resv[mt][ntl][i]);
        }
  }
  __syncthreads();

  // ---- phase 4: m = relu(hI @ mu_W1[a] + mb1[a]); tile mt == a ----
  v4f accm[3][2];
#pragma unroll
  for (int mt = 0; mt < 3; mt++)
#pragma unroll
    for (int n = 0; n < 2; n++) accm[mt][n] = (v4f){0.f, 0.f, 0.f, 0.f};
#pragma unroll
  for (int kt = 0; kt < 4; kt++) {
#pragma unroll
    for (int mt = 0; mt < 3; mt++) {
      short8 af = *(const short8*)&xS[(mt * 16 + lr) * XSTR + kt * 32 + lg * 8];
#pragma unroll
      for (int ntl = 0; ntl < 2; ntl++) {
        short8 b = *(const short8*)(WM1 + (long)mt * 16384 +
                                    (long)(kt * 8 + 2 * w + ntl) * 512 + l * 8);
        accm[mt][ntl] = __builtin_amdgcn_mfma_f32_16x16x32_bf16(af, b, accm[mt][ntl], 0, 0, 0);
      }
    }
  }
  __syncthreads();   // all hI reads done

  // write m into xS (already a-major: tile mt rows = a*16 + nd)
#pragma unroll
  for (int mt = 0; mt < 3; mt++)
#pragma unroll
    for (int ntl = 0; ntl < 2; ntl++) {
      int col = 32 * w + ntl * 16 + lr;
      float bias = mb1[mt * 128 + col];
#pragma unroll
      for (int i = 0; i < 4; i++) {
        int rowp = mt * 16 + lg * 4 + i;
        xS[rowp * XSTR + col] = f2bf(fmaxf(accm[mt][ntl][i] + bias, 0.0f));
      }
    }
  __syncthreads();

  // ---- phase 5: mu = m @ mu_W2[a] + mb2[a]; wave w handles a = w (w<3) ----
  if (w < 3) {
    v4f accu = (v4f){0.f, 0.f, 0.f, 0.f};
#pragma unroll
    for (int kt = 0; kt < 4; kt++) {
      short8 af = *(const short8*)&xS[(w * 16 + lr) * XSTR + kt * 32 + lg * 8];
      short8 b = *(const short8*)(WM2 + w * 2048 + kt * 512 + l * 8);
      accu = __builtin_amdgcn_mfma_f32_16x16x32_bf16(af, b, accu, 0, 0, 0);
    }
    float bias = mb2[w * 16 + lr];
#pragma unroll
    for (int i = 0; i < 4; i++) {
      int nd = lg * 4 + i;
      float mu = accu[i] + bias;
      unsigned gidx = (unsigned)((node0 + nd) * 48 + w * 16 + lr);
      unsigned bits = jax_random_bits32(gidx);
      float noise = jax_normal_from_bits(bits);
      float sample = mu + noise;
      float lp = -0.9189385332046727f - 0.5f * noise * noise;
      lp += __shfl_xor(lp, 1, 64);
      lp += __shfl_xor(lp, 2, 64);
      lp += __shfl_xor(lp, 4, 64);
      lp += __shfl_xor(lp, 8, 64);
      if (lr == 0) lpS[w * 16 + nd] = lp;
      float res;
      if (w == 0) {
        float th = tanhf(sample);
        float mx = th;
        mx = fmaxf(mx, __shfl_xor(mx, 1, 64));
        mx = fmaxf(mx, __shfl_xor(mx, 2, 64));
        mx = fmaxf(mx, __shfl_xor(mx, 4, 64));
        mx = fmaxf(mx, __shfl_xor(mx, 8, 64));
        float ex = expf(th - mx);
        float ss = ex;
        ss += __shfl_xor(ss, 1, 64);
        ss += __shfl_xor(ss, 2, 64);
        ss += __shfl_xor(ss, 4, 64);
        ss += __shfl_xor(ss, 8, 64);
        res = ex / ss;
      } else if (w == 1) {
        res = 1.0f / (1.0f + expf(-sample));
      } else {
        res = tanhf(sample);
      }
      out0[gidx] = res;
    }
  }
  __syncthreads();
  if (tid < 16)
    out1[node0 + tid] = lpS[tid] + lpS[16 + tid] + lpS[32 + tid];
}

// ---------------------------------------------------------------------------
extern "C" void kernel_launch(void* const* d_in, const int* in_sizes, int n_in,
                              void* d_out, int out_size, void* d_ws, size_t ws_size,
                              hipStream_t stream) {
  const float* x = (const float*)d_in[0];
  const int* ei = (const int*)d_in[1];
  const float* W1 = (const float*)d_in[2];
  const float* b1 = (const float*)d_in[3];
  const float* W2 = (const float*)d_in[4];
  const float* b2 = (const float*)d_in[5];
  const float* Wq = (const float*)d_in[6];
  const float* bq = (const float*)d_in[7];
  const float* Wk = (const float*)d_in[8];
  const float* bk = (const float*)d_in[9];
  const float* Wv = (const float*)d_in[10];
  const float* bv = (const float*)d_in[11];
  const float* Wo = (const float*)d_in[12];
  const float* bo = (const float*)d_in[13];
  const float* mW1 = (const float*)d_in[14];
  const float* mb1 = (const float*)d_in[15];
  const float* mW2 = (const float*)d_in[16];
  const float* mb2 = (const float*)d_in[17];
  (void)in_sizes; (void)n_in; (void)out_size; (void)ws_size;

  unsigned short* HB = (unsigned short*)d_ws;      // 12,582,912 (h bf16)
  int* deg = (int*)(HB + 12582912);                // 16384
  int* offs = deg + NN;                            // 16385
  int* cur = offs + (NN + 1);                      // 16384
  int* csr = cur + NN;                             // 262144
  unsigned short* wfrag = (unsigned short*)(((uintptr_t)(csr + EE) + 15) & ~(uintptr_t)15);
  unsigned short* w2frag = wfrag + 13 * 16384;     // 3*2048

  const int* dst = ei;
  const int* srcv = ei + EE;

  float* out0 = (float*)d_out;
  float* out1 = out0 + TOT_NOISE;

  hipMemsetAsync(deg, 0, NN * sizeof(int), stream);
  edge_count<<<EE / 256, 256, 0, stream>>>(dst, deg);
  scan_k<<<1, 256, 0, stream>>>(deg, offs, cur);
  edge_fill<<<EE / 256, 256, 0, stream>>>(dst, srcv, cur, csr);
  prep_wfrag<<<dim3(64, 13), 256, 0, stream>>>(W1, W2, mW1, Wq, Wk, Wv, Wo, wfrag);
  prep_w2frag<<<dim3(8, 3), 256, 0, stream>>>(mW2, w2frag);

  // h = relu(x@W1+b1)@W2 + b2  (fused 2-layer MLP)
  mlp_fused<<<dim3(BNODES / 128, 3), 256, 0, stream>>>(x, wfrag, b1, wfrag + 3 * 16384, b2, HB);
  // gather + attention + hI + mu-MLP + noise/logp (mega-fused)
  attn_mega<<<BNODES / 16, 256, 0, stream>>>(HB, offs, csr,
                                             wfrag + 9 * 16384, bq, bk, bv, bo,
                                             wfrag + 6 * 16384, mb1, w2frag, mb2,
                                             out0, out1);
}

// Round 8
// 239.927 us; speedup vs baseline: 2.8053x; 1.0199x over previous
//
#include <hip/hip_runtime.h>
#include <hip/hip_bf16.h>

// Problem constants
#define NN    16384      // N nodes
#define EE    262144     // edges
#define BNODES 32768     // B*N
#define AH    384        // A*H
#define TOT_NOISE 1572864u

typedef __attribute__((ext_vector_type(8))) short short8;
typedef __attribute__((ext_vector_type(4))) float v4f;

__device__ __forceinline__ unsigned short f2bf(float f) {
  unsigned u = __float_as_uint(f);
  unsigned r = u + 0x7fffu + ((u >> 16) & 1u);
  return (unsigned short)(r >> 16);
}
__device__ __forceinline__ float bf2f(unsigned short h) {
  return __uint_as_float(((unsigned)h) << 16);
}
__device__ __forceinline__ float bflo(unsigned u) { return __uint_as_float(u << 16); }
__device__ __forceinline__ float bfhi(unsigned u) { return __uint_as_float(u & 0xffff0000u); }
// HW packed fp32x2 -> bf16x2 (v_cvt_pk_bf16_f32, RNE — identical to f2bf)
__device__ __forceinline__ unsigned pk_bf16(float a, float b) {
  __hip_bfloat162 h = __float22bfloat162_rn(make_float2(a, b));
  return *(unsigned*)&h;
}

// ---------------------------------------------------------------------------
// Threefry-2x32, keys = (0, 42)
// ---------------------------------------------------------------------------
__device__ __forceinline__ void threefry2x32_042(unsigned& x0, unsigned& x1) {
  const unsigned ks0 = 0u;
  const unsigned ks1 = 42u;
  const unsigned ks2 = 0x1BD11BDAu ^ 0u ^ 42u;
  x0 += ks0; x1 += ks1;
#define TFR(r) { x0 += x1; x1 = (x1 << (r)) | (x1 >> (32 - (r))); x1 ^= x0; }
  TFR(13) TFR(15) TFR(26) TFR(6)   x0 += ks1; x1 += ks2 + 1u;
  TFR(17) TFR(29) TFR(16) TFR(24)  x0 += ks2; x1 += ks0 + 2u;
  TFR(13) TFR(15) TFR(26) TFR(6)   x0 += ks0; x1 += ks1 + 3u;
  TFR(17) TFR(29) TFR(16) TFR(24)  x0 += ks1; x1 += ks2 + 4u;
  TFR(13) TFR(15) TFR(26) TFR(6)   x0 += ks2; x1 += ks0 + 5u;
#undef TFR
}

// XLA ErfInv32 (Giles) polynomial
__device__ __forceinline__ float erfinv_f32(float x) {
  float w = -log1pf(-x * x);
  float p;
  if (w < 5.0f) {
    w -= 2.5f;
    p = 2.81022636e-08f;
    p = fmaf(p, w, 3.43273939e-07f);
    p = fmaf(p, w, -3.5233877e-06f);
    p = fmaf(p, w, -4.39150654e-06f);
    p = fmaf(p, w, 0.00021858087f);
    p = fmaf(p, w, -0.00125372503f);
    p = fmaf(p, w, -0.00417768164f);
    p = fmaf(p, w, 0.246640727f);
    p = fmaf(p, w, 1.50140941f);
  } else {
    w = sqrtf(w) - 3.0f;
    p = -0.000200214257f;
    p = fmaf(p, w, 0.000100950558f);
    p = fmaf(p, w, 0.00134934322f);
    p = fmaf(p, w, -0.00367342844f);
    p = fmaf(p, w, 0.00573950773f);
    p = fmaf(p, w, -0.0076224613f);
    p = fmaf(p, w, 0.00943887047f);
    p = fmaf(p, w, 1.00167406f);
    p = fmaf(p, w, 2.83297682f);
  }
  return p * x;
}

__device__ __forceinline__ unsigned jax_random_bits32(unsigned i) {
  unsigned x0 = 0u, x1 = i;
  threefry2x32_042(x0, x1);
  return x0 ^ x1;
}

__device__ __forceinline__ float jax_normal_from_bits(unsigned bits) {
  float f = __uint_as_float((bits >> 9) | 0x3f800000u) - 1.0f;  // [0,1)
  const float lo = -0.99999994f;                                 // nextafter(-1,0)
  float u = f * 2.0f + lo;
  u = fmaxf(u, lo);
  return 1.4142135623730951f * erfinv_f32(u);
}

// ---------------------------------------------------------------------------
// CSR build
// ---------------------------------------------------------------------------
__global__ void edge_count(const int* __restrict__ dst, int* __restrict__ deg) {
  int e = blockIdx.x * 256 + threadIdx.x;
  if (e < EE) atomicAdd(&deg[dst[e]], 1);
}

__global__ __launch_bounds__(1024) void scan_k(const int* __restrict__ deg,
                                               int* __restrict__ offs,
                                               int* __restrict__ cur) {
  __shared__ int wsum[16];
  const int t = threadIdx.x;
  const int base = t * 16;
  int loc[16];
  int s = 0;
#pragma unroll
  for (int i = 0; i < 16; i++) { loc[i] = deg[base + i]; s += loc[i]; }
  const int mysum = s;
  const int lane = t & 63, wid = t >> 6;
#pragma unroll
  for (int off = 1; off < 64; off <<= 1) {
    int v = __shfl_up(s, off, 64);
    if (lane >= off) s += v;
  }
  if (lane == 63) wsum[wid] = s;
  __syncthreads();
  if (t == 0) {
    int r = 0;
#pragma unroll
    for (int i = 0; i < 16; i++) { int v = wsum[i]; wsum[i] = r; r += v; }
  }
  __syncthreads();
  int run = wsum[wid] + s - mysum;
#pragma unroll
  for (int i = 0; i < 16; i++) {
    offs[base + i] = run;
    cur[base + i] = run;
    run += loc[i];
  }
  if (t == 1023) offs[NN] = run;
}

__global__ void edge_fill(const int* __restrict__ dst, const int* __restrict__ srcv,
                          int* __restrict__ cur, int* __restrict__ csr) {
  int e = blockIdx.x * 256 + threadIdx.x;
  if (e < EE) {
    int d = dst[e];
    int p = atomicAdd(&cur[d], 1);
    csr[p] = srcv[e];
  }
}

// ---------------------------------------------------------------------------
// Weight prep: slots 0-2: W1[a]; 3-5: W2[a]; 6-8: mu_W1[a]; 9:Wq 10:Wk 11:Wv
// 12:Wo  (each 16384)  |  slot 13 region: mu_W2 fragments (3 x 2048)
// ---------------------------------------------------------------------------
__global__ __launch_bounds__(256) void prep_wfrag(
    const float* __restrict__ W1, const float* __restrict__ W2,
    const float* __restrict__ mW1,
    const float* __restrict__ Wq, const float* __restrict__ Wk,
    const float* __restrict__ Wv, const float* __restrict__ Wo,
    const float* __restrict__ mW2,
    unsigned short* __restrict__ F) {
  int m = blockIdx.y;
  int f = blockIdx.x * 256 + threadIdx.x;
  if (m == 13) {   // mu_W2: A x 128 x 16
    if (f < 6144) {
      int a = f >> 11;
      int r2 = f & 2047;
      int kt = r2 >> 9;
      int r = r2 & 511;
      int lane = r >> 3, j = r & 7;
      int k = kt * 32 + (lane >> 4) * 8 + j;
      int n = lane & 15;
      F[13 * 16384 + f] = f2bf(mW2[(a * 128 + k) * 16 + n]);
    }
    return;
  }
  const float* W;
  if (m < 3) W = W1 + (long)m * 16384;
  else if (m < 6) W = W2 + (long)(m - 3) * 16384;
  else if (m < 9) W = mW1 + (long)(m - 6) * 16384;
  else W = (m == 9) ? Wq : (m == 10) ? Wk : (m == 11) ? Wv : Wo;
  int tile = f >> 9;
  int kt = tile >> 3, nt = tile & 7;
  int r = f & 511;
  int lane = r >> 3, j = r & 7;
  int k = kt * 32 + (lane >> 4) * 8 + j;
  int n = nt * 16 + (lane & 15);
  F[(long)m * 16384 + f] = f2bf(W[k * 128 + n]);
}

// ---------------------------------------------------------------------------
// Fused 2-layer MLP: h = relu(x@W1+b1)@W2 + b2, per a. 128-row tiles.
// ---------------------------------------------------------------------------
#define GXSTR 136
__global__ __launch_bounds__(256, 4) void mlp_fused(
    const float* __restrict__ X,
    const unsigned short* __restrict__ WF1, const float* __restrict__ b1,
    const unsigned short* __restrict__ WF2, const float* __restrict__ b2,
    unsigned short* __restrict__ H) {
  __shared__ __align__(16) unsigned short As[128 * GXSTR];
  const int a = blockIdx.y;
  const long m0 = (long)blockIdx.x * 128;
  const int tid = threadIdx.x;
  const unsigned short* Wp1 = WF1 + (long)a * 16384;
  const unsigned short* Wp2 = WF2 + (long)a * 16384;

  // stage x tile fp32 -> bf16 (HW packed convert)
#pragma unroll
  for (int p = 0; p < 8; p++) {
    int c = tid + p * 256;
    int row = c >> 4, c8 = (c & 15) * 8;
    float4 v1 = *(const float4*)(X + (m0 + row) * 128 + c8);
    float4 v2 = *(const float4*)(X + (m0 + row) * 128 + c8 + 4);
    uint4 o = make_uint4(pk_bf16(v1.x, v1.y), pk_bf16(v1.z, v1.w),
                         pk_bf16(v2.x, v2.y), pk_bf16(v2.z, v2.w));
    *(uint4*)(&As[row * GXSTR + c8]) = o;
  }
  __syncthreads();

  const int w = tid >> 6, l = tid & 63, lr = l & 15, lg = l >> 4;

  v4f acc[8][2];
#pragma unroll
  for (int mt = 0; mt < 8; mt++) {
    acc[mt][0] = (v4f){0.f, 0.f, 0.f, 0.f};
    acc[mt][1] = (v4f){0.f, 0.f, 0.f, 0.f};
  }
  // phase 1: t1 = x @ W1
#pragma unroll
  for (int kt = 0; kt < 4; kt++) {
    short8 bfr[2];
#pragma unroll
    for (int ntl = 0; ntl < 2; ntl++)
      bfr[ntl] = *(const short8*)(Wp1 + (long)(kt * 8 + 2 * w + ntl) * 512 + l * 8);
#pragma unroll
    for (int mt = 0; mt < 8; mt++) {
      short8 af = *(const short8*)(&As[(mt * 16 + lr) * GXSTR + kt * 32 + lg * 8]);
      acc[mt][0] = __builtin_amdgcn_mfma_f32_16x16x32_bf16(af, bfr[0], acc[mt][0], 0, 0, 0);
      acc[mt][1] = __builtin_amdgcn_mfma_f32_16x16x32_bf16(af, bfr[1], acc[mt][1], 0, 0, 0);
    }
  }
  __syncthreads();   // all As (x) reads done

  // write t1 = relu(acc + b1) back into As
  {
    float bv[2] = {b1[a * 128 + 32 * w + lr], b1[a * 128 + 32 * w + 16 + lr]};
#pragma unroll
    for (int mt = 0; mt < 8; mt++)
#pragma unroll
      for (int ntl = 0; ntl < 2; ntl++)
#pragma unroll
        for (int i = 0; i < 4; i++) {
          int row = mt * 16 + lg * 4 + i;
          int col = 32 * w + ntl * 16 + lr;
          As[row * GXSTR + col] = f2bf(fmaxf(acc[mt][ntl][i] + bv[ntl], 0.0f));
        }
  }
  __syncthreads();

  // phase 2: h = t1 @ W2 + b2
#pragma unroll
  for (int mt = 0; mt < 8; mt++) {
    acc[mt][0] = (v4f){0.f, 0.f, 0.f, 0.f};
    acc[mt][1] = (v4f){0.f, 0.f, 0.f, 0.f};
  }
#pragma unroll
  for (int kt = 0; kt < 4; kt++) {
    short8 bfr[2];
#pragma unroll
    for (int ntl = 0; ntl < 2; ntl++)
      bfr[ntl] = *(const short8*)(Wp2 + (long)(kt * 8 + 2 * w + ntl) * 512 + l * 8);
#pragma unroll
    for (int mt = 0; mt < 8; mt++) {
      short8 af = *(const short8*)(&As[(mt * 16 + lr) * GXSTR + kt * 32 + lg * 8]);
      acc[mt][0] = __builtin_amdgcn_mfma_f32_16x16x32_bf16(af, bfr[0], acc[mt][0], 0, 0, 0);
      acc[mt][1] = __builtin_amdgcn_mfma_f32_16x16x32_bf16(af, bfr[1], acc[mt][1], 0, 0, 0);
    }
  }
  {
    float bv[2] = {b2[a * 128 + 32 * w + lr], b2[a * 128 + 32 * w + 16 + lr]};
#pragma unroll
    for (int mt = 0; mt < 8; mt++)
#pragma unroll
      for (int ntl = 0; ntl < 2; ntl++)
#pragma unroll
        for (int i = 0; i < 4; i++) {
          long row = m0 + mt * 16 + lg * 4 + i;
          int col = 32 * w + ntl * 16 + lr;
          H[row * 384 + a * 128 + col] = f2bf(acc[mt][ntl][i] + bv[ntl]);
        }
  }
}

// ---------------------------------------------------------------------------
// Mega-fused: gather + attention + mu-MLP + noise/logp. 16 nodes/block.
// Q lives in xS (per-wave head cols) -> no qS buffer; LDS 39360 B -> 4 blk/CU.
// Gather unrolled x4 (12 dwordx4 in flight per thread).
// ---------------------------------------------------------------------------
#define XSTR 136
#define QSTR 34
__global__ __launch_bounds__(256, 4) void attn_mega(
    const unsigned short* __restrict__ H, const int* __restrict__ offs,
    const int* __restrict__ csr,
    const unsigned short* __restrict__ WF,
    const float* __restrict__ bq, const float* __restrict__ bk,
    const float* __restrict__ bv, const float* __restrict__ bo,
    const unsigned short* __restrict__ WM1, const float* __restrict__ mb1,
    const unsigned short* __restrict__ WM2, const float* __restrict__ mb2,
    float* __restrict__ out0, float* __restrict__ out1) {
  __shared__ __align__(16) unsigned short xS[48 * XSTR];
  __shared__ __align__(16) unsigned short kS[4 * 48 * QSTR];
  __shared__ __align__(16) unsigned short vS[4 * 48 * QSTR];
  __shared__ float lpS[48];

  const int tid = threadIdx.x;
  const long node0 = (long)blockIdx.x * 16;

  // ---- phase 0: gather + segment-sum agg for 16 nodes directly into xS ----
  {
    const int bt = (int)(node0 >> 14);           // batch
    const int nbase = (int)(node0 & (NN - 1));
    const int nd = tid >> 4;                     // 0..15 local node
    const int sub = tid & 15;                    // 0..15 col group (24 bf16)
    const int n = nbase + nd;
    const int e0 = offs[n], e1 = offs[n + 1];
    const unsigned short* hb = H + (long)bt * NN * 384 + sub * 24;
    float acc24[24];
#pragma unroll
    for (int i = 0; i < 24; i++) acc24[i] = 0.f;

#define ACC8(base, u)                                                   \
    { acc24[base+0] += bflo(u.x); acc24[base+1] += bfhi(u.x);           \
      acc24[base+2] += bflo(u.y); acc24[base+3] += bfhi(u.y);           \
      acc24[base+4] += bflo(u.z); acc24[base+5] += bfhi(u.z);           \
      acc24[base+6] += bflo(u.w); acc24[base+7] += bfhi(u.w); }
    int j = e0;
    for (; j + 4 <= e1; j += 4) {
      int s0 = csr[j], s1 = csr[j + 1], s2 = csr[j + 2], s3 = csr[j + 3];
      const unsigned short* p0 = hb + (long)s0 * 384;
      const unsigned short* p1 = hb + (long)s1 * 384;
      const unsigned short* p2 = hb + (long)s2 * 384;
      const unsigned short* p3 = hb + (long)s3 * 384;
      uint4 A0 = *(const uint4*)(p0);
      uint4 A1 = *(const uint4*)(p0 + 8);
      uint4 A2 = *(const uint4*)(p0 + 16);
      uint4 B0 = *(const uint4*)(p1);
      uint4 B1 = *(const uint4*)(p1 + 8);
      uint4 B2 = *(const uint4*)(p1 + 16);
      uint4 C0 = *(const uint4*)(p2);
      uint4 C1 = *(const uint4*)(p2 + 8);
      uint4 C2 = *(const uint4*)(p2 + 16);
      uint4 D0 = *(const uint4*)(p3);
      uint4 D1 = *(const uint4*)(p3 + 8);
      uint4 D2 = *(const uint4*)(p3 + 16);
      ACC8(0, A0) ACC8(8, A1) ACC8(16, A2)
      ACC8(0, B0) ACC8(8, B1) ACC8(16, B2)
      ACC8(0, C0) ACC8(8, C1) ACC8(16, C2)
      ACC8(0, D0) ACC8(8, D1) ACC8(16, D2)
    }
    for (; j < e1; j++) {
      int s0 = csr[j];
      const unsigned short* p0 = hb + (long)s0 * 384;
      uint4 A0 = *(const uint4*)(p0);
      uint4 A1 = *(const uint4*)(p0 + 8);
      uint4 A2 = *(const uint4*)(p0 + 16);
      ACC8(0, A0) ACC8(8, A1) ACC8(16, A2)
    }
#undef ACC8
    // write agg -> xS rows (3*nd + a), packed pairs (pairs never cross a)
#pragma unroll
    for (int jj = 0; jj < 12; jj++) {
      int g = sub * 24 + 2 * jj;
      int a_ = g >> 7;
      int c = g & 127;
      *(unsigned*)&xS[(3 * nd + a_) * XSTR + c] =
          pk_bf16(acc24[2 * jj], acc24[2 * jj + 1]);
    }
  }
  __syncthreads();

  const int w = tid >> 6;
  const int l = tid & 63;
  const int lr = l & 15;
  const int lg = l >> 4;
  const unsigned short* WQ = WF;
  const unsigned short* WK = WF + 16384;
  const unsigned short* WV = WF + 32768;
  const unsigned short* WO = WF + 49152;

  // ---- phase 1: QKV projections ----
  v4f accq[3][2], acck[3][2], accv[3][2];
#pragma unroll
  for (int mt = 0; mt < 3; mt++)
#pragma unroll
    for (int n = 0; n < 2; n++) {
      accq[mt][n] = (v4f){0.f, 0.f, 0.f, 0.f};
      acck[mt][n] = (v4f){0.f, 0.f, 0.f, 0.f};
      accv[mt][n] = (v4f){0.f, 0.f, 0.f, 0.f};
    }
#pragma unroll
  for (int kt = 0; kt < 4; kt++) {
    short8 af[3];
#pragma unroll
    for (int mt = 0; mt < 3; mt++)
      af[mt] = *(const short8*)&xS[(mt * 16 + lr) * XSTR + kt * 32 + lg * 8];
#pragma unroll
    for (int ntl = 0; ntl < 2; ntl++) {
      long tf = (long)(kt * 8 + 2 * w + ntl) * 512 + l * 8;
      short8 b0 = *(const short8*)&WQ[tf];
      short8 b1 = *(const short8*)&WK[tf];
      short8 b2 = *(const short8*)&WV[tf];
#pragma unroll
      for (int mt = 0; mt < 3; mt++) {
        accq[mt][ntl] = __builtin_amdgcn_mfma_f32_16x16x32_bf16(af[mt], b0, accq[mt][ntl], 0, 0, 0);
        acck[mt][ntl] = __builtin_amdgcn_mfma_f32_16x16x32_bf16(af[mt], b1, acck[mt][ntl], 0, 0, 0);
        accv[mt][ntl] = __builtin_amdgcn_mfma_f32_16x16x32_bf16(af[mt], b2, accv[mt][ntl], 0, 0, 0);
      }
    }
  }
  __syncthreads();   // all waves' xS (agg) MFMA reads complete

  // residual pre-read (per-wave own head cols of xS), THEN write Q over them
  float resv[3][2][4];
#pragma unroll
  for (int mt = 0; mt < 3; mt++)
#pragma unroll
    for (int ntl = 0; ntl < 2; ntl++)
#pragma unroll
      for (int i = 0; i < 4; i++)
        resv[mt][ntl][i] =
            bf2f(xS[(mt * 16 + lg * 4 + i) * XSTR + 32 * w + ntl * 16 + lr]);

  {
    const float scale = 0.17677669529663687f;  // 1/sqrt(32)
    unsigned short* kw = &kS[w * 48 * QSTR];
    unsigned short* vw = &vS[w * 48 * QSTR];
    float bqv[2] = {bq[32 * w + lr], bq[32 * w + 16 + lr]};
    float bkv[2] = {bk[32 * w + lr], bk[32 * w + 16 + lr]};
    float bvv[2] = {bv[32 * w + lr], bv[32 * w + 16 + lr]};
#pragma unroll
    for (int mt = 0; mt < 3; mt++)
#pragma unroll
      for (int ntl = 0; ntl < 2; ntl++)
#pragma unroll
        for (int i = 0; i < 4; i++) {
          int row = mt * 16 + lg * 4 + i;
          int col = ntl * 16 + lr;
          xS[row * XSTR + 32 * w + col] = f2bf((accq[mt][ntl][i] + bqv[ntl]) * scale);
          kw[row * QSTR + col] = f2bf(acck[mt][ntl][i] + bkv[ntl]);
          vw[row * QSTR + col] = f2bf(accv[mt][ntl][i] + bvv[ntl]);
        }
  }
  __syncthreads();

  // ---- phase 2: attention; lane l<48 owns (nd=l/3, aq=l%3) of head w.
  // O overwrites lane's own Q row in xS — race-free.
  if (l < 48) {
    int aq = l % 3;
    int ndr = l - aq;
    const unsigned* qr = (const unsigned*)&xS[l * XSTR + 32 * w];
    const unsigned* kr0 = (const unsigned*)&kS[(w * 48 + ndr) * QSTR];
    const unsigned* kr1 = (const unsigned*)&kS[(w * 48 + ndr + 1) * QSTR];
    const unsigned* kr2 = (const unsigned*)&kS[(w * 48 + ndr + 2) * QSTR];
    float s0 = 0.f, s1 = 0.f, s2 = 0.f;
#pragma unroll
    for (int j = 0; j < 16; j++) {
      unsigned uq = qr[j], u0 = kr0[j], u1 = kr1[j], u2 = kr2[j];
      float qa = bflo(uq), qb = bfhi(uq);
      s0 = fmaf(qa, bflo(u0), fmaf(qb, bfhi(u0), s0));
      s1 = fmaf(qa, bflo(u1), fmaf(qb, bfhi(u1), s1));
      s2 = fmaf(qa, bflo(u2), fmaf(qb, bfhi(u2), s2));
    }
    float mx = fmaxf(s0, fmaxf(s1, s2));
    float e0 = expf(s0 - mx), e1 = expf(s1 - mx), e2 = expf(s2 - mx);
    float inv = 1.0f / (e0 + e1 + e2);
    e0 *= inv; e1 *= inv; e2 *= inv;
    const unsigned* vr0 = (const unsigned*)&vS[(w * 48 + ndr) * QSTR];
    const unsigned* vr1 = (const unsigned*)&vS[(w * 48 + ndr + 1) * QSTR];
    const unsigned* vr2 = (const unsigned*)&vS[(w * 48 + ndr + 2) * QSTR];
    unsigned ov[16];
#pragma unroll
    for (int j = 0; j < 16; j++) {
      unsigned u0 = vr0[j], u1 = vr1[j], u2 = vr2[j];
      float oa = fmaf(e0, bflo(u0), fmaf(e1, bflo(u1), e2 * bflo(u2)));
      float ob = fmaf(e0, bfhi(u0), fmaf(e1, bfhi(u1), e2 * bfhi(u2)));
      ov[j] = pk_bf16(oa, ob);
    }
    uint4* orow = (uint4*)&xS[l * XSTR + 32 * w];
    orow[0] = make_uint4(ov[0], ov[1], ov[2], ov[3]);
    orow[1] = make_uint4(ov[4], ov[5], ov[6], ov[7]);
    orow[2] = make_uint4(ov[8], ov[9], ov[10], ov[11]);
    orow[3] = make_uint4(ov[12], ov[13], ov[14], ov[15]);
  }
  __syncthreads();

  // ---- phase 3: hI = agg + O @ Wo + bo ----
  v4f acco[3][2];
#pragma unroll
  for (int mt = 0; mt < 3; mt++)
#pragma unroll
    for (int n = 0; n < 2; n++) acco[mt][n] = (v4f){0.f, 0.f, 0.f, 0.f};
#pragma unroll
  for (int kt = 0; kt < 4; kt++) {
    short8 af[3];
#pragma unroll
    for (int mt = 0; mt < 3; mt++)
      af[mt] = *(const short8*)&xS[(mt * 16 + lr) * XSTR + kt * 32 + lg * 8];
#pragma unroll
    for (int ntl = 0; ntl < 2; ntl++) {
      long tf = (long)(kt * 8 + 2 * w + ntl) * 512 + l * 8;
      short8 b = *(const short8*)&WO[tf];
#pragma unroll
      for (int mt = 0; mt < 3; mt++)
        acco[mt][ntl] = __builtin_amdgcn_mfma_f32_16x16x32_bf16(af[mt], b, acco[mt][ntl], 0, 0, 0);
    }
  }
  __syncthreads();   // all O reads of xS done

  // write hI into xS, a-major rows: row' = a*16 + nd  (orig row = 3*nd + a)
  {
    float bov[2] = {bo[32 * w + lr], bo[32 * w + 16 + lr]};
#pragma unroll
    for (int mt = 0; mt < 3; mt++)
#pragma unroll
      for (int ntl = 0; ntl < 2; ntl++)
#pragma unroll
        for (int i = 0; i < 4; i++) {
          int row = mt * 16 + lg * 4 + i;
          int nd = row / 3, a_ = row - nd * 3;
          int gcol = 32 * w + ntl * 16 + lr;
          xS[(a_ * 16 + nd) * XSTR + gcol] =
              f2bf(acco[mt][ntl][i] + bov[ntl] + resv[mt][ntl][i]);
        }
  }
  __syncthreads();

  // ---- phase 4: m = relu(hI @ mu_W1[a] + mb1[a]); tile mt == a ----
  v4f accm[3][2];
#pragma unroll
  for (int mt = 0; mt < 3; mt++)
#pragma unroll
    for (int n = 0; n < 2; n++) accm[mt][n] = (v4f){0.f, 0.f, 0.f, 0.f};
#pragma unroll
  for (int kt = 0; kt < 4; kt++) {
#pragma unroll
    for (int mt = 0; mt < 3; mt++) {
      short8 af = *(const short8*)&xS[(mt * 16 + lr) * XSTR + kt * 32 + lg * 8];
#pragma unroll
      for (int ntl = 0; ntl < 2; ntl++) {
        short8 b = *(const short8*)(WM1 + (long)mt * 16384 +
                                    (long)(kt * 8 + 2 * w + ntl) * 512 + l * 8);
        accm[mt][ntl] = __builtin_amdgcn_mfma_f32_16x16x32_bf16(af, b, accm[mt][ntl], 0, 0, 0);
      }
    }
  }
  __syncthreads();   // all hI reads done

  // write m into xS (already a-major: tile mt rows = a*16 + nd)
#pragma unroll
  for (int mt = 0; mt < 3; mt++)
#pragma unroll
    for (int ntl = 0; ntl < 2; ntl++) {
      int col = 32 * w + ntl * 16 + lr;
      float bias = mb1[mt * 128 + col];
#pragma unroll
      for (int i = 0; i < 4; i++) {
        int rowp = mt * 16 + lg * 4 + i;
        xS[rowp * XSTR + col] = f2bf(fmaxf(accm[mt][ntl][i] + bias, 0.0f));
      }
    }
  __syncthreads();

  // ---- phase 5: mu = m @ mu_W2[a] + mb2[a]; wave w handles a = w (w<3) ----
  if (w < 3) {
    v4f accu = (v4f){0.f, 0.f, 0.f, 0.f};
#pragma unroll
    for (int kt = 0; kt < 4; kt++) {
      short8 af = *(const short8*)&xS[(w * 16 + lr) * XSTR + kt * 32 + lg * 8];
      short8 b = *(const short8*)(WM2 + w * 2048 + kt * 512 + l * 8);
      accu = __builtin_amdgcn_mfma_f32_16x16x32_bf16(af, b, accu, 0, 0, 0);
    }
    float bias = mb2[w * 16 + lr];
#pragma unroll
    for (int i = 0; i < 4; i++) {
      int nd = lg * 4 + i;
      float mu = accu[i] + bias;
      unsigned gidx = (unsigned)((node0 + nd) * 48 + w * 16 + lr);
      unsigned bits = jax_random_bits32(gidx);
      float noise = jax_normal_from_bits(bits);
      float sample = mu + noise;
      float lp = -0.9189385332046727f - 0.5f * noise * noise;
      lp += __shfl_xor(lp, 1, 64);
      lp += __shfl_xor(lp, 2, 64);
      lp += __shfl_xor(lp, 4, 64);
      lp += __shfl_xor(lp, 8, 64);
      if (lr == 0) lpS[w * 16 + nd] = lp;
      float res;
      if (w == 0) {
        float th = tanhf(sample);
        float mx = th;
        mx = fmaxf(mx, __shfl_xor(mx, 1, 64));
        mx = fmaxf(mx, __shfl_xor(mx, 2, 64));
        mx = fmaxf(mx, __shfl_xor(mx, 4, 64));
        mx = fmaxf(mx, __shfl_xor(mx, 8, 64));
        float ex = expf(th - mx);
        float ss = ex;
        ss += __shfl_xor(ss, 1, 64);
        ss += __shfl_xor(ss, 2, 64);
        ss += __shfl_xor(ss, 4, 64);
        ss += __shfl_xor(ss, 8, 64);
        res = ex / ss;
      } else if (w == 1) {
        res = 1.0f / (1.0f + expf(-sample));
      } else {
        res = tanhf(sample);
      }
      out0[gidx] = res;
    }
  }
  __syncthreads();
  if (tid < 16)
    out1[node0 + tid] = lpS[tid] + lpS[16 + tid] + lpS[32 + tid];
}

// ---------------------------------------------------------------------------
extern "C" void kernel_launch(void* const* d_in, const int* in_sizes, int n_in,
                              void* d_out, int out_size, void* d_ws, size_t ws_size,
                              hipStream_t stream) {
  const float* x = (const float*)d_in[0];
  const int* ei = (const int*)d_in[1];
  const float* W1 = (const float*)d_in[2];
  const float* b1 = (const float*)d_in[3];
  const float* W2 = (const float*)d_in[4];
  const float* b2 = (const float*)d_in[5];
  const float* Wq = (const float*)d_in[6];
  const float* bq = (const float*)d_in[7];
  const float* Wk = (const float*)d_in[8];
  const float* bk = (const float*)d_in[9];
  const float* Wv = (const float*)d_in[10];
  const float* bv = (const float*)d_in[11];
  const float* Wo = (const float*)d_in[12];
  const float* bo = (const float*)d_in[13];
  const float* mW1 = (const float*)d_in[14];
  const float* mb1 = (const float*)d_in[15];
  const float* mW2 = (const float*)d_in[16];
  const float* mb2 = (const float*)d_in[17];
  (void)in_sizes; (void)n_in; (void)out_size; (void)ws_size;

  unsigned short* HB = (unsigned short*)d_ws;      // 12,582,912 (h bf16)
  int* deg = (int*)(HB + 12582912);                // 16384
  int* offs = deg + NN;                            // 16385
  int* cur = offs + (NN + 1);                      // 16384
  int* csr = cur + NN;                             // 262144
  unsigned short* wfrag = (unsigned short*)(((uintptr_t)(csr + EE) + 15) & ~(uintptr_t)15);
  unsigned short* w2frag = wfrag + 13 * 16384;     // 3*2048

  const int* dst = ei;
  const int* srcv = ei + EE;

  float* out0 = (float*)d_out;
  float* out1 = out0 + TOT_NOISE;

  hipMemsetAsync(deg, 0, NN * sizeof(int), stream);
  edge_count<<<EE / 256, 256, 0, stream>>>(dst, deg);
  scan_k<<<1, 1024, 0, stream>>>(deg, offs, cur);
  edge_fill<<<EE / 256, 256, 0, stream>>>(dst, srcv, cur, csr);
  prep_wfrag<<<dim3(64, 14), 256, 0, stream>>>(W1, W2, mW1, Wq, Wk, Wv, Wo, mW2, wfrag);

  // h = relu(x@W1+b1)@W2 + b2  (fused 2-layer MLP)
  mlp_fused<<<dim3(BNODES / 128, 3), 256, 0, stream>>>(x, wfrag, b1, wfrag + 3 * 16384, b2, HB);
  // gather + attention + hI + mu-MLP + noise/logp (mega-fused)
  attn_mega<<<BNODES / 16, 256, 0, stream>>>(HB, offs, csr,
                                             wfrag + 9 * 16384, bq, bk, bv, bo,
                                             wfrag + 6 * 16384, mb1, w2frag, mb2,
                                             out0, out1);
}